// Round 1
// baseline (1158.083 us; speedup 1.0000x reference)
//
#include <hip/hip_runtime.h>
#include <hip/hip_bf16.h>

#define L_SEQ 1408
#define DMODEL 512
#define NH 8
#define DH 64
#define BATCH 2
#define BH 16
#define ROWS 2816
#define DFF 2048
#define KSEL 704

__device__ __forceinline__ float gelu_f(float x){
  return 0.5f*x*(1.0f+erff(x*0.70710678118654752440f));
}

// monotonic float->uint transform (ascending order)
__device__ __forceinline__ unsigned f2o(float f){
  unsigned u = __float_as_uint(f);
  return (u & 0x80000000u) ? ~u : (u | 0x80000000u);
}

__device__ __forceinline__ float block_reduce_sum(float v){
  __shared__ float sred[8];
  int lane = threadIdx.x & 63;
  int w = threadIdx.x >> 6;
  #pragma unroll
  for (int o=32;o>0;o>>=1) v += __shfl_down(v,o,64);
  if (lane==0) sred[w]=v;
  __syncthreads();
  if (w==0){
    float x = (lane < (int)(blockDim.x>>6)) ? sred[lane] : 0.f;
    #pragma unroll
    for (int o=4;o>0;o>>=1) x += __shfl_down(x,o,64);
    if (lane==0) sred[0]=x;
  }
  __syncthreads();
  float r = sred[0];
  __syncthreads();
  return r;
}

__device__ __forceinline__ float block_reduce_max(float v){
  __shared__ float sredm[8];
  int lane = threadIdx.x & 63;
  int w = threadIdx.x >> 6;
  #pragma unroll
  for (int o=32;o>0;o>>=1) v = fmaxf(v, __shfl_down(v,o,64));
  if (lane==0) sredm[w]=v;
  __syncthreads();
  if (w==0){
    float x = (lane < (int)(blockDim.x>>6)) ? sredm[lane] : -3.0e38f;
    #pragma unroll
    for (int o=4;o>0;o>>=1) x = fmaxf(x, __shfl_down(x,o,64));
    if (lane==0) sredm[0]=x;
  }
  __syncthreads();
  float r = sredm[0];
  __syncthreads();
  return r;
}

// ---------------- LayerNorm (D=512), one row per 256-thread block ----------------
__global__ __launch_bounds__(256) void ln_kernel(const float* __restrict__ x,
                                                 const float* __restrict__ g,
                                                 const float* __restrict__ b,
                                                 float* __restrict__ out){
  int row = blockIdx.x;
  const float* xr = x + (size_t)row*DMODEL;
  int t = threadIdx.x;
  float v0 = xr[t], v1 = xr[t+256];
  float s = block_reduce_sum(v0+v1);
  float mean = s * (1.f/512.f);
  float d0 = v0-mean, d1 = v1-mean;
  float ss = block_reduce_sum(d0*d0 + d1*d1);
  float rstd = rsqrtf(ss*(1.f/512.f) + 1e-5f);
  float* orow = out + (size_t)row*DMODEL;
  orow[t]     = d0*rstd*g[t]     + b[t];
  orow[t+256] = d1*rstd*g[t+256] + b[t+256];
}

// ---------------- Q/K projections: per (b,l), 512 threads, 8 rows/block ----------------
__global__ __launch_bounds__(512) void qk_proj_kernel(const float* __restrict__ xn,
                                                      const float* __restrict__ w1, const float* __restrict__ bp1,
                                                      const float* __restrict__ w2, const float* __restrict__ bp2,
                                                      float* __restrict__ q, float* __restrict__ k){
  __shared__ float sw1[64*64], sw2[64*64], xr[512];
  int t = threadIdx.x;
  #pragma unroll
  for (int i=0;i<8;i++){ sw1[i*512+t]=w1[i*512+t]; sw2[i*512+t]=w2[i*512+t]; }
  int rowbase = blockIdx.x*8;
  int h = t>>6, j = t&63;
  float bb1 = bp1[j], bb2 = bp2[j];
  for (int r=0;r<8;r++){
    int row = rowbase + r;
    __syncthreads();
    xr[t] = xn[(size_t)row*DMODEL + t];
    __syncthreads();
    float a1=bb1, a2=bb2;
    const float* xv = &xr[h*64];
    #pragma unroll
    for (int kk=0;kk<64;kk++){
      float xvk = xv[kk];
      a1 += xvk*sw1[kk*64+j];
      a2 += xvk*sw2[kk*64+j];
    }
    int b_ = row / L_SEQ, l = row % L_SEQ;
    size_t o = (((size_t)(b_*NH+h))*L_SEQ + l)*64 + j;
    q[o]=a1; k[o]=a2;
  }
}

// ---------------- adj = gelu(Q K^T) per (b,h) ----------------
__global__ __launch_bounds__(256) void qkt_gelu_kernel(const float* __restrict__ q,
                                                       const float* __restrict__ k,
                                                       float* __restrict__ adj){
  __shared__ float Qs[64][65], Ks[64][65];
  int z = blockIdx.z;
  const float* Qb = q + (size_t)z*L_SEQ*64;
  const float* Kb = k + (size_t)z*L_SEQ*64;
  int i0 = blockIdx.x*64, j0 = blockIdx.y*64;
  int t = threadIdx.x;
  #pragma unroll
  for (int i=0;i<16;i++){
    int lin=i*256+t; int r=lin>>6, c=lin&63;
    Qs[r][c] = Qb[(size_t)(i0+r)*64 + c];
    Ks[r][c] = Kb[(size_t)(j0+r)*64 + c];
  }
  __syncthreads();
  int tx=t&15, ty=t>>4;
  float acc[4][4]={};
  #pragma unroll
  for (int kk=0;kk<64;kk++){
    float a[4], bv[4];
    #pragma unroll
    for(int m=0;m<4;m++) a[m]=Qs[ty*4+m][kk];
    #pragma unroll
    for(int n=0;n<4;n++) bv[n]=Ks[tx*4+n][kk];
    #pragma unroll
    for(int m=0;m<4;m++)
      #pragma unroll
      for(int n=0;n<4;n++) acc[m][n] += a[m]*bv[n];
  }
  float* Cb = adj + (size_t)z*L_SEQ*L_SEQ;
  #pragma unroll
  for(int m=0;m<4;m++){
    int r=i0+ty*4+m;
    #pragma unroll
    for(int n=0;n<4;n++) Cb[(size_t)r*L_SEQ + j0+tx*4+n] = gelu_f(acc[m][n]);
  }
}

// ---------------- per-row: top-k mask, gating, losses, final softmax ----------------
__global__ __launch_bounds__(256) void row_pipe_kernel(float* __restrict__ adj,
                                                       const float* __restrict__ wg,
                                                       const float* __restrict__ masks,
                                                       float* __restrict__ spz,
                                                       float* __restrict__ entp){
  __shared__ float s[L_SEQ];
  __shared__ unsigned hist[256];
  __shared__ unsigned scanbuf[256];
  __shared__ unsigned sel_u, sel_base;
  int l = blockIdx.x, z = blockIdx.y;
  float* row = adj + ((size_t)z*L_SEQ + l)*L_SEQ;
  int t = threadIdx.x;
  for (int d=t; d<L_SEQ; d+=256) s[d] = row[d];
  __syncthreads();

  // radix select: value at ascending rank KSEL
  unsigned prefix=0, himask=0;
  int rem = KSEL;
  for (int pass=0; pass<4; pass++){
    int shift = 24 - 8*pass;
    hist[t]=0; __syncthreads();
    for (int d=t; d<L_SEQ; d+=256){
      unsigned u = f2o(s[d]);
      if ((u & himask) == prefix) atomicAdd(&hist[(u>>shift)&255u], 1u);
    }
    __syncthreads();
    unsigned h = hist[t]; scanbuf[t]=h; __syncthreads();
    for (int o=1;o<256;o<<=1){
      unsigned v=(t>=o)?scanbuf[t-o]:0u; __syncthreads();
      scanbuf[t]+=v; __syncthreads();
    }
    unsigned incl = scanbuf[t], excl = incl - h;
    if ((int)excl < rem && rem <= (int)incl){ sel_u = (unsigned)t; sel_base = excl; }
    __syncthreads();
    prefix |= (sel_u << shift);
    himask |= (255u << shift);
    rem -= (int)sel_base;
    __syncthreads();
  }
  unsigned t_u = prefix;
  int z_eq = rem;   // # equal-valued entries to zero, lowest index first

  // tie zeroing (pristine equality), wave 0, index order
  if (t < 64){
    int cnt = 0;
    for (int c=0; c<22 && cnt < z_eq; c++){
      int d = c*64 + t;
      bool eq = (f2o(s[d]) == t_u);
      unsigned long long m = __ballot(eq);
      int pre = __popcll(m & ((1ull<<t)-1ull));
      if (eq && (cnt + pre) < z_eq) s[d] = 0.f;
      cnt += __popcll(m);
    }
  }
  __syncthreads();
  for (int d=t; d<L_SEQ; d+=256){
    if (f2o(s[d]) < t_u) s[d] = 0.f;
  }
  __syncthreads();

  // gating logits = masked_row @ w_gate  -> softmax3
  float p0=0.f, p1v=0.f, p2v=0.f;
  for (int d=t; d<L_SEQ; d+=256){
    float a = s[d];
    p0  += a*wg[d*3+0];
    p1v += a*wg[d*3+1];
    p2v += a*wg[d*3+2];
  }
  p0  = block_reduce_sum(p0);
  p1v = block_reduce_sum(p1v);
  p2v = block_reduce_sum(p2v);
  float mx = fmaxf(p0, fmaxf(p1v,p2v));
  float e0=expf(p0-mx), e1=expf(p1v-mx), e2=expf(p2v-mx);
  float inv = 1.f/(e0+e1+e2);
  float pr0=e0*inv, pr1=e1*inv, pr2=e2*inv;
  float pr[3]={pr0,pr1,pr2};
  int i0=0; if (pr[1]>pr[i0]) i0=1; if (pr[2]>pr[i0]) i0=2;
  int a_=(i0==0)?1:0, b_=(i0==2)?1:2;
  int i1 = (pr[b_]>pr[a_])?b_:a_;
  bool top2 = !(pr[i0] > 0.5f);
  float g0=(i0==0)||(top2&&i1==0)?1.f:0.f;
  float g1=(i0==1)||(top2&&i1==1)?1.f:0.f;
  float g2=(i0==2)||(top2&&i1==2)?1.f:0.f;
  if (t==0){
    float ent = pr0*logf(pr0+1e-10f)+pr1*logf(pr1+1e-10f)+pr2*logf(pr2+1e-10f);
    atomicAdd(&entp[(z*L_SEQ+l) & 255], ent);
    atomicAdd(&spz[l*3+0], pr[i0]);
    if (top2) atomicAdd(&spz[l*3+1], pr[i1]);
  }

  // final mask + softmax
  const float* m0 = masks + ((size_t)l*3+0)*L_SEQ;
  const float* m1 = m0 + L_SEQ;
  const float* m2 = m1 + L_SEQ;
  float lmax = -3.0e38f;
  for (int d=t; d<L_SEQ; d+=256){
    float fm = (d==l) ? 1.f : 0.f;
    if (g0!=0.f) fm += m0[d];
    if (g1!=0.f) fm += m1[d];
    if (g2!=0.f) fm += m2[d];
    float v = s[d]*fm;
    s[d] = v;
    lmax = fmaxf(lmax, v);
  }
  __syncthreads();
  lmax = block_reduce_max(lmax);
  float lsum = 0.f;
  for (int d=t; d<L_SEQ; d+=256){
    float e = expf(s[d]-lmax); s[d]=e; lsum += e;
  }
  lsum = block_reduce_sum(lsum);
  float invs = 1.f/lsum;
  for (int d=t; d<L_SEQ; d+=256) row[d] = s[d]*invs;
}

// ---------------- generic NN GEMM: C = act(A@B + bias) (+res) ----------------
__global__ __launch_bounds__(256) void gemm_nn_kernel(const float* __restrict__ A,
                                                      const float* __restrict__ B,
                                                      float* __restrict__ C,
                                                      const float* __restrict__ bias,
                                                      const float* __restrict__ res,
                                                      int N, int K, int act){
  __shared__ float As[64][65], Bs[64][65];
  int i0 = blockIdx.x*64, j0 = blockIdx.y*64;
  int t = threadIdx.x, tx=t&15, ty=t>>4;
  float acc[4][4]={};
  for (int k0=0;k0<K;k0+=64){
    #pragma unroll
    for (int i=0;i<16;i++){
      int lin=i*256+t, r=lin>>6, c=lin&63;
      As[r][c] = A[(size_t)(i0+r)*K + k0+c];
      Bs[r][c] = B[(size_t)(k0+r)*N + j0+c];
    }
    __syncthreads();
    #pragma unroll
    for (int kk=0;kk<64;kk++){
      float a[4], bv[4];
      #pragma unroll
      for(int m=0;m<4;m++) a[m]=As[ty*4+m][kk];
      #pragma unroll
      for(int n=0;n<4;n++) bv[n]=Bs[kk][tx*4+n];
      #pragma unroll
      for(int m=0;m<4;m++)
        #pragma unroll
        for(int n=0;n<4;n++) acc[m][n] += a[m]*bv[n];
    }
    __syncthreads();
  }
  #pragma unroll
  for (int m=0;m<4;m++){
    int r=i0+ty*4+m;
    #pragma unroll
    for (int n=0;n<4;n++){
      int c=j0+tx*4+n;
      float v=acc[m][n];
      if (bias) v += bias[c];
      if (act) v = gelu_f(v);
      if (res) v += res[(size_t)r*N+c];
      C[(size_t)r*N+c]=v;
    }
  }
}

// ---------------- graph conv: x1 = x + adjn @ xp (per b,h) ----------------
__global__ __launch_bounds__(256) void gc_gemm_kernel(const float* __restrict__ adj,
                                                      const float* __restrict__ xp,
                                                      const float* __restrict__ x,
                                                      float* __restrict__ x1){
  __shared__ float As[64][65], Bs[64][65];
  int z = blockIdx.z; int b = z>>3, h = z&7;
  const float* A  = adj + (size_t)z*L_SEQ*L_SEQ;
  const float* Bp = xp + ((size_t)b*L_SEQ)*DMODEL + h*64;
  const float* Rp = x  + ((size_t)b*L_SEQ)*DMODEL + h*64;
  float* Cp = x1 + ((size_t)b*L_SEQ)*DMODEL + h*64;
  int i0 = blockIdx.x*64;
  int t=threadIdx.x, tx=t&15, ty=t>>4;
  float acc[4][4]={};
  for (int k0=0;k0<L_SEQ;k0+=64){
    #pragma unroll
    for (int i=0;i<16;i++){
      int lin=i*256+t, r=lin>>6, c=lin&63;
      As[r][c]=A[(size_t)(i0+r)*L_SEQ + k0+c];
      Bs[r][c]=Bp[(size_t)(k0+r)*DMODEL + c];
    }
    __syncthreads();
    #pragma unroll
    for (int kk=0;kk<64;kk++){
      float a[4], bv[4];
      #pragma unroll
      for(int m=0;m<4;m++) a[m]=As[ty*4+m][kk];
      #pragma unroll
      for(int n=0;n<4;n++) bv[n]=Bs[kk][tx*4+n];
      #pragma unroll
      for(int m=0;m<4;m++)
        #pragma unroll
        for(int n=0;n<4;n++) acc[m][n]+=a[m]*bv[n];
    }
    __syncthreads();
  }
  #pragma unroll
  for (int m=0;m<4;m++){
    int r=i0+ty*4+m;
    #pragma unroll
    for (int n=0;n<4;n++){
      int c=tx*4+n;
      Cp[(size_t)r*DMODEL+c] = acc[m][n] + Rp[(size_t)r*DMODEL+c];
    }
  }
}

// ---------------- loss finalize ----------------
__global__ __launch_bounds__(256) void loss_kernel(const float* __restrict__ spz,
                                                   const float* __restrict__ entp,
                                                   float* __restrict__ out){
  int t = threadIdx.x;
  float sum=0.f;
  for (int i=t;i<4224;i+=256) sum += spz[i];
  sum = block_reduce_sum(sum);
  float mu = sum/4224.f;
  float ss=0.f;
  for (int i=t;i<4224;i+=256){ float d=spz[i]-mu; ss+=d*d; }
  ss = block_reduce_sum(ss);
  float ent = block_reduce_sum(entp[t]);
  if (t==0){
    float var = ss/4223.f;
    float li = var/(mu*mu+1e-10f);
    float ld = -ent/48.f;
    out[0] = li + 0.1f*ld;
  }
}

extern "C" void kernel_launch(void* const* d_in, const int* in_sizes, int n_in,
                              void* d_out, int out_size, void* d_ws, size_t ws_size,
                              hipStream_t stream) {
  const float* x     = (const float*)d_in[0];
  const float* masks = (const float*)d_in[1];
  const float* ln1_g = (const float*)d_in[2];
  const float* ln1_b = (const float*)d_in[3];
  const float* w_p1  = (const float*)d_in[4];
  const float* b_p1  = (const float*)d_in[5];
  const float* w_p2  = (const float*)d_in[6];
  const float* b_p2  = (const float*)d_in[7];
  const float* w_gate= (const float*)d_in[8];
  const float* w_gcn = (const float*)d_in[9];
  const float* b_gcn = (const float*)d_in[10];
  const float* ln2_g = (const float*)d_in[11];
  const float* ln2_b = (const float*)d_in[12];
  const float* w_f1  = (const float*)d_in[13];
  const float* b_f1  = (const float*)d_in[14];
  const float* w_f2  = (const float*)d_in[15];
  const float* b_f2  = (const float*)d_in[16];
  float* out = (float*)d_out;

  char* wsb = (char*)d_ws;
  size_t adjB = (size_t)BH*L_SEQ*L_SEQ*sizeof(float);   // 126.9 MB
  size_t rB   = (size_t)ROWS*DMODEL*sizeof(float);      // 5.77 MB
  float* adj = (float*)wsb;                  // also reused as ffh after graph conv
  float* regB = (float*)(wsb + adjB);        // xn, then x1
  float* regC = (float*)(wsb + adjB + rB);   // q,  then xn2
  float* regD = (float*)(wsb + adjB + 2*rB); // k,  then xp
  float* spz  = (float*)(wsb + adjB + 3*rB); // 4224 floats
  float* entp = spz + 4224;                  // 256 floats

  float* xn  = regB;
  float* q   = regC;
  float* k   = regD;
  float* xp  = regD;
  float* x1  = regB;
  float* xn2 = regC;
  float* ffh = adj;

  hipMemsetAsync(spz, 0, (4224+256)*sizeof(float), stream);

  // 1. LN1
  ln_kernel<<<ROWS, 256, 0, stream>>>(x, ln1_g, ln1_b, xn);
  // 2. Q/K projections
  qk_proj_kernel<<<ROWS/8, 512, 0, stream>>>(xn, w_p1, b_p1, w_p2, b_p2, q, k);
  // 3. adj = gelu(Q K^T)
  qkt_gelu_kernel<<<dim3(22,22,BH), 256, 0, stream>>>(q, k, adj);
  // 4. per-row pipeline (topk, gating, losses, final softmax) -> adj overwritten with adjn
  row_pipe_kernel<<<dim3(L_SEQ,BH), 256, 0, stream>>>(adj, w_gate, masks, spz, entp);
  // 5. xp = xn @ w_gcn + b_gcn
  gemm_nn_kernel<<<dim3(44,8), 256, 0, stream>>>(xn, w_gcn, xp, b_gcn, nullptr, DMODEL, DMODEL, 0);
  // 6. x1 = x + adjn @ xp
  gc_gemm_kernel<<<dim3(22,1,BH), 256, 0, stream>>>(adj, xp, x, x1);
  // 7. LN2
  ln_kernel<<<ROWS, 256, 0, stream>>>(x1, ln2_g, ln2_b, xn2);
  // 8. ffh = gelu(xn2 @ w_f1 + b_f1)
  gemm_nn_kernel<<<dim3(44,32), 256, 0, stream>>>(xn2, w_f1, ffh, b_f1, nullptr, DFF, DMODEL, 1);
  // 9. out = x1 + ffh @ w_f2 + b_f2
  gemm_nn_kernel<<<dim3(44,8), 256, 0, stream>>>(ffh, w_f2, out, b_f2, x1, DMODEL, DFF, 0);
  // 10. loss
  loss_kernel<<<1, 256, 0, stream>>>(spz, entp, out + (size_t)ROWS*DMODEL);
}

// Round 2
// 491.786 us; speedup vs baseline: 2.3548x; 2.3548x over previous
//
#include <hip/hip_runtime.h>

#define L_SEQ 1408
#define DMODEL 512
#define NH 8
#define BATCH 2
#define BH 16
#define ROWS 2816
#define DFF 2048
#define KSEL 704

typedef unsigned short u16;
typedef short s8v __attribute__((ext_vector_type(8)));
typedef float f4v __attribute__((ext_vector_type(4)));

__device__ __forceinline__ float gelu_f(float x){
  return 0.5f*x*(1.0f+erff(x*0.70710678118654752440f));
}
__device__ __forceinline__ u16 f2bf(float f){
  unsigned u = __float_as_uint(f);
  u += 0x7fffu + ((u>>16)&1u);
  return (u16)(u>>16);
}
__device__ __forceinline__ float b2f(u16 h){ return __uint_as_float(((unsigned)h)<<16); }

__device__ __forceinline__ f4v MFMA(s8v a, s8v b, f4v c){
  return __builtin_amdgcn_mfma_f32_16x16x32_bf16(a, b, c, 0, 0, 0);
}

// all LDS tiles have 128-byte rows (64 bf16); XOR swizzle spreads banks
__device__ __forceinline__ s8v ldfrag(const u16* lds, int row, int kb /*bf16 index*/){
  return *(const s8v*)((const char*)lds + row*128 + ((kb*2) ^ ((row&7)<<4)));
}
__device__ __forceinline__ void stage_tile(const char* g, size_t gstride, u16* lds, int nrows, int t){
  int nch = nrows*8;
  for (int ci = t; ci < nch; ci += 256){
    int row = ci>>3, kc = (ci&7)*16;
    uint4 v = *(const uint4*)(g + (size_t)row*gstride + kc);
    *(uint4*)((char*)lds + row*128 + (kc ^ ((row&7)<<4))) = v;
  }
}

__device__ __forceinline__ float block_reduce_sum(float v){
  __shared__ float sred[8];
  int lane = threadIdx.x & 63, w = threadIdx.x >> 6;
  #pragma unroll
  for (int o=32;o>0;o>>=1) v += __shfl_down(v,o,64);
  if (lane==0) sred[w]=v;
  __syncthreads();
  if (w==0){
    float x = (lane < (int)(blockDim.x>>6)) ? sred[lane] : 0.f;
    #pragma unroll
    for (int o=4;o>0;o>>=1) x += __shfl_down(x,o,64);
    if (lane==0) sred[0]=x;
  }
  __syncthreads();
  float r = sred[0];
  __syncthreads();
  return r;
}
__device__ __forceinline__ float block_reduce_max(float v){
  __shared__ float sredm[8];
  int lane = threadIdx.x & 63, w = threadIdx.x >> 6;
  #pragma unroll
  for (int o=32;o>0;o>>=1) v = fmaxf(v, __shfl_down(v,o,64));
  if (lane==0) sredm[w]=v;
  __syncthreads();
  if (w==0){
    float x = (lane < (int)(blockDim.x>>6)) ? sredm[lane] : -3.0e38f;
    #pragma unroll
    for (int o=4;o>0;o>>=1) x = fmaxf(x, __shfl_down(x,o,64));
    if (lane==0) sredm[0]=x;
  }
  __syncthreads();
  float r = sredm[0];
  __syncthreads();
  return r;
}
// inclusive 256-scan: shfl within wave, cross-wave via shared
__device__ __forceinline__ unsigned scan256(unsigned v, int t, unsigned* woff){
  int lane = t&63, w = t>>6;
  unsigned sv = v, u;
  u=__shfl_up(sv,1,64);  if(lane>=1)  sv+=u;
  u=__shfl_up(sv,2,64);  if(lane>=2)  sv+=u;
  u=__shfl_up(sv,4,64);  if(lane>=4)  sv+=u;
  u=__shfl_up(sv,8,64);  if(lane>=8)  sv+=u;
  u=__shfl_up(sv,16,64); if(lane>=16) sv+=u;
  u=__shfl_up(sv,32,64); if(lane>=32) sv+=u;
  if (lane==63) woff[w]=sv;
  __syncthreads();
  if (t==0){ unsigned a=0; for(int i=0;i<4;i++){ unsigned tm=woff[i]; woff[i]=a; a+=tm; } }
  __syncthreads();
  return sv + woff[w];
}

// ---------------- LayerNorm f32 -> bf16 ----------------
__global__ __launch_bounds__(256) void ln_kernel(const float* __restrict__ x,
                                                 const float* __restrict__ g,
                                                 const float* __restrict__ b,
                                                 u16* __restrict__ out){
  int row = blockIdx.x;
  const float* xr = x + (size_t)row*DMODEL;
  int t = threadIdx.x;
  float v0 = xr[t], v1 = xr[t+256];
  float s = block_reduce_sum(v0+v1);
  float mean = s * (1.f/512.f);
  float d0 = v0-mean, d1 = v1-mean;
  float ss = block_reduce_sum(d0*d0 + d1*d1);
  float rstd = rsqrtf(ss*(1.f/512.f) + 1e-5f);
  u16* orow = out + (size_t)row*DMODEL;
  orow[t]     = f2bf(d0*rstd*g[t]     + b[t]);
  orow[t+256] = f2bf(d1*rstd*g[t+256] + b[t+256]);
}

// ---------------- transpose-cast f32 [K][N] -> bf16 [N][K] ----------------
__global__ __launch_bounds__(256) void castT_kernel(const float* __restrict__ in,
                                                    u16* __restrict__ outT, int K, int N){
  __shared__ u16 tl[32][33];
  int k0 = blockIdx.x*32, n0 = blockIdx.y*32;
  int t = threadIdx.x, r = t>>5, c = t&31;
  #pragma unroll
  for (int i=0;i<4;i++){
    int rr = r + i*8;
    tl[rr][c] = f2bf(in[(size_t)(k0+rr)*N + n0 + c]);
  }
  __syncthreads();
  #pragma unroll
  for (int i=0;i<4;i++){
    int rr = r + i*8;
    outT[(size_t)(n0+rr)*K + k0 + c] = tl[c][rr];
  }
}

// ---------------- Q/K projections (bf16 in/out, f32 math) ----------------
__global__ __launch_bounds__(512) void qk_proj_kernel(const u16* __restrict__ xn,
                                                      const float* __restrict__ w1, const float* __restrict__ bp1,
                                                      const float* __restrict__ w2, const float* __restrict__ bp2,
                                                      u16* __restrict__ q, u16* __restrict__ k){
  __shared__ float sw1[64*64], sw2[64*64], xr[512];
  int t = threadIdx.x;
  #pragma unroll
  for (int i=0;i<8;i++){ sw1[i*512+t]=w1[i*512+t]; sw2[i*512+t]=w2[i*512+t]; }
  int rowbase = blockIdx.x*8;
  int h = t>>6, j = t&63;
  float bb1 = bp1[j], bb2 = bp2[j];
  for (int r=0;r<8;r++){
    int row = rowbase + r;
    __syncthreads();
    xr[t] = b2f(xn[(size_t)row*DMODEL + t]);
    __syncthreads();
    float a1=bb1, a2=bb2;
    const float* xv = &xr[h*64];
    #pragma unroll
    for (int kk=0;kk<64;kk++){
      float xvk = xv[kk];
      a1 += xvk*sw1[kk*64+j];
      a2 += xvk*sw2[kk*64+j];
    }
    int b_ = row / L_SEQ, l = row % L_SEQ;
    size_t o = (((size_t)(b_*NH+h))*L_SEQ + l)*64 + j;
    q[o]=f2bf(a1); k[o]=f2bf(a2);
  }
}

// ---------------- adj = gelu(Q K^T), bf16, MFMA, 128x128 tile ----------------
__global__ __launch_bounds__(256) void qkt_mfma_kernel(const u16* __restrict__ q,
                                                       const u16* __restrict__ k,
                                                       u16* __restrict__ adj){
  __shared__ u16 Qs[128*64], Ks[128*64];
  int z = blockIdx.z;
  int i0 = blockIdx.x*128, j0 = blockIdx.y*128;
  int t = threadIdx.x;
  const char* Qb = (const char*)(q + (size_t)z*L_SEQ*64) + (size_t)i0*128;
  const char* Kb = (const char*)(k + (size_t)z*L_SEQ*64) + (size_t)j0*128;
  stage_tile(Qb, 128, Qs, 128, t);
  stage_tile(Kb, 128, Ks, 128, t);
  __syncthreads();
  int lane = t&63, w = t>>6, wm = w>>1, wn = w&1;
  int fr = lane&15, kb = (lane>>4)*8;
  f4v acc[4][4];
  #pragma unroll
  for (int m=0;m<4;m++)
    #pragma unroll
    for (int n=0;n<4;n++) acc[m][n]=(f4v){0.f,0.f,0.f,0.f};
  #pragma unroll
  for (int kk=0;kk<2;kk++){
    s8v a[4], bv[4];
    #pragma unroll
    for (int m=0;m<4;m++) a[m] = ldfrag(Qs, wm*64+m*16+fr, kk*32+kb);
    #pragma unroll
    for (int n=0;n<4;n++) bv[n] = ldfrag(Ks, wn*64+n*16+fr, kk*32+kb);
    #pragma unroll
    for (int m=0;m<4;m++)
      #pragma unroll
      for (int n=0;n<4;n++) acc[m][n] = MFMA(a[m], bv[n], acc[m][n]);
  }
  u16* Cb = adj + (size_t)z*L_SEQ*L_SEQ;
  #pragma unroll
  for (int m=0;m<4;m++){
    int row = i0 + wm*64 + m*16 + (lane>>4)*4;
    #pragma unroll
    for (int n=0;n<4;n++){
      int col = j0 + wn*64 + n*16 + fr;
      #pragma unroll
      for (int r=0;r<4;r++)
        Cb[(size_t)(row+r)*L_SEQ + col] = f2bf(gelu_f(acc[m][n][r]));
    }
  }
}

// ---------------- generic MFMA GEMM: C = f(A@B + bias) [+res] ----------------
// A [M][K] bf16, BT [N][K] bf16 (B transposed)
template<int OUTBF16,int ACT,int RES,int TRANSOUT>
__global__ __launch_bounds__(256) void gemm_mfma_kernel(const u16* __restrict__ A,
                                                        const u16* __restrict__ BT,
                                                        const float* __restrict__ bias,
                                                        const float* __restrict__ res,
                                                        void* __restrict__ outp,
                                                        int M, int N, int K){
  __shared__ u16 As[128*64], Bs[128*64];
  int i0 = blockIdx.x*128, j0 = blockIdx.y*128;
  int t = threadIdx.x, lane=t&63, w=t>>6, wm=w>>1, wn=w&1;
  int fr=lane&15, kb=(lane>>4)*8;
  f4v acc[4][4];
  #pragma unroll
  for (int m=0;m<4;m++)
    #pragma unroll
    for (int n=0;n<4;n++) acc[m][n]=(f4v){0.f,0.f,0.f,0.f};
  size_t strA=(size_t)K*2;
  const char* Ab = (const char*)A + (size_t)i0*strA;
  const char* Bb = (const char*)BT + (size_t)j0*strA;
  for (int k0=0;k0<K;k0+=64){
    stage_tile(Ab + (size_t)k0*2, strA, As, 128, t);
    stage_tile(Bb + (size_t)k0*2, strA, Bs, 128, t);
    __syncthreads();
    #pragma unroll
    for (int kk=0;kk<2;kk++){
      s8v a[4], bv[4];
      #pragma unroll
      for (int m=0;m<4;m++) a[m]=ldfrag(As, wm*64+m*16+fr, kk*32+kb);
      #pragma unroll
      for (int n=0;n<4;n++) bv[n]=ldfrag(Bs, wn*64+n*16+fr, kk*32+kb);
      #pragma unroll
      for (int m=0;m<4;m++)
        #pragma unroll
        for (int n=0;n<4;n++) acc[m][n]=MFMA(a[m],bv[n],acc[m][n]);
    }
    __syncthreads();
  }
  #pragma unroll
  for (int m=0;m<4;m++){
    int row = i0 + wm*64+m*16+(lane>>4)*4;
    #pragma unroll
    for (int n=0;n<4;n++){
      int col = j0 + wn*64+n*16+fr;
      float bb = bias[col];
      #pragma unroll
      for (int r=0;r<4;r++){
        float v = acc[m][n][r]+bb;
        if (ACT) v = gelu_f(v);
        if (RES) v += res[(size_t)(row+r)*N+col];
        if (TRANSOUT) ((u16*)outp)[(size_t)col*M + row + r] = f2bf(v);
        else if (OUTBF16) ((u16*)outp)[(size_t)(row+r)*N+col] = f2bf(v);
        else ((float*)outp)[(size_t)(row+r)*N+col] = v;
      }
    }
  }
}

// ---------------- graph conv: x1 = x + adjn @ xp  (per z=(b,h)) ----------------
__global__ __launch_bounds__(256) void gc_mfma_kernel(const u16* __restrict__ adj,
                                                      const u16* __restrict__ xpt,
                                                      const float* __restrict__ x,
                                                      float* __restrict__ x1){
  __shared__ u16 As[128*64], Bs[64*64];
  int z = blockIdx.z, b = z>>3, h = z&7;
  int i0 = blockIdx.x*128;
  int t = threadIdx.x, lane=t&63, w=t>>6, wm=w>>1, wn=w&1;
  int fr=lane&15, kb=(lane>>4)*8;
  const char* Ab = (const char*)(adj + (size_t)z*L_SEQ*L_SEQ) + (size_t)i0*2816;
  const char* Bb = (const char*)xpt + (size_t)(h*64)*5632 + (size_t)(b*L_SEQ)*2;
  f4v acc[4][2];
  #pragma unroll
  for (int m=0;m<4;m++){ acc[m][0]=(f4v){0.f,0.f,0.f,0.f}; acc[m][1]=(f4v){0.f,0.f,0.f,0.f}; }
  for (int k0=0;k0<L_SEQ;k0+=64){
    stage_tile(Ab + (size_t)k0*2, 2816, As, 128, t);
    stage_tile(Bb + (size_t)k0*2, 5632, Bs, 64, t);
    __syncthreads();
    #pragma unroll
    for (int kk=0;kk<2;kk++){
      s8v a[4], bv[2];
      #pragma unroll
      for (int m=0;m<4;m++) a[m]=ldfrag(As, wm*64+m*16+fr, kk*32+kb);
      #pragma unroll
      for (int n=0;n<2;n++) bv[n]=ldfrag(Bs, wn*32+n*16+fr, kk*32+kb);
      #pragma unroll
      for (int m=0;m<4;m++)
        #pragma unroll
        for (int n=0;n<2;n++) acc[m][n]=MFMA(a[m],bv[n],acc[m][n]);
    }
    __syncthreads();
  }
  #pragma unroll
  for (int m=0;m<4;m++){
    int rl = i0 + wm*64+m*16+(lane>>4)*4;
    #pragma unroll
    for (int n=0;n<2;n++){
      int col = h*64 + wn*32+n*16+fr;
      #pragma unroll
      for (int r=0;r<4;r++){
        size_t gi = (size_t)(b*L_SEQ + rl + r)*DMODEL + col;
        x1[gi] = acc[m][n][r] + x[gi];
      }
    }
  }
}

// ---------------- per-row: top-k, gating, losses, final softmax (bf16) ----------------
__global__ __launch_bounds__(256) void row_pipe_kernel(u16* __restrict__ adj,
                                                       const float* __restrict__ wg,
                                                       const float* __restrict__ masks,
                                                       float* __restrict__ spz,
                                                       float* __restrict__ entp){
  __shared__ float s[L_SEQ];
  __shared__ u16 kys[L_SEQ];
  __shared__ unsigned hist[256];
  __shared__ unsigned woff[4];
  __shared__ unsigned selv, selbase;
  int l = blockIdx.x, z = blockIdx.y;
  u16* row = adj + ((size_t)z*L_SEQ + l)*L_SEQ;
  int t = threadIdx.x, lane = t&63, w = t>>6;
  for (int d=t; d<L_SEQ; d+=256){
    u16 h = row[d];
    kys[d] = (h & 0x8000u) ? (u16)(~h) : (u16)(h | 0x8000u);
    s[d] = b2f(h);
  }
  __syncthreads();
  int rem = KSEL;
  unsigned sel_hi, thr;
  // pass 0: high byte
  hist[t]=0; __syncthreads();
  for (int d=t; d<L_SEQ; d+=256) atomicAdd(&hist[kys[d]>>8], 1u);
  __syncthreads();
  {
    unsigned v = hist[t];
    unsigned incl = scan256(v, t, woff);
    unsigned excl = incl - v;
    if ((int)excl < rem && rem <= (int)incl){ selv=(unsigned)t; selbase=excl; }
    __syncthreads();
    sel_hi = selv; rem -= (int)selbase;
    __syncthreads();
  }
  // pass 1: low byte within selected high byte
  hist[t]=0; __syncthreads();
  for (int d=t; d<L_SEQ; d+=256){
    unsigned ky = kys[d];
    if ((ky>>8)==sel_hi) atomicAdd(&hist[ky&255u], 1u);
  }
  __syncthreads();
  {
    unsigned v = hist[t];
    unsigned incl = scan256(v, t, woff);
    unsigned excl = incl - v;
    if ((int)excl < rem && rem <= (int)incl){ selv=(unsigned)t; selbase=excl; }
    __syncthreads();
    thr = (sel_hi<<8) | selv; rem -= (int)selbase;
    __syncthreads();
  }
  int z_eq = rem;  // # entries equal to thr to zero, lowest index first
  if (w==0){
    int cnt = 0;
    for (int c=0; c<22 && cnt < z_eq; c++){
      int d = c*64 + lane;
      bool eq = (kys[d] == (u16)thr);
      unsigned long long mb = __ballot(eq);
      int pre = __popcll(mb & ((1ull<<lane)-1ull));
      if (eq && (cnt + pre) < z_eq) s[d] = 0.f;
      cnt += __popcll(mb);
    }
  }
  __syncthreads();
  for (int d=t; d<L_SEQ; d+=256) if (kys[d] < (u16)thr) s[d] = 0.f;
  __syncthreads();

  // gating
  float p0=0.f, p1v=0.f, p2v=0.f;
  for (int d=t; d<L_SEQ; d+=256){
    float a = s[d];
    p0  += a*wg[d*3+0];
    p1v += a*wg[d*3+1];
    p2v += a*wg[d*3+2];
  }
  p0  = block_reduce_sum(p0);
  p1v = block_reduce_sum(p1v);
  p2v = block_reduce_sum(p2v);
  float mx = fmaxf(p0, fmaxf(p1v,p2v));
  float e0=expf(p0-mx), e1=expf(p1v-mx), e2=expf(p2v-mx);
  float inv = 1.f/(e0+e1+e2);
  float pr[3]={e0*inv, e1*inv, e2*inv};
  int i0=0; if (pr[1]>pr[i0]) i0=1; if (pr[2]>pr[i0]) i0=2;
  int a_=(i0==0)?1:0, b_=(i0==2)?1:2;
  int i1 = (pr[b_]>pr[a_])?b_:a_;
  bool top2 = !(pr[i0] > 0.5f);
  float g0=(i0==0)||(top2&&i1==0)?1.f:0.f;
  float g1=(i0==1)||(top2&&i1==1)?1.f:0.f;
  float g2=(i0==2)||(top2&&i1==2)?1.f:0.f;
  if (t==0){
    float ent = pr[0]*logf(pr[0]+1e-10f)+pr[1]*logf(pr[1]+1e-10f)+pr[2]*logf(pr[2]+1e-10f);
    atomicAdd(&entp[(z*L_SEQ+l) & 255], ent);
    atomicAdd(&spz[l*3+0], pr[i0]);
    if (top2) atomicAdd(&spz[l*3+1], pr[i1]);
  }

  // final mask + softmax, write bf16
  const float* m0 = masks + ((size_t)l*3+0)*L_SEQ;
  const float* m1 = m0 + L_SEQ;
  const float* m2 = m1 + L_SEQ;
  float lmax = -3.0e38f;
  for (int d=t; d<L_SEQ; d+=256){
    float fm = (d==l) ? 1.f : 0.f;
    if (g0!=0.f) fm += m0[d];
    if (g1!=0.f) fm += m1[d];
    if (g2!=0.f) fm += m2[d];
    float v = s[d]*fm;
    s[d] = v;
    lmax = fmaxf(lmax, v);
  }
  __syncthreads();
  lmax = block_reduce_max(lmax);
  float lsum = 0.f;
  for (int d=t; d<L_SEQ; d+=256){
    float e = expf(s[d]-lmax); s[d]=e; lsum += e;
  }
  lsum = block_reduce_sum(lsum);
  float invs = 1.f/lsum;
  for (int d=t; d<L_SEQ; d+=256) row[d] = f2bf(s[d]*invs);
}

// ---------------- loss finalize ----------------
__global__ __launch_bounds__(256) void loss_kernel(const float* __restrict__ spz,
                                                   const float* __restrict__ entp,
                                                   float* __restrict__ out){
  int t = threadIdx.x;
  float sum=0.f;
  for (int i=t;i<4224;i+=256) sum += spz[i];
  sum = block_reduce_sum(sum);
  float mu = sum/4224.f;
  float ss=0.f;
  for (int i=t;i<4224;i+=256){ float d=spz[i]-mu; ss+=d*d; }
  ss = block_reduce_sum(ss);
  float ent = block_reduce_sum(entp[t]);
  if (t==0){
    float var = ss/4223.f;
    float li = var/(mu*mu+1e-10f);
    float ld = -ent/48.f;
    out[0] = li + 0.1f*ld;
  }
}

extern "C" void kernel_launch(void* const* d_in, const int* in_sizes, int n_in,
                              void* d_out, int out_size, void* d_ws, size_t ws_size,
                              hipStream_t stream) {
  const float* x     = (const float*)d_in[0];
  const float* masks = (const float*)d_in[1];
  const float* ln1_g = (const float*)d_in[2];
  const float* ln1_b = (const float*)d_in[3];
  const float* w_p1  = (const float*)d_in[4];
  const float* b_p1  = (const float*)d_in[5];
  const float* w_p2  = (const float*)d_in[6];
  const float* b_p2  = (const float*)d_in[7];
  const float* w_gate= (const float*)d_in[8];
  const float* w_gcn = (const float*)d_in[9];
  const float* b_gcn = (const float*)d_in[10];
  const float* ln2_g = (const float*)d_in[11];
  const float* ln2_b = (const float*)d_in[12];
  const float* w_f1  = (const float*)d_in[13];
  const float* b_f1  = (const float*)d_in[14];
  const float* w_f2  = (const float*)d_in[15];
  const float* b_f2  = (const float*)d_in[16];
  float* out = (float*)d_out;

  char* wsb = (char*)d_ws;
  size_t off = 0;
  u16* adj   = (u16*)(wsb+off); off += (size_t)BH*L_SEQ*L_SEQ*2;  // 63.4 MB
  u16* xn    = (u16*)(wsb+off); off += (size_t)ROWS*DMODEL*2;
  u16* q     = (u16*)(wsb+off); off += (size_t)BH*L_SEQ*64*2;
  u16* kk    = (u16*)(wsb+off); off += (size_t)BH*L_SEQ*64*2;
  u16* xpt   = (u16*)(wsb+off); off += (size_t)DMODEL*ROWS*2;     // transposed [512][2816]
  u16* xn2   = (u16*)(wsb+off); off += (size_t)ROWS*DMODEL*2;
  float* x1  = (float*)(wsb+off); off += (size_t)ROWS*DMODEL*4;
  u16* wgcnT = (u16*)(wsb+off); off += (size_t)DMODEL*DMODEL*2;
  u16* wf1T  = (u16*)(wsb+off); off += (size_t)DFF*DMODEL*2;
  u16* wf2T  = (u16*)(wsb+off); off += (size_t)DMODEL*DFF*2;
  float* spz = (float*)(wsb+off); off += 4224*4;
  float* entp= (float*)(wsb+off); off += 256*4;
  u16* ffh   = adj;   // reuse after graph conv

  hipMemsetAsync(spz, 0, (4224+256)*sizeof(float), stream);

  // weight transpose-casts
  castT_kernel<<<dim3(16,16), 256, 0, stream>>>(w_gcn, wgcnT, DMODEL, DMODEL);
  castT_kernel<<<dim3(16,64), 256, 0, stream>>>(w_f1,  wf1T,  DMODEL, DFF);
  castT_kernel<<<dim3(64,16), 256, 0, stream>>>(w_f2,  wf2T,  DFF,    DMODEL);

  // 1. LN1 -> xn (bf16)
  ln_kernel<<<ROWS, 256, 0, stream>>>(x, ln1_g, ln1_b, xn);
  // 2. Q/K projections (bf16)
  qk_proj_kernel<<<ROWS/8, 512, 0, stream>>>(xn, w_p1, b_p1, w_p2, b_p2, q, kk);
  // 3. adj = gelu(Q K^T) bf16 via MFMA
  qkt_mfma_kernel<<<dim3(11,11,BH), 256, 0, stream>>>(q, kk, adj);
  // 4. per-row pipeline
  row_pipe_kernel<<<dim3(L_SEQ,BH), 256, 0, stream>>>(adj, w_gate, masks, spz, entp);
  // 5. xp^T = (xn @ w_gcn + b_gcn)^T  (bf16, transposed out)
  gemm_mfma_kernel<0,0,0,1><<<dim3(22,4), 256, 0, stream>>>(xn, wgcnT, b_gcn, nullptr, xpt, ROWS, DMODEL, DMODEL);
  // 6. x1 = x + adjn @ xp   (f32)
  gc_mfma_kernel<<<dim3(11,1,BH), 256, 0, stream>>>(adj, xpt, x, x1);
  // 7. LN2 -> xn2 (bf16)
  ln_kernel<<<ROWS, 256, 0, stream>>>(x1, ln2_g, ln2_b, xn2);
  // 8. ffh = gelu(xn2 @ w_f1 + b_f1)  (bf16)
  gemm_mfma_kernel<1,1,0,0><<<dim3(22,16), 256, 0, stream>>>(xn2, wf1T, b_f1, nullptr, ffh, ROWS, DFF, DMODEL);
  // 9. out = x1 + ffh @ w_f2 + b_f2   (f32)
  gemm_mfma_kernel<0,0,1,0><<<dim3(22,4), 256, 0, stream>>>(ffh, wf2T, b_f2, x1, out, ROWS, DMODEL, DFF);
  // 10. loss
  loss_kernel<<<1, 256, 0, stream>>>(spz, entp, out + (size_t)ROWS*DMODEL);
}

// Round 4
// 326.101 us; speedup vs baseline: 3.5513x; 1.5081x over previous
//
#include <hip/hip_runtime.h>

#define L_SEQ 1408
#define DMODEL 512
#define NH 8
#define BATCH 2
#define BH 16
#define ROWS 2816
#define DFF 2048
#define KSEL 704

typedef unsigned short u16;
typedef short s8v __attribute__((ext_vector_type(8)));
typedef float f4v __attribute__((ext_vector_type(4)));

__device__ __forceinline__ float gelu_f(float x){
  return 0.5f*x*(1.0f+erff(x*0.70710678118654752440f));
}
__device__ __forceinline__ u16 f2bf(float f){
  unsigned u = __float_as_uint(f);
  u += 0x7fffu + ((u>>16)&1u);
  return (u16)(u>>16);
}
__device__ __forceinline__ float b2f(unsigned h){ return __uint_as_float(h<<16); }
__device__ __forceinline__ unsigned key16(unsigned h){
  return (h & 0x8000u) ? (0xFFFFu & ~h) : (h | 0x8000u);
}

__device__ __forceinline__ f4v MFMA(s8v a, s8v b, f4v c){
  return __builtin_amdgcn_mfma_f32_16x16x32_bf16(a, b, c, 0, 0, 0);
}

// all LDS tiles have 128-byte rows (64 bf16); XOR swizzle spreads banks
__device__ __forceinline__ s8v ldfrag(const u16* lds, int row, int kb){
  return *(const s8v*)((const char*)lds + row*128 + ((kb*2) ^ ((row&7)<<4)));
}
__device__ __forceinline__ void stage_tile(const char* g, size_t gstride, u16* lds, int nrows, int t){
  int nch = nrows*8;
  for (int ci = t; ci < nch; ci += 256){
    int row = ci>>3, kc = (ci&7)*16;
    uint4 v = *(const uint4*)(g + (size_t)row*gstride + kc);
    *(uint4*)((char*)lds + row*128 + (kc ^ ((row&7)<<4))) = v;
  }
}

__device__ __forceinline__ float block_reduce_sum(float v){
  __shared__ float sred[8];
  int lane = threadIdx.x & 63, w = threadIdx.x >> 6;
  #pragma unroll
  for (int o=32;o>0;o>>=1) v += __shfl_down(v,o,64);
  if (lane==0) sred[w]=v;
  __syncthreads();
  if (w==0){
    float x = (lane < (int)(blockDim.x>>6)) ? sred[lane] : 0.f;
    #pragma unroll
    for (int o=4;o>0;o>>=1) x += __shfl_down(x,o,64);
    if (lane==0) sred[0]=x;
  }
  __syncthreads();
  float r = sred[0];
  __syncthreads();
  return r;
}

// ---------------- LayerNorm f32 -> bf16 ----------------
__global__ __launch_bounds__(256) void ln_kernel(const float* __restrict__ x,
                                                 const float* __restrict__ g,
                                                 const float* __restrict__ b,
                                                 u16* __restrict__ out){
  int row = blockIdx.x;
  const float* xr = x + (size_t)row*DMODEL;
  int t = threadIdx.x;
  float v0 = xr[t], v1 = xr[t+256];
  float s = block_reduce_sum(v0+v1);
  float mean = s * (1.f/512.f);
  float d0 = v0-mean, d1 = v1-mean;
  float ss = block_reduce_sum(d0*d0 + d1*d1);
  float rstd = rsqrtf(ss*(1.f/512.f) + 1e-5f);
  u16* orow = out + (size_t)row*DMODEL;
  orow[t]     = f2bf(d0*rstd*g[t]     + b[t]);
  orow[t+256] = f2bf(d1*rstd*g[t+256] + b[t+256]);
}

// ---------------- fused x1 = x+P0+P1 ; xn2 = LN(x1) ----------------
__global__ __launch_bounds__(256) void ln2_fuse_kernel(const float* __restrict__ x,
                                                       const float* __restrict__ P,
                                                       const float* __restrict__ g,
                                                       const float* __restrict__ b,
                                                       float* __restrict__ x1,
                                                       u16* __restrict__ xn2){
  int row = blockIdx.x, t = threadIdx.x;
  size_t base = (size_t)row*DMODEL;
  const float* P1 = P + (size_t)ROWS*DMODEL;
  float v0 = x[base+t]     + P[base+t]     + P1[base+t];
  float v1 = x[base+t+256] + P[base+t+256] + P1[base+t+256];
  x1[base+t] = v0; x1[base+t+256] = v1;
  float s = block_reduce_sum(v0+v1);
  float mean = s * (1.f/512.f);
  float d0 = v0-mean, d1 = v1-mean;
  float ss = block_reduce_sum(d0*d0 + d1*d1);
  float rstd = rsqrtf(ss*(1.f/512.f) + 1e-5f);
  xn2[base+t]     = f2bf(d0*rstd*g[t]     + b[t]);
  xn2[base+t+256] = f2bf(d1*rstd*g[t+256] + b[t+256]);
}

// ---------------- transpose-cast f32 [K][N] -> bf16 [N][K] ----------------
__global__ __launch_bounds__(256) void castT_kernel(const float* __restrict__ in,
                                                    u16* __restrict__ outT, int K, int N){
  __shared__ u16 tl[32][33];
  int k0 = blockIdx.x*32, n0 = blockIdx.y*32;
  int t = threadIdx.x, r = t>>5, c = t&31;
  #pragma unroll
  for (int i=0;i<4;i++){
    int rr = r + i*8;
    tl[rr][c] = f2bf(in[(size_t)(k0+rr)*N + n0 + c]);
  }
  __syncthreads();
  #pragma unroll
  for (int i=0;i<4;i++){
    int rr = r + i*8;
    outT[(size_t)(n0+rr)*K + k0 + c] = tl[c][rr];
  }
}

// ---------------- Q/K projections ----------------
__global__ __launch_bounds__(512) void qk_proj_kernel(const u16* __restrict__ xn,
                                                      const float* __restrict__ w1, const float* __restrict__ bp1,
                                                      const float* __restrict__ w2, const float* __restrict__ bp2,
                                                      u16* __restrict__ q, u16* __restrict__ k){
  __shared__ float sw1[64*64], sw2[64*64], xr[512];
  int t = threadIdx.x;
  #pragma unroll
  for (int i=0;i<8;i++){ sw1[i*512+t]=w1[i*512+t]; sw2[i*512+t]=w2[i*512+t]; }
  int rowbase = blockIdx.x*8;
  int h = t>>6, j = t&63;
  float bb1 = bp1[j], bb2 = bp2[j];
  for (int r=0;r<8;r++){
    int row = rowbase + r;
    __syncthreads();
    xr[t] = b2f(xn[(size_t)row*DMODEL + t]);
    __syncthreads();
    float a1=bb1, a2=bb2;
    const float* xv = &xr[h*64];
    #pragma unroll
    for (int kk=0;kk<64;kk++){
      float xvk = xv[kk];
      a1 += xvk*sw1[kk*64+j];
      a2 += xvk*sw2[kk*64+j];
    }
    int b_ = row / L_SEQ, l = row % L_SEQ;
    size_t o = (((size_t)(b_*NH+h))*L_SEQ + l)*64 + j;
    q[o]=f2bf(a1); k[o]=f2bf(a2);
  }
}

// ---------------- adj = gelu(Q K^T), LDS-staged coalesced store ----------------
__global__ __launch_bounds__(256) void qkt_mfma_kernel(const u16* __restrict__ q,
                                                       const u16* __restrict__ k,
                                                       u16* __restrict__ adj){
  __shared__ u16 sbuf[128*128];
  u16* Qs = sbuf; u16* Ks = sbuf + 128*64; u16* Cs = sbuf;
  int z = blockIdx.z;
  int i0 = blockIdx.x*128, j0 = blockIdx.y*128;
  int t = threadIdx.x;
  const char* Qb = (const char*)(q + (size_t)z*L_SEQ*64) + (size_t)i0*128;
  const char* Kb = (const char*)(k + (size_t)z*L_SEQ*64) + (size_t)j0*128;
  stage_tile(Qb, 128, Qs, 128, t);
  stage_tile(Kb, 128, Ks, 128, t);
  __syncthreads();
  int lane = t&63, w = t>>6, wm = w>>1, wn = w&1;
  int fr = lane&15, kb = (lane>>4)*8;
  f4v acc[4][4];
  #pragma unroll
  for (int m=0;m<4;m++)
    #pragma unroll
    for (int n=0;n<4;n++) acc[m][n]=(f4v){0.f,0.f,0.f,0.f};
  #pragma unroll
  for (int kk=0;kk<2;kk++){
    s8v a[4], bv[4];
    #pragma unroll
    for (int m=0;m<4;m++) a[m] = ldfrag(Qs, wm*64+m*16+fr, kk*32+kb);
    #pragma unroll
    for (int n=0;n<4;n++) bv[n] = ldfrag(Ks, wn*64+n*16+fr, kk*32+kb);
    #pragma unroll
    for (int m=0;m<4;m++)
      #pragma unroll
      for (int n=0;n<4;n++) acc[m][n] = MFMA(a[m], bv[n], acc[m][n]);
  }
  __syncthreads();
  #pragma unroll
  for (int m=0;m<4;m++){
    int row = wm*64 + m*16 + (lane>>4)*4;
    #pragma unroll
    for (int n=0;n<4;n++){
      int col = wn*64 + n*16 + fr;
      #pragma unroll
      for (int r=0;r<4;r++)
        Cs[(row+r)*128 + col] = f2bf(gelu_f(acc[m][n][r]));
    }
  }
  __syncthreads();
  u16* Cb = adj + (size_t)z*L_SEQ*L_SEQ;
  // C tile is 128 u16 wide = 16 uint4 chunks per row; 2048 chunks total
  #pragma unroll
  for (int i=0;i<8;i++){
    int idx = i*256 + t;
    int r = idx>>4, cc = (idx&15)*8;
    uint4 v = *(const uint4*)&Cs[r*128 + cc];
    *(uint4*)((char*)Cb + (size_t)(i0+r)*2816 + (j0+cc)*2) = v;
  }
}

// ---------------- generic MFMA GEMM: C = f(A@B + bias) ----------------
template<int OUTBF16,int ACT,int TRANSOUT>
__global__ __launch_bounds__(256) void gemm_mfma_kernel(const u16* __restrict__ A,
                                                        const u16* __restrict__ BT,
                                                        const float* __restrict__ bias,
                                                        void* __restrict__ outp,
                                                        int M, int N, int K){
  __shared__ u16 As[128*64], Bs[128*64];
  int i0 = blockIdx.x*128, j0 = blockIdx.y*128;
  int t = threadIdx.x, lane=t&63, w=t>>6, wm=w>>1, wn=w&1;
  int fr=lane&15, kb=(lane>>4)*8;
  f4v acc[4][4];
  #pragma unroll
  for (int m=0;m<4;m++)
    #pragma unroll
    for (int n=0;n<4;n++) acc[m][n]=(f4v){0.f,0.f,0.f,0.f};
  size_t strA=(size_t)K*2;
  const char* Ab = (const char*)A + (size_t)i0*strA;
  const char* Bb = (const char*)BT + (size_t)j0*strA;
  for (int k0=0;k0<K;k0+=64){
    stage_tile(Ab + (size_t)k0*2, strA, As, 128, t);
    stage_tile(Bb + (size_t)k0*2, strA, Bs, 128, t);
    __syncthreads();
    #pragma unroll
    for (int kk=0;kk<2;kk++){
      s8v a[4], bv[4];
      #pragma unroll
      for (int m=0;m<4;m++) a[m]=ldfrag(As, wm*64+m*16+fr, kk*32+kb);
      #pragma unroll
      for (int n=0;n<4;n++) bv[n]=ldfrag(Bs, wn*64+n*16+fr, kk*32+kb);
      #pragma unroll
      for (int m=0;m<4;m++)
        #pragma unroll
        for (int n=0;n<4;n++) acc[m][n]=MFMA(a[m],bv[n],acc[m][n]);
    }
    __syncthreads();
  }
  #pragma unroll
  for (int m=0;m<4;m++){
    int row = i0 + wm*64+m*16+(lane>>4)*4;
    #pragma unroll
    for (int n=0;n<4;n++){
      int col = j0 + wn*64+n*16+fr;
      float bb = bias[col];
      #pragma unroll
      for (int r=0;r<4;r++){
        float v = acc[m][n][r]+bb;
        if (ACT) v = gelu_f(v);
        if (TRANSOUT) ((u16*)outp)[(size_t)col*M + row + r] = f2bf(v);
        else if (OUTBF16) ((u16*)outp)[(size_t)(row+r)*N+col] = f2bf(v);
        else ((float*)outp)[(size_t)(row+r)*N+col] = v;
      }
    }
  }
}

// ---------------- split-K GEMM partial: P[z] = A@B over K slice ----------------
__global__ __launch_bounds__(256) void gemm_ks_kernel(const u16* __restrict__ A,
                                                      const u16* __restrict__ BT,
                                                      float* __restrict__ P,
                                                      int M, int N, int K, int KS){
  __shared__ u16 As[128*64], Bs[128*64];
  int i0 = blockIdx.x*128, j0 = blockIdx.y*128;
  int kbeg = blockIdx.z*KS;
  int t = threadIdx.x, lane=t&63, w=t>>6, wm=w>>1, wn=w&1;
  int fr=lane&15, kb=(lane>>4)*8;
  f4v acc[4][4];
  #pragma unroll
  for (int m=0;m<4;m++)
    #pragma unroll
    for (int n=0;n<4;n++) acc[m][n]=(f4v){0.f,0.f,0.f,0.f};
  size_t strA=(size_t)K*2;
  const char* Ab = (const char*)A + (size_t)i0*strA;
  const char* Bb = (const char*)BT + (size_t)j0*strA;
  for (int k0=kbeg; k0<kbeg+KS; k0+=64){
    stage_tile(Ab + (size_t)k0*2, strA, As, 128, t);
    stage_tile(Bb + (size_t)k0*2, strA, Bs, 128, t);
    __syncthreads();
    #pragma unroll
    for (int kk=0;kk<2;kk++){
      s8v a[4], bv[4];
      #pragma unroll
      for (int m=0;m<4;m++) a[m]=ldfrag(As, wm*64+m*16+fr, kk*32+kb);
      #pragma unroll
      for (int n=0;n<4;n++) bv[n]=ldfrag(Bs, wn*64+n*16+fr, kk*32+kb);
      #pragma unroll
      for (int m=0;m<4;m++)
        #pragma unroll
        for (int n=0;n<4;n++) acc[m][n]=MFMA(a[m],bv[n],acc[m][n]);
    }
    __syncthreads();
  }
  float* Pz = P + (size_t)blockIdx.z*M*N;
  #pragma unroll
  for (int m=0;m<4;m++){
    int row = i0 + wm*64+m*16+(lane>>4)*4;
    #pragma unroll
    for (int n=0;n<4;n++){
      int col = j0 + wn*64+n*16+fr;
      #pragma unroll
      for (int r=0;r<4;r++) Pz[(size_t)(row+r)*N+col] = acc[m][n][r];
    }
  }
}

// ---------------- FFN2 epilogue: out = P0+P1+x1+bias ----------------
__global__ __launch_bounds__(256) void add9_kernel(const float* __restrict__ P,
                                                   const float* __restrict__ x1,
                                                   const float* __restrict__ bias,
                                                   float* __restrict__ out){
  int idx = blockIdx.x*256 + threadIdx.x;   // float4 index
  const float4* P0 = (const float4*)P;
  const float4* P1 = (const float4*)(P + (size_t)ROWS*DMODEL);
  const float4* X  = (const float4*)x1;
  const float4* B4 = (const float4*)bias;
  float4 a = P0[idx], b = P1[idx], c = X[idx], d = B4[idx & 127];
  float4 o; o.x=a.x+b.x+c.x+d.x; o.y=a.y+b.y+c.y+d.y; o.z=a.z+b.z+c.z+d.z; o.w=a.w+b.w+c.w+d.w;
  ((float4*)out)[idx] = o;
}

// ---------------- graph conv split-K partial: P[ks] = adjn @ xp ----------------
__global__ __launch_bounds__(256) void gc_ks_kernel(const u16* __restrict__ adj,
                                                    const u16* __restrict__ xpt,
                                                    float* __restrict__ P){
  __shared__ u16 As[128*64], Bs[64*64];
  int z = blockIdx.z, b = z>>3, h = z&7;
  int i0 = blockIdx.x*128;
  int kbeg = blockIdx.y*704;
  int t = threadIdx.x, lane=t&63, w=t>>6, wm=w>>1, wn=w&1;
  int fr=lane&15, kb=(lane>>4)*8;
  const char* Ab = (const char*)(adj + (size_t)z*L_SEQ*L_SEQ) + (size_t)i0*2816;
  const char* Bb = (const char*)xpt + (size_t)(h*64)*5632 + (size_t)(b*L_SEQ)*2;
  f4v acc[4][2];
  #pragma unroll
  for (int m=0;m<4;m++){ acc[m][0]=(f4v){0.f,0.f,0.f,0.f}; acc[m][1]=(f4v){0.f,0.f,0.f,0.f}; }
  for (int k0=kbeg; k0<kbeg+704; k0+=64){
    stage_tile(Ab + (size_t)k0*2, 2816, As, 128, t);
    stage_tile(Bb + (size_t)k0*2, 5632, Bs, 64, t);
    __syncthreads();
    #pragma unroll
    for (int kk=0;kk<2;kk++){
      s8v a[4], bv[2];
      #pragma unroll
      for (int m=0;m<4;m++) a[m]=ldfrag(As, wm*64+m*16+fr, kk*32+kb);
      #pragma unroll
      for (int n=0;n<2;n++) bv[n]=ldfrag(Bs, wn*32+n*16+fr, kk*32+kb);
      #pragma unroll
      for (int m=0;m<4;m++)
        #pragma unroll
        for (int n=0;n<2;n++) acc[m][n]=MFMA(a[m],bv[n],acc[m][n]);
    }
    __syncthreads();
  }
  float* Pz = P + (size_t)blockIdx.y*ROWS*DMODEL;
  #pragma unroll
  for (int m=0;m<4;m++){
    int rl = i0 + wm*64+m*16+(lane>>4)*4;
    #pragma unroll
    for (int n=0;n<2;n++){
      int col = h*64 + wn*32+n*16+fr;
      #pragma unroll
      for (int r=0;r<4;r++)
        Pz[(size_t)(b*L_SEQ + rl + r)*DMODEL + col] = acc[m][n][r];
    }
  }
}

// ---- wave-level bucket select for radix pass ----
__device__ __forceinline__ void wave_select(const unsigned* hist, int lane, unsigned rem,
                                            unsigned &selB, unsigned &selBase){
  uint4 hv = *(const uint4*)&hist[4*lane];
  unsigned lsum = hv.x+hv.y+hv.z+hv.w;
  unsigned incl = lsum, u;
  u=__shfl_up(incl,1,64);  if(lane>=1)  incl+=u;
  u=__shfl_up(incl,2,64);  if(lane>=2)  incl+=u;
  u=__shfl_up(incl,4,64);  if(lane>=4)  incl+=u;
  u=__shfl_up(incl,8,64);  if(lane>=8)  incl+=u;
  u=__shfl_up(incl,16,64); if(lane>=16) incl+=u;
  u=__shfl_up(incl,32,64); if(lane>=32) incl+=u;
  unsigned excl = incl - lsum;
  bool cross = (excl < rem) && (rem <= incl);
  unsigned long long bal = __ballot(cross);
  int L = __builtin_ctzll(bal);
  unsigned c1 = excl+hv.x, c2=c1+hv.y, c3=c2+hv.z;
  unsigned myB, myBase;
  if (rem <= c1){ myB=4*lane+0; myBase=excl; }
  else if (rem <= c2){ myB=4*lane+1; myBase=c1; }
  else if (rem <= c3){ myB=4*lane+2; myBase=c2; }
  else { myB=4*lane+3; myBase=c3; }
  selB = (unsigned)__shfl((int)myB, L, 64);
  selBase = (unsigned)__shfl((int)myBase, L, 64);
}

// ---------------- per-row pipeline: one WAVE per row, no block barriers ----------------
__global__ __launch_bounds__(256) void row_pipe2_kernel(u16* __restrict__ adj,
                                                        const float* __restrict__ wg,
                                                        const float* __restrict__ masks,
                                                        float* __restrict__ spz,
                                                        float* __restrict__ entp){
  __shared__ float wgT[3][L_SEQ];
  __shared__ unsigned histAll[4][256];
  int t = threadIdx.x, lane = t&63, w = t>>6;
  for (int idx=t; idx<3*L_SEQ; idx+=256){
    float v = wg[idx];
    int e = idx/3, j = idx - 3*e;
    wgT[j][e] = v;
  }
  __syncthreads();

  unsigned* hist = histAll[w];
  int rid = blockIdx.x*4 + w;
  int z = rid / L_SEQ;
  int l = rid - z*L_SEQ;
  unsigned* rowp = (unsigned*)(adj + (size_t)rid*L_SEQ);

  unsigned r[11];
  #pragma unroll
  for (int i=0;i<11;i++) r[i] = rowp[i*64 + lane];

  // --- radix select pass 0 (high byte of 16-bit order key) ---
  *(uint4*)&hist[4*lane] = (uint4){0,0,0,0};
  #pragma unroll
  for (int i=0;i<11;i++){
    atomicAdd(&hist[key16(r[i]&0xFFFFu)>>8], 1u);
    atomicAdd(&hist[key16(r[i]>>16)>>8], 1u);
  }
  __asm__ volatile("s_waitcnt lgkmcnt(0)" ::: "memory");
  unsigned rem = KSEL, B0, base0;
  wave_select(hist, lane, rem, B0, base0);
  rem -= base0;
  // --- pass 1 (low byte within selected high byte) ---
  *(uint4*)&hist[4*lane] = (uint4){0,0,0,0};
  #pragma unroll
  for (int i=0;i<11;i++){
    unsigned k0 = key16(r[i]&0xFFFFu), k1 = key16(r[i]>>16);
    if ((k0>>8)==B0) atomicAdd(&hist[k0&255u], 1u);
    if ((k1>>8)==B0) atomicAdd(&hist[k1&255u], 1u);
  }
  __asm__ volatile("s_waitcnt lgkmcnt(0)" ::: "memory");
  unsigned B1, base1;
  wave_select(hist, lane, rem, B1, base1);
  unsigned thr = (B0<<8) | B1;
  int z_eq = (int)(rem - base1);

  // decode values
  float x0[11], x1[11];
  #pragma unroll
  for (int i=0;i<11;i++){ x0[i] = b2f(r[i]&0xFFFFu); x1[i] = b2f(r[i]>>16); }

  // tie zeroing in global index order: pairs (lane,j) interleaved within step i
  unsigned long long mlt = (1ull<<lane)-1ull;
  int cnt = 0;
  #pragma unroll
  for (int i=0;i<11;i++){
    bool act = (cnt < z_eq);
    bool eq0 = act && (key16(r[i]&0xFFFFu)==thr);
    bool eq1 = act && (key16(r[i]>>16)==thr);
    unsigned long long b0 = __ballot(eq0), b1 = __ballot(eq1);
    int pre0 = __popcll(b0&mlt) + __popcll(b1&mlt);
    int pre1 = pre0 + (eq0?1:0);
    if (eq0 && cnt+pre0 < z_eq) x0[i]=0.f;
    if (eq1 && cnt+pre1 < z_eq) x1[i]=0.f;
    cnt += __popcll(b0)+__popcll(b1);
  }
  // zero everything strictly below threshold
  #pragma unroll
  for (int i=0;i<11;i++){
    if (key16(r[i]&0xFFFFu) < thr) x0[i]=0.f;
    if (key16(r[i]>>16)     < thr) x1[i]=0.f;
  }

  // --- gating: p_j = sum x * wg[:,j] ---
  float p0=0.f, p1=0.f, p2=0.f;
  #pragma unroll
  for (int i=0;i<11;i++){
    int e0 = 2*(i*64+lane);
    float2 w0 = *(const float2*)&wgT[0][e0];
    float2 w1 = *(const float2*)&wgT[1][e0];
    float2 w2 = *(const float2*)&wgT[2][e0];
    p0 += x0[i]*w0.x + x1[i]*w0.y;
    p1 += x0[i]*w1.x + x1[i]*w1.y;
    p2 += x0[i]*w2.x + x1[i]*w2.y;
  }
  #pragma unroll
  for (int o=1;o<64;o<<=1){
    p0 += __shfl_xor(p0,o,64);
    p1 += __shfl_xor(p1,o,64);
    p2 += __shfl_xor(p2,o,64);
  }
  float mx = fmaxf(p0, fmaxf(p1,p2));
  float e0s=expf(p0-mx), e1s=expf(p1-mx), e2s=expf(p2-mx);
  float inv = 1.f/(e0s+e1s+e2s);
  float pr[3]={e0s*inv, e1s*inv, e2s*inv};
  int i0=0; if (pr[1]>pr[i0]) i0=1; if (pr[2]>pr[i0]) i0=2;
  int a_=(i0==0)?1:0, b_=(i0==2)?1:2;
  int i1 = (pr[b_]>pr[a_])?b_:a_;
  bool top2 = !(pr[i0] > 0.5f);
  bool g0=(i0==0)||(top2&&i1==0);
  bool g1=(i0==1)||(top2&&i1==1);
  bool g2=(i0==2)||(top2&&i1==2);
  if (lane==0){
    float ent = pr[0]*logf(pr[0]+1e-10f)+pr[1]*logf(pr[1]+1e-10f)+pr[2]*logf(pr[2]+1e-10f);
    atomicAdd(&entp[rid & 255], ent);
    atomicAdd(&spz[l*3+0], pr[i0]);
    if (top2) atomicAdd(&spz[l*3+1], pr[i1]);
  }

  // --- final mask + softmax ---
  const float* m0 = masks + ((size_t)l*3+0)*L_SEQ;
  const float* m1 = m0 + L_SEQ;
  const float* m2 = m1 + L_SEQ;
  float mxv = -3.0e38f;
  #pragma unroll
  for (int i=0;i<11;i++){
    int e0 = 2*(i*64+lane);
    float fm0 = (e0==l)?1.f:0.f, fm1 = (e0+1==l)?1.f:0.f;
    if (g0){ float2 v=*(const float2*)&m0[e0]; fm0+=v.x; fm1+=v.y; }
    if (g1){ float2 v=*(const float2*)&m1[e0]; fm0+=v.x; fm1+=v.y; }
    if (g2){ float2 v=*(const float2*)&m2[e0]; fm0+=v.x; fm1+=v.y; }
    x0[i] *= fm0; x1[i] *= fm1;
    mxv = fmaxf(mxv, fmaxf(x0[i], x1[i]));
  }
  #pragma unroll
  for (int o=1;o<64;o<<=1) mxv = fmaxf(mxv, __shfl_xor(mxv,o,64));
  float sum=0.f;
  #pragma unroll
  for (int i=0;i<11;i++){
    x0[i] = expf(x0[i]-mxv);
    x1[i] = expf(x1[i]-mxv);
    sum += x0[i]+x1[i];
  }
  #pragma unroll
  for (int o=1;o<64;o<<=1) sum += __shfl_xor(sum,o,64);
  float invs = 1.f/sum;
  #pragma unroll
  for (int i=0;i<11;i++){
    unsigned lo = f2bf(x0[i]*invs), hi = f2bf(x1[i]*invs);
    rowp[i*64+lane] = lo | (hi<<16);
  }
}

// ---------------- loss finalize ----------------
__global__ __launch_bounds__(256) void loss_kernel(const float* __restrict__ spz,
                                                   const float* __restrict__ entp,
                                                   float* __restrict__ out){
  int t = threadIdx.x;
  float sum=0.f;
  for (int i=t;i<4224;i+=256) sum += spz[i];
  sum = block_reduce_sum(sum);
  float mu = sum/4224.f;
  float ss=0.f;
  for (int i=t;i<4224;i+=256){ float d=spz[i]-mu; ss+=d*d; }
  ss = block_reduce_sum(ss);
  float ent = block_reduce_sum(entp[t]);
  if (t==0){
    float var = ss/4223.f;
    float li = var/(mu*mu+1e-10f);
    float ld = -ent/48.f;
    out[0] = li + 0.1f*ld;
  }
}

extern "C" void kernel_launch(void* const* d_in, const int* in_sizes, int n_in,
                              void* d_out, int out_size, void* d_ws, size_t ws_size,
                              hipStream_t stream) {
  const float* x     = (const float*)d_in[0];
  const float* masks = (const float*)d_in[1];
  const float* ln1_g = (const float*)d_in[2];
  const float* ln1_b = (const float*)d_in[3];
  const float* w_p1  = (const float*)d_in[4];
  const float* b_p1  = (const float*)d_in[5];
  const float* w_p2  = (const float*)d_in[6];
  const float* b_p2  = (const float*)d_in[7];
  const float* w_gate= (const float*)d_in[8];
  const float* w_gcn = (const float*)d_in[9];
  const float* b_gcn = (const float*)d_in[10];
  const float* ln2_g = (const float*)d_in[11];
  const float* ln2_b = (const float*)d_in[12];
  const float* w_f1  = (const float*)d_in[13];
  const float* b_f1  = (const float*)d_in[14];
  const float* w_f2  = (const float*)d_in[15];
  const float* b_f2  = (const float*)d_in[16];
  float* out = (float*)d_out;

  char* wsb = (char*)d_ws;
  size_t off = 0;
  u16* adj   = (u16*)(wsb+off); off += (size_t)BH*L_SEQ*L_SEQ*2;  // 63.4 MB
  u16* xn    = (u16*)(wsb+off); off += (size_t)ROWS*DMODEL*2;
  u16* q     = (u16*)(wsb+off); off += (size_t)BH*L_SEQ*64*2;
  u16* kk    = (u16*)(wsb+off); off += (size_t)BH*L_SEQ*64*2;
  u16* xpt   = (u16*)(wsb+off); off += (size_t)DMODEL*ROWS*2;     // [512][2816]
  u16* xn2   = (u16*)(wsb+off); off += (size_t)ROWS*DMODEL*2;
  float* x1  = (float*)(wsb+off); off += (size_t)ROWS*DMODEL*4;
  float* Pk  = (float*)(wsb+off); off += (size_t)2*ROWS*DMODEL*4; // split-K partials (gc, then ffn2)
  u16* wgcnT = (u16*)(wsb+off); off += (size_t)DMODEL*DMODEL*2;
  u16* wf1T  = (u16*)(wsb+off); off += (size_t)DFF*DMODEL*2;
  u16* wf2T  = (u16*)(wsb+off); off += (size_t)DMODEL*DFF*2;
  float* spz = (float*)(wsb+off); off += 4224*4;
  float* entp= (float*)(wsb+off); off += 256*4;
  u16* ffh   = adj;   // reuse after graph conv

  hipMemsetAsync(spz, 0, (4224+256)*sizeof(float), stream);

  castT_kernel<<<dim3(16,16), 256, 0, stream>>>(w_gcn, wgcnT, DMODEL, DMODEL);
  castT_kernel<<<dim3(16,64), 256, 0, stream>>>(w_f1,  wf1T,  DMODEL, DFF);
  castT_kernel<<<dim3(64,16), 256, 0, stream>>>(w_f2,  wf2T,  DFF,    DMODEL);

  // 1. LN1
  ln_kernel<<<ROWS, 256, 0, stream>>>(x, ln1_g, ln1_b, xn);
  // 2. Q/K projections
  qk_proj_kernel<<<ROWS/8, 512, 0, stream>>>(xn, w_p1, b_p1, w_p2, b_p2, q, kk);
  // 3. adj = gelu(Q K^T)
  qkt_mfma_kernel<<<dim3(11,11,BH), 256, 0, stream>>>(q, kk, adj);
  // 4. per-row pipeline (wave per row)
  row_pipe2_kernel<<<dim3(BH*L_SEQ/4), 256, 0, stream>>>(adj, w_gate, masks, spz, entp);
  // 5. xp^T = (xn @ w_gcn + b_gcn)^T
  gemm_mfma_kernel<0,0,1><<<dim3(22,4), 256, 0, stream>>>(xn, wgcnT, b_gcn, xpt, ROWS, DMODEL, DMODEL);
  // 6. gc partials (split-K 2)
  gc_ks_kernel<<<dim3(11,2,BH), 256, 0, stream>>>(adj, xpt, Pk);
  // 7. x1 = x+P0+P1 ; xn2 = LN2(x1)
  ln2_fuse_kernel<<<ROWS, 256, 0, stream>>>(x, Pk, ln2_g, ln2_b, x1, xn2);
  // 8. ffh = gelu(xn2 @ w_f1 + b_f1)
  gemm_mfma_kernel<1,1,0><<<dim3(22,16), 256, 0, stream>>>(xn2, wf1T, b_f1, ffh, ROWS, DFF, DMODEL);
  // 9. FFN2 partials (split-K 2) then epilogue
  gemm_ks_kernel<<<dim3(22,4,2), 256, 0, stream>>>(ffh, wf2T, Pk, ROWS, DMODEL, DFF, DFF/2);
  add9_kernel<<<dim3(ROWS*DMODEL/1024), 256, 0, stream>>>(Pk, x1, b_f2, out);
  // 10. loss
  loss_kernel<<<1, 256, 0, stream>>>(spz, entp, out + (size_t)ROWS*DMODEL);
}

// Round 5
// 315.947 us; speedup vs baseline: 3.6654x; 1.0321x over previous
//
#include <hip/hip_runtime.h>

#define L_SEQ 1408
#define DMODEL 512
#define NH 8
#define BATCH 2
#define BH 16
#define ROWS 2816
#define DFF 2048
#define KSEL 704

typedef unsigned short u16;
typedef short s8v __attribute__((ext_vector_type(8)));
typedef float f4v __attribute__((ext_vector_type(4)));

__device__ __forceinline__ float gelu_f(float x){
  return 0.5f*x*(1.0f+erff(x*0.70710678118654752440f));
}
__device__ __forceinline__ u16 f2bf(float f){
  unsigned u = __float_as_uint(f);
  u += 0x7fffu + ((u>>16)&1u);
  return (u16)(u>>16);
}
__device__ __forceinline__ float b2f(unsigned h){ return __uint_as_float(h<<16); }
__device__ __forceinline__ unsigned key16(unsigned h){
  return (h & 0x8000u) ? (0xFFFFu & ~h) : (h | 0x8000u);
}

__device__ __forceinline__ f4v MFMA(s8v a, s8v b, f4v c){
  return __builtin_amdgcn_mfma_f32_16x16x32_bf16(a, b, c, 0, 0, 0);
}

// all LDS tiles have 128-byte rows (64 bf16); XOR swizzle spreads banks
__device__ __forceinline__ s8v ldfrag(const u16* lds, int row, int kb){
  return *(const s8v*)((const char*)lds + row*128 + ((kb*2) ^ ((row&7)<<4)));
}
__device__ __forceinline__ void stage_tile(const char* g, size_t gstride, u16* lds, int nrows, int t){
  int nch = nrows*8;
  for (int ci = t; ci < nch; ci += 256){
    int row = ci>>3, kc = (ci&7)*16;
    uint4 v = *(const uint4*)(g + (size_t)row*gstride + kc);
    *(uint4*)((char*)lds + row*128 + (kc ^ ((row&7)<<4))) = v;
  }
}

__device__ __forceinline__ float block_reduce_sum(float v){
  __shared__ float sred[8];
  int lane = threadIdx.x & 63, w = threadIdx.x >> 6;
  #pragma unroll
  for (int o=32;o>0;o>>=1) v += __shfl_down(v,o,64);
  if (lane==0) sred[w]=v;
  __syncthreads();
  if (w==0){
    float x = (lane < (int)(blockDim.x>>6)) ? sred[lane] : 0.f;
    #pragma unroll
    for (int o=4;o>0;o>>=1) x += __shfl_down(x,o,64);
    if (lane==0) sred[0]=x;
  }
  __syncthreads();
  float r = sred[0];
  __syncthreads();
  return r;
}

// ---------------- LayerNorm f32 -> bf16 ----------------
__global__ __launch_bounds__(256) void ln_kernel(const float* __restrict__ x,
                                                 const float* __restrict__ g,
                                                 const float* __restrict__ b,
                                                 u16* __restrict__ out){
  int row = blockIdx.x;
  const float* xr = x + (size_t)row*DMODEL;
  int t = threadIdx.x;
  float v0 = xr[t], v1 = xr[t+256];
  float s = block_reduce_sum(v0+v1);
  float mean = s * (1.f/512.f);
  float d0 = v0-mean, d1 = v1-mean;
  float ss = block_reduce_sum(d0*d0 + d1*d1);
  float rstd = rsqrtf(ss*(1.f/512.f) + 1e-5f);
  u16* orow = out + (size_t)row*DMODEL;
  orow[t]     = f2bf(d0*rstd*g[t]     + b[t]);
  orow[t+256] = f2bf(d1*rstd*g[t+256] + b[t+256]);
}

// ---------------- fused x1 = x+P0+P1 ; xn2 = LN(x1) ----------------
__global__ __launch_bounds__(256) void ln2_fuse_kernel(const float* __restrict__ x,
                                                       const float* __restrict__ P,
                                                       const float* __restrict__ g,
                                                       const float* __restrict__ b,
                                                       float* __restrict__ x1,
                                                       u16* __restrict__ xn2){
  int row = blockIdx.x, t = threadIdx.x;
  size_t base = (size_t)row*DMODEL;
  const float* P1 = P + (size_t)ROWS*DMODEL;
  float v0 = x[base+t]     + P[base+t]     + P1[base+t];
  float v1 = x[base+t+256] + P[base+t+256] + P1[base+t+256];
  x1[base+t] = v0; x1[base+t+256] = v1;
  float s = block_reduce_sum(v0+v1);
  float mean = s * (1.f/512.f);
  float d0 = v0-mean, d1 = v1-mean;
  float ss = block_reduce_sum(d0*d0 + d1*d1);
  float rstd = rsqrtf(ss*(1.f/512.f) + 1e-5f);
  xn2[base+t]     = f2bf(d0*rstd*g[t]     + b[t]);
  xn2[base+t+256] = f2bf(d1*rstd*g[t+256] + b[t+256]);
}

// ---------------- all three weight transpose-casts in one launch ----------------
__device__ __forceinline__ void castT_tile(const float* in, u16* outT, int K, int N,
                                           int k0, int n0, int t){
  __shared__ u16 tl[32][33];
  int r = t>>5, c = t&31;
  #pragma unroll
  for (int i=0;i<4;i++){
    int rr = r + i*8;
    tl[rr][c] = f2bf(in[(size_t)(k0+rr)*N + n0 + c]);
  }
  __syncthreads();
  #pragma unroll
  for (int i=0;i<4;i++){
    int rr = r + i*8;
    outT[(size_t)(n0+rr)*K + k0 + c] = tl[c][rr];
  }
}
__global__ __launch_bounds__(256) void castT_all_kernel(const float* __restrict__ w_gcn, u16* __restrict__ wgcnT,
                                                        const float* __restrict__ w_f1,  u16* __restrict__ wf1T,
                                                        const float* __restrict__ w_f2,  u16* __restrict__ wf2T){
  int b = blockIdx.x, t = threadIdx.x;
  if (b < 256){
    castT_tile(w_gcn, wgcnT, DMODEL, DMODEL, (b>>4)*32, (b&15)*32, t);
  } else if (b < 1280){
    int local = b - 256;   // K=512 (16 tiles), N=2048 (64 tiles)
    castT_tile(w_f1, wf1T, DMODEL, DFF, (local&15)*32, (local>>4)*32, t);
  } else {
    int local = b - 1280;  // K=2048 (64 tiles), N=512 (16 tiles)
    castT_tile(w_f2, wf2T, DFF, DMODEL, (local&63)*32, (local>>6)*32, t);
  }
}

// ---------------- Q/K projections ----------------
__global__ __launch_bounds__(512) void qk_proj_kernel(const u16* __restrict__ xn,
                                                      const float* __restrict__ w1, const float* __restrict__ bp1,
                                                      const float* __restrict__ w2, const float* __restrict__ bp2,
                                                      u16* __restrict__ q, u16* __restrict__ k){
  __shared__ float sw1[64*64], sw2[64*64], xr[512];
  int t = threadIdx.x;
  #pragma unroll
  for (int i=0;i<8;i++){ sw1[i*512+t]=w1[i*512+t]; sw2[i*512+t]=w2[i*512+t]; }
  int rowbase = blockIdx.x*8;
  int h = t>>6, j = t&63;
  float bb1 = bp1[j], bb2 = bp2[j];
  for (int r=0;r<8;r++){
    int row = rowbase + r;
    __syncthreads();
    xr[t] = b2f(xn[(size_t)row*DMODEL + t]);
    __syncthreads();
    float a1=bb1, a2=bb2;
    const float* xv = &xr[h*64];
    #pragma unroll
    for (int kk=0;kk<64;kk++){
      float xvk = xv[kk];
      a1 += xvk*sw1[kk*64+j];
      a2 += xvk*sw2[kk*64+j];
    }
    int b_ = row / L_SEQ, l = row % L_SEQ;
    size_t o = (((size_t)(b_*NH+h))*L_SEQ + l)*64 + j;
    q[o]=f2bf(a1); k[o]=f2bf(a2);
  }
}

// ---------------- adj = gelu(Q K^T), LDS-staged coalesced store ----------------
__global__ __launch_bounds__(256) void qkt_mfma_kernel(const u16* __restrict__ q,
                                                       const u16* __restrict__ k,
                                                       u16* __restrict__ adj){
  __shared__ u16 sbuf[128*128];
  u16* Qs = sbuf; u16* Ks = sbuf + 128*64; u16* Cs = sbuf;
  int z = blockIdx.z;
  int i0 = blockIdx.x*128, j0 = blockIdx.y*128;
  int t = threadIdx.x;
  const char* Qb = (const char*)(q + (size_t)z*L_SEQ*64) + (size_t)i0*128;
  const char* Kb = (const char*)(k + (size_t)z*L_SEQ*64) + (size_t)j0*128;
  stage_tile(Qb, 128, Qs, 128, t);
  stage_tile(Kb, 128, Ks, 128, t);
  __syncthreads();
  int lane = t&63, w = t>>6, wm = w>>1, wn = w&1;
  int fr = lane&15, kb = (lane>>4)*8;
  f4v acc[4][4];
  #pragma unroll
  for (int m=0;m<4;m++)
    #pragma unroll
    for (int n=0;n<4;n++) acc[m][n]=(f4v){0.f,0.f,0.f,0.f};
  #pragma unroll
  for (int kk=0;kk<2;kk++){
    s8v a[4], bv[4];
    #pragma unroll
    for (int m=0;m<4;m++) a[m] = ldfrag(Qs, wm*64+m*16+fr, kk*32+kb);
    #pragma unroll
    for (int n=0;n<4;n++) bv[n] = ldfrag(Ks, wn*64+n*16+fr, kk*32+kb);
    #pragma unroll
    for (int m=0;m<4;m++)
      #pragma unroll
      for (int n=0;n<4;n++) acc[m][n] = MFMA(a[m], bv[n], acc[m][n]);
  }
  __syncthreads();
  #pragma unroll
  for (int m=0;m<4;m++){
    int row = wm*64 + m*16 + (lane>>4)*4;
    #pragma unroll
    for (int n=0;n<4;n++){
      int col = wn*64 + n*16 + fr;
      #pragma unroll
      for (int r=0;r<4;r++)
        Cs[(row+r)*128 + col] = f2bf(gelu_f(acc[m][n][r]));
    }
  }
  __syncthreads();
  u16* Cb = adj + (size_t)z*L_SEQ*L_SEQ;
  // C tile is 128 u16 wide = 16 uint4 chunks per row; 2048 chunks total
  #pragma unroll
  for (int i=0;i<8;i++){
    int idx = i*256 + t;
    int r = idx>>4, cc = (idx&15)*8;
    uint4 v = *(const uint4*)&Cs[r*128 + cc];
    *(uint4*)((char*)Cb + (size_t)(i0+r)*2816 + (j0+cc)*2) = v;
  }
}

// ---------------- generic MFMA GEMM: C = f(A@B + bias) ----------------
template<int OUTBF16,int ACT,int TRANSOUT>
__global__ __launch_bounds__(256) void gemm_mfma_kernel(const u16* __restrict__ A,
                                                        const u16* __restrict__ BT,
                                                        const float* __restrict__ bias,
                                                        void* __restrict__ outp,
                                                        int M, int N, int K){
  __shared__ u16 As[128*64], Bs[128*64];
  int i0 = blockIdx.x*128, j0 = blockIdx.y*128;
  int t = threadIdx.x, lane=t&63, w=t>>6, wm=w>>1, wn=w&1;
  int fr=lane&15, kb=(lane>>4)*8;
  f4v acc[4][4];
  #pragma unroll
  for (int m=0;m<4;m++)
    #pragma unroll
    for (int n=0;n<4;n++) acc[m][n]=(f4v){0.f,0.f,0.f,0.f};
  size_t strA=(size_t)K*2;
  const char* Ab = (const char*)A + (size_t)i0*strA;
  const char* Bb = (const char*)BT + (size_t)j0*strA;
  for (int k0=0;k0<K;k0+=64){
    stage_tile(Ab + (size_t)k0*2, strA, As, 128, t);
    stage_tile(Bb + (size_t)k0*2, strA, Bs, 128, t);
    __syncthreads();
    #pragma unroll
    for (int kk=0;kk<2;kk++){
      s8v a[4], bv[4];
      #pragma unroll
      for (int m=0;m<4;m++) a[m]=ldfrag(As, wm*64+m*16+fr, kk*32+kb);
      #pragma unroll
      for (int n=0;n<4;n++) bv[n]=ldfrag(Bs, wn*64+n*16+fr, kk*32+kb);
      #pragma unroll
      for (int m=0;m<4;m++)
        #pragma unroll
        for (int n=0;n<4;n++) acc[m][n]=MFMA(a[m],bv[n],acc[m][n]);
    }
    __syncthreads();
  }
  #pragma unroll
  for (int m=0;m<4;m++){
    int row = i0 + wm*64+m*16+(lane>>4)*4;
    #pragma unroll
    for (int n=0;n<4;n++){
      int col = j0 + wn*64+n*16+fr;
      float bb = bias[col];
      #pragma unroll
      for (int r=0;r<4;r++){
        float v = acc[m][n][r]+bb;
        if (ACT) v = gelu_f(v);
        if (TRANSOUT) ((u16*)outp)[(size_t)col*M + row + r] = f2bf(v);
        else if (OUTBF16) ((u16*)outp)[(size_t)(row+r)*N+col] = f2bf(v);
        else ((float*)outp)[(size_t)(row+r)*N+col] = v;
      }
    }
  }
}

// ---------------- split-K GEMM partial: P[z] = A@B over K slice ----------------
__global__ __launch_bounds__(256) void gemm_ks_kernel(const u16* __restrict__ A,
                                                      const u16* __restrict__ BT,
                                                      float* __restrict__ P,
                                                      int M, int N, int K, int KS){
  __shared__ u16 As[128*64], Bs[128*64];
  int i0 = blockIdx.x*128, j0 = blockIdx.y*128;
  int kbeg = blockIdx.z*KS;
  int t = threadIdx.x, lane=t&63, w=t>>6, wm=w>>1, wn=w&1;
  int fr=lane&15, kb=(lane>>4)*8;
  f4v acc[4][4];
  #pragma unroll
  for (int m=0;m<4;m++)
    #pragma unroll
    for (int n=0;n<4;n++) acc[m][n]=(f4v){0.f,0.f,0.f,0.f};
  size_t strA=(size_t)K*2;
  const char* Ab = (const char*)A + (size_t)i0*strA;
  const char* Bb = (const char*)BT + (size_t)j0*strA;
  for (int k0=kbeg; k0<kbeg+KS; k0+=64){
    stage_tile(Ab + (size_t)k0*2, strA, As, 128, t);
    stage_tile(Bb + (size_t)k0*2, strA, Bs, 128, t);
    __syncthreads();
    #pragma unroll
    for (int kk=0;kk<2;kk++){
      s8v a[4], bv[4];
      #pragma unroll
      for (int m=0;m<4;m++) a[m]=ldfrag(As, wm*64+m*16+fr, kk*32+kb);
      #pragma unroll
      for (int n=0;n<4;n++) bv[n]=ldfrag(Bs, wn*64+n*16+fr, kk*32+kb);
      #pragma unroll
      for (int m=0;m<4;m++)
        #pragma unroll
        for (int n=0;n<4;n++) acc[m][n]=MFMA(a[m],bv[n],acc[m][n]);
    }
    __syncthreads();
  }
  float* Pz = P + (size_t)blockIdx.z*M*N;
  #pragma unroll
  for (int m=0;m<4;m++){
    int row = i0 + wm*64+m*16+(lane>>4)*4;
    #pragma unroll
    for (int n=0;n<4;n++){
      int col = j0 + wn*64+n*16+fr;
      #pragma unroll
      for (int r=0;r<4;r++) Pz[(size_t)(row+r)*N+col] = acc[m][n][r];
    }
  }
}

// ---------------- FFN2 epilogue: out = P0+P1+x1+bias ----------------
__global__ __launch_bounds__(256) void add9_kernel(const float* __restrict__ P,
                                                   const float* __restrict__ x1,
                                                   const float* __restrict__ bias,
                                                   float* __restrict__ out){
  int idx = blockIdx.x*256 + threadIdx.x;   // float4 index
  const float4* P0 = (const float4*)P;
  const float4* P1 = (const float4*)(P + (size_t)ROWS*DMODEL);
  const float4* X  = (const float4*)x1;
  const float4* B4 = (const float4*)bias;
  float4 a = P0[idx], b = P1[idx], c = X[idx], d = B4[idx & 127];
  float4 o; o.x=a.x+b.x+c.x+d.x; o.y=a.y+b.y+c.y+d.y; o.z=a.z+b.z+c.z+d.z; o.w=a.w+b.w+c.w+d.w;
  ((float4*)out)[idx] = o;
}

// ---------------- graph conv split-K partial: P[ks] = adjn @ xp ----------------
__global__ __launch_bounds__(256) void gc_ks_kernel(const u16* __restrict__ adj,
                                                    const u16* __restrict__ xpt,
                                                    float* __restrict__ P){
  __shared__ u16 As[128*64], Bs[64*64];
  int z = blockIdx.z, b = z>>3, h = z&7;
  int i0 = blockIdx.x*128;
  int kbeg = blockIdx.y*704;
  int t = threadIdx.x, lane=t&63, w=t>>6, wm=w>>1, wn=w&1;
  int fr=lane&15, kb=(lane>>4)*8;
  const char* Ab = (const char*)(adj + (size_t)z*L_SEQ*L_SEQ) + (size_t)i0*2816;
  const char* Bb = (const char*)xpt + (size_t)(h*64)*5632 + (size_t)(b*L_SEQ)*2;
  f4v acc[4][2];
  #pragma unroll
  for (int m=0;m<4;m++){ acc[m][0]=(f4v){0.f,0.f,0.f,0.f}; acc[m][1]=(f4v){0.f,0.f,0.f,0.f}; }
  for (int k0=kbeg; k0<kbeg+704; k0+=64){
    stage_tile(Ab + (size_t)k0*2, 2816, As, 128, t);
    stage_tile(Bb + (size_t)k0*2, 5632, Bs, 64, t);
    __syncthreads();
    #pragma unroll
    for (int kk=0;kk<2;kk++){
      s8v a[4], bv[2];
      #pragma unroll
      for (int m=0;m<4;m++) a[m]=ldfrag(As, wm*64+m*16+fr, kk*32+kb);
      #pragma unroll
      for (int n=0;n<2;n++) bv[n]=ldfrag(Bs, wn*32+n*16+fr, kk*32+kb);
      #pragma unroll
      for (int m=0;m<4;m++)
        #pragma unroll
        for (int n=0;n<2;n++) acc[m][n]=MFMA(a[m],bv[n],acc[m][n]);
    }
    __syncthreads();
  }
  float* Pz = P + (size_t)blockIdx.y*ROWS*DMODEL;
  #pragma unroll
  for (int m=0;m<4;m++){
    int rl = i0 + wm*64+m*16+(lane>>4)*4;
    #pragma unroll
    for (int n=0;n<2;n++){
      int col = h*64 + wn*32+n*16+fr;
      #pragma unroll
      for (int r=0;r<4;r++)
        Pz[(size_t)(b*L_SEQ + rl + r)*DMODEL + col] = acc[m][n][r];
    }
  }
}

// ---------------- per-row pipeline: one WAVE per row, ballot binary-search select ----------------
__global__ __launch_bounds__(256) void row_pipe2_kernel(u16* __restrict__ adj,
                                                        const float* __restrict__ wg,
                                                        const float* __restrict__ masks,
                                                        float* __restrict__ spz,
                                                        float* __restrict__ entp){
  __shared__ float wgT[3][L_SEQ];
  int t = threadIdx.x, lane = t&63, w = t>>6;
  for (int idx=t; idx<3*L_SEQ; idx+=256){
    float v = wg[idx];
    int e = idx/3, j = idx - 3*e;
    wgT[j][e] = v;
  }
  __syncthreads();

  int rid = blockIdx.x*4 + w;
  int z = rid / L_SEQ;
  int l = rid - z*L_SEQ;
  unsigned* rowp = (unsigned*)(adj + (size_t)rid*L_SEQ);

  unsigned r[11], ky[11];
  #pragma unroll
  for (int i=0;i<11;i++) r[i] = rowp[i*64 + lane];
  #pragma unroll
  for (int i=0;i<11;i++) ky[i] = key16(r[i]&0xFFFFu) | (key16(r[i]>>16)<<16);

  // --- 16-step ballot binary search for threshold key ---
  // thr = largest 16-bit value with c(thr)=#{keys < thr} < KSEL; track cnt_thr=c(thr)
  unsigned thr = 0; int cnt_thr = 0;
  #pragma unroll
  for (int b=15;b>=0;b--){
    unsigned cand = thr | (1u<<b);
    int cnt = 0;
    #pragma unroll
    for (int i=0;i<11;i++){
      cnt += __popcll(__ballot((ky[i]&0xFFFFu) < cand));
      cnt += __popcll(__ballot((ky[i]>>16)     < cand));
    }
    if ((unsigned)cnt < KSEL){ thr = cand; cnt_thr = cnt; }
  }
  int z_eq = (int)(KSEL - cnt_thr);   // # entries equal to thr to zero, lowest index first

  // decode values
  float x0[11], x1[11];
  #pragma unroll
  for (int i=0;i<11;i++){ x0[i] = b2f(r[i]&0xFFFFu); x1[i] = b2f(r[i]>>16); }

  // tie zeroing in global index order: pairs (lane,j) interleaved within step i
  unsigned long long mlt = (1ull<<lane)-1ull;
  int cnt = 0;
  #pragma unroll
  for (int i=0;i<11;i++){
    bool act = (cnt < z_eq);
    bool eq0 = act && ((ky[i]&0xFFFFu)==thr);
    bool eq1 = act && ((ky[i]>>16)==thr);
    unsigned long long b0 = __ballot(eq0), b1 = __ballot(eq1);
    int pre0 = __popcll(b0&mlt) + __popcll(b1&mlt);
    int pre1 = pre0 + (eq0?1:0);
    if (eq0 && cnt+pre0 < z_eq) x0[i]=0.f;
    if (eq1 && cnt+pre1 < z_eq) x1[i]=0.f;
    cnt += __popcll(b0)+__popcll(b1);
  }
  // zero everything strictly below threshold
  #pragma unroll
  for (int i=0;i<11;i++){
    if ((ky[i]&0xFFFFu) < thr) x0[i]=0.f;
    if ((ky[i]>>16)     < thr) x1[i]=0.f;
  }

  // --- gating: p_j = sum x * wg[:,j] ---
  float p0=0.f, p1=0.f, p2=0.f;
  #pragma unroll
  for (int i=0;i<11;i++){
    int e0 = 2*(i*64+lane);
    float2 w0 = *(const float2*)&wgT[0][e0];
    float2 w1 = *(const float2*)&wgT[1][e0];
    float2 w2 = *(const float2*)&wgT[2][e0];
    p0 += x0[i]*w0.x + x1[i]*w0.y;
    p1 += x0[i]*w1.x + x1[i]*w1.y;
    p2 += x0[i]*w2.x + x1[i]*w2.y;
  }
  #pragma unroll
  for (int o=1;o<64;o<<=1){
    p0 += __shfl_xor(p0,o,64);
    p1 += __shfl_xor(p1,o,64);
    p2 += __shfl_xor(p2,o,64);
  }
  float mx = fmaxf(p0, fmaxf(p1,p2));
  float e0s=expf(p0-mx), e1s=expf(p1-mx), e2s=expf(p2-mx);
  float inv = 1.f/(e0s+e1s+e2s);
  float pr[3]={e0s*inv, e1s*inv, e2s*inv};
  int i0=0; if (pr[1]>pr[i0]) i0=1; if (pr[2]>pr[i0]) i0=2;
  int a_=(i0==0)?1:0, b_=(i0==2)?1:2;
  int i1 = (pr[b_]>pr[a_])?b_:a_;
  bool top2 = !(pr[i0] > 0.5f);
  bool g0=(i0==0)||(top2&&i1==0);
  bool g1=(i0==1)||(top2&&i1==1);
  bool g2=(i0==2)||(top2&&i1==2);
  if (lane==0){
    float ent = pr[0]*logf(pr[0]+1e-10f)+pr[1]*logf(pr[1]+1e-10f)+pr[2]*logf(pr[2]+1e-10f);
    atomicAdd(&entp[rid & 255], ent);
    atomicAdd(&spz[l*3+0], pr[i0]);
    if (top2) atomicAdd(&spz[l*3+1], pr[i1]);
  }

  // --- final mask + softmax ---
  const float* m0 = masks + ((size_t)l*3+0)*L_SEQ;
  const float* m1 = m0 + L_SEQ;
  const float* m2 = m1 + L_SEQ;
  float mxv = -3.0e38f;
  #pragma unroll
  for (int i=0;i<11;i++){
    int e0 = 2*(i*64+lane);
    float fm0 = (e0==l)?1.f:0.f, fm1 = (e0+1==l)?1.f:0.f;
    if (g0){ float2 v=*(const float2*)&m0[e0]; fm0+=v.x; fm1+=v.y; }
    if (g1){ float2 v=*(const float2*)&m1[e0]; fm0+=v.x; fm1+=v.y; }
    if (g2){ float2 v=*(const float2*)&m2[e0]; fm0+=v.x; fm1+=v.y; }
    x0[i] *= fm0; x1[i] *= fm1;
    mxv = fmaxf(mxv, fmaxf(x0[i], x1[i]));
  }
  #pragma unroll
  for (int o=1;o<64;o<<=1) mxv = fmaxf(mxv, __shfl_xor(mxv,o,64));
  float sum=0.f;
  #pragma unroll
  for (int i=0;i<11;i++){
    x0[i] = expf(x0[i]-mxv);
    x1[i] = expf(x1[i]-mxv);
    sum += x0[i]+x1[i];
  }
  #pragma unroll
  for (int o=1;o<64;o<<=1) sum += __shfl_xor(sum,o,64);
  float invs = 1.f/sum;
  #pragma unroll
  for (int i=0;i<11;i++){
    unsigned lo = f2bf(x0[i]*invs), hi = f2bf(x1[i]*invs);
    rowp[i*64+lane] = lo | (hi<<16);
  }
}

// ---------------- loss finalize ----------------
__global__ __launch_bounds__(256) void loss_kernel(const float* __restrict__ spz,
                                                   const float* __restrict__ entp,
                                                   float* __restrict__ out){
  int t = threadIdx.x;
  float sum=0.f;
  for (int i=t;i<4224;i+=256) sum += spz[i];
  sum = block_reduce_sum(sum);
  float mu = sum/4224.f;
  float ss=0.f;
  for (int i=t;i<4224;i+=256){ float d=spz[i]-mu; ss+=d*d; }
  ss = block_reduce_sum(ss);
  float ent = block_reduce_sum(entp[t]);
  if (t==0){
    float var = ss/4223.f;
    float li = var/(mu*mu+1e-10f);
    float ld = -ent/48.f;
    out[0] = li + 0.1f*ld;
  }
}

extern "C" void kernel_launch(void* const* d_in, const int* in_sizes, int n_in,
                              void* d_out, int out_size, void* d_ws, size_t ws_size,
                              hipStream_t stream) {
  const float* x     = (const float*)d_in[0];
  const float* masks = (const float*)d_in[1];
  const float* ln1_g = (const float*)d_in[2];
  const float* ln1_b = (const float*)d_in[3];
  const float* w_p1  = (const float*)d_in[4];
  const float* b_p1  = (const float*)d_in[5];
  const float* w_p2  = (const float*)d_in[6];
  const float* b_p2  = (const float*)d_in[7];
  const float* w_gate= (const float*)d_in[8];
  const float* w_gcn = (const float*)d_in[9];
  const float* b_gcn = (const float*)d_in[10];
  const float* ln2_g = (const float*)d_in[11];
  const float* ln2_b = (const float*)d_in[12];
  const float* w_f1  = (const float*)d_in[13];
  const float* b_f1  = (const float*)d_in[14];
  const float* w_f2  = (const float*)d_in[15];
  const float* b_f2  = (const float*)d_in[16];
  float* out = (float*)d_out;

  char* wsb = (char*)d_ws;
  size_t off = 0;
  u16* adj   = (u16*)(wsb+off); off += (size_t)BH*L_SEQ*L_SEQ*2;  // 63.4 MB
  u16* xn    = (u16*)(wsb+off); off += (size_t)ROWS*DMODEL*2;
  u16* q     = (u16*)(wsb+off); off += (size_t)BH*L_SEQ*64*2;
  u16* kk    = (u16*)(wsb+off); off += (size_t)BH*L_SEQ*64*2;
  u16* xpt   = (u16*)(wsb+off); off += (size_t)DMODEL*ROWS*2;     // [512][2816]
  u16* xn2   = (u16*)(wsb+off); off += (size_t)ROWS*DMODEL*2;
  float* x1  = (float*)(wsb+off); off += (size_t)ROWS*DMODEL*4;
  float* Pk  = (float*)(wsb+off); off += (size_t)2*ROWS*DMODEL*4; // split-K partials (gc, then ffn2)
  u16* wgcnT = (u16*)(wsb+off); off += (size_t)DMODEL*DMODEL*2;
  u16* wf1T  = (u16*)(wsb+off); off += (size_t)DFF*DMODEL*2;
  u16* wf2T  = (u16*)(wsb+off); off += (size_t)DMODEL*DFF*2;
  float* spz = (float*)(wsb+off); off += 4224*4;
  float* entp= (float*)(wsb+off); off += 256*4;
  u16* ffh   = adj;   // reuse after graph conv

  hipMemsetAsync(spz, 0, (4224+256)*sizeof(float), stream);

  // weight transpose-casts (one launch)
  castT_all_kernel<<<dim3(2304), 256, 0, stream>>>(w_gcn, wgcnT, w_f1, wf1T, w_f2, wf2T);

  // 1. LN1
  ln_kernel<<<ROWS, 256, 0, stream>>>(x, ln1_g, ln1_b, xn);
  // 2. Q/K projections
  qk_proj_kernel<<<ROWS/8, 512, 0, stream>>>(xn, w_p1, b_p1, w_p2, b_p2, q, kk);
  // 3. adj = gelu(Q K^T)
  qkt_mfma_kernel<<<dim3(11,11,BH), 256, 0, stream>>>(q, kk, adj);
  // 4. per-row pipeline (wave per row)
  row_pipe2_kernel<<<dim3(BH*L_SEQ/4), 256, 0, stream>>>(adj, w_gate, masks, spz, entp);
  // 5. xp^T = (xn @ w_gcn + b_gcn)^T
  gemm_mfma_kernel<0,0,1><<<dim3(22,4), 256, 0, stream>>>(xn, wgcnT, b_gcn, xpt, ROWS, DMODEL, DMODEL);
  // 6. gc partials (split-K 2)
  gc_ks_kernel<<<dim3(11,2,BH), 256, 0, stream>>>(adj, xpt, Pk);
  // 7. x1 = x+P0+P1 ; xn2 = LN2(x1)
  ln2_fuse_kernel<<<ROWS, 256, 0, stream>>>(x, Pk, ln2_g, ln2_b, x1, xn2);
  // 8. ffh = gelu(xn2 @ w_f1 + b_f1)
  gemm_mfma_kernel<1,1,0><<<dim3(22,16), 256, 0, stream>>>(xn2, wf1T, b_f1, ffh, ROWS, DFF, DMODEL);
  // 9. FFN2 partials (split-K 2) then epilogue
  gemm_ks_kernel<<<dim3(22,4,2), 256, 0, stream>>>(ffh, wf2T, Pk, ROWS, DMODEL, DFF, DFF/2);
  add9_kernel<<<dim3(ROWS*DMODEL/1024), 256, 0, stream>>>(Pk, x1, b_f2, out);
  // 10. loss
  loss_kernel<<<1, 256, 0, stream>>>(spz, entp, out + (size_t)ROWS*DMODEL);
}

// Round 6
// 293.635 us; speedup vs baseline: 3.9439x; 1.0760x over previous
//
#include <hip/hip_runtime.h>

#define L_SEQ 1408
#define DMODEL 512
#define NH 8
#define BATCH 2
#define BH 16
#define ROWS 2816
#define DFF 2048
#define KSEL 704

typedef unsigned short u16;
typedef short s8v __attribute__((ext_vector_type(8)));
typedef float f4v __attribute__((ext_vector_type(4)));

// fast gelu: 0.5x(1+tanh(.79788(x+.044715x^3))) == x*sigmoid(1.59577(x+.044715x^3))
// max abs err ~1e-3, below bf16 quantization of adj
__device__ __forceinline__ float gelu_f(float x){
  float u = 1.595769122f*(x + 0.044715f*x*x*x);
  return x * __builtin_amdgcn_rcpf(1.0f + __expf(-u));
}
__device__ __forceinline__ u16 f2bf(float f){
  unsigned u = __float_as_uint(f);
  u += 0x7fffu + ((u>>16)&1u);
  return (u16)(u>>16);
}
__device__ __forceinline__ float b2f(unsigned h){ return __uint_as_float(h<<16); }
__device__ __forceinline__ unsigned key16(unsigned h){
  return (h & 0x8000u) ? (0xFFFFu & ~h) : (h | 0x8000u);
}

__device__ __forceinline__ f4v MFMA(s8v a, s8v b, f4v c){
  return __builtin_amdgcn_mfma_f32_16x16x32_bf16(a, b, c, 0, 0, 0);
}

// all LDS tiles have 128-byte rows (64 bf16); XOR swizzle spreads banks
__device__ __forceinline__ s8v ldfrag(const u16* lds, int row, int kb){
  return *(const s8v*)((const char*)lds + row*128 + ((kb*2) ^ ((row&7)<<4)));
}
__device__ __forceinline__ void stage_tile(const char* g, size_t gstride, u16* lds, int nrows, int t){
  int nch = nrows*8;
  for (int ci = t; ci < nch; ci += 256){
    int row = ci>>3, kc = (ci&7)*16;
    uint4 v = *(const uint4*)(g + (size_t)row*gstride + kc);
    *(uint4*)((char*)lds + row*128 + (kc ^ ((row&7)<<4))) = v;
  }
}

__device__ __forceinline__ float block_reduce_sum(float v){
  __shared__ float sred[8];
  int lane = threadIdx.x & 63, w = threadIdx.x >> 6;
  #pragma unroll
  for (int o=32;o>0;o>>=1) v += __shfl_down(v,o,64);
  if (lane==0) sred[w]=v;
  __syncthreads();
  if (w==0){
    float x = (lane < (int)(blockDim.x>>6)) ? sred[lane] : 0.f;
    #pragma unroll
    for (int o=4;o>0;o>>=1) x += __shfl_down(x,o,64);
    if (lane==0) sred[0]=x;
  }
  __syncthreads();
  float r = sred[0];
  __syncthreads();
  return r;
}

// ---------------- LayerNorm f32 -> bf16 ----------------
__global__ __launch_bounds__(256) void ln_kernel(const float* __restrict__ x,
                                                 const float* __restrict__ g,
                                                 const float* __restrict__ b,
                                                 u16* __restrict__ out){
  int row = blockIdx.x;
  const float* xr = x + (size_t)row*DMODEL;
  int t = threadIdx.x;
  float v0 = xr[t], v1 = xr[t+256];
  float s = block_reduce_sum(v0+v1);
  float mean = s * (1.f/512.f);
  float d0 = v0-mean, d1 = v1-mean;
  float ss = block_reduce_sum(d0*d0 + d1*d1);
  float rstd = rsqrtf(ss*(1.f/512.f) + 1e-5f);
  u16* orow = out + (size_t)row*DMODEL;
  orow[t]     = f2bf(d0*rstd*g[t]     + b[t]);
  orow[t+256] = f2bf(d1*rstd*g[t+256] + b[t+256]);
}

// ---------------- fused x1 = x+P0+P1 ; xn2 = LN(x1) ----------------
__global__ __launch_bounds__(256) void ln2_fuse_kernel(const float* __restrict__ x,
                                                       const float* __restrict__ P,
                                                       const float* __restrict__ g,
                                                       const float* __restrict__ b,
                                                       float* __restrict__ x1,
                                                       u16* __restrict__ xn2){
  int row = blockIdx.x, t = threadIdx.x;
  size_t base = (size_t)row*DMODEL;
  const float* P1 = P + (size_t)ROWS*DMODEL;
  float v0 = x[base+t]     + P[base+t]     + P1[base+t];
  float v1 = x[base+t+256] + P[base+t+256] + P1[base+t+256];
  x1[base+t] = v0; x1[base+t+256] = v1;
  float s = block_reduce_sum(v0+v1);
  float mean = s * (1.f/512.f);
  float d0 = v0-mean, d1 = v1-mean;
  float ss = block_reduce_sum(d0*d0 + d1*d1);
  float rstd = rsqrtf(ss*(1.f/512.f) + 1e-5f);
  xn2[base+t]     = f2bf(d0*rstd*g[t]     + b[t]);
  xn2[base+t+256] = f2bf(d1*rstd*g[t+256] + b[t+256]);
}

// ---------------- all three weight transpose-casts in one launch ----------------
__device__ __forceinline__ void castT_tile(const float* in, u16* outT, int K, int N,
                                           int k0, int n0, int t){
  __shared__ u16 tl[32][33];
  int r = t>>5, c = t&31;
  #pragma unroll
  for (int i=0;i<4;i++){
    int rr = r + i*8;
    tl[rr][c] = f2bf(in[(size_t)(k0+rr)*N + n0 + c]);
  }
  __syncthreads();
  #pragma unroll
  for (int i=0;i<4;i++){
    int rr = r + i*8;
    outT[(size_t)(n0+rr)*K + k0 + c] = tl[c][rr];
  }
}
__global__ __launch_bounds__(256) void castT_all_kernel(const float* __restrict__ w_gcn, u16* __restrict__ wgcnT,
                                                        const float* __restrict__ w_f1,  u16* __restrict__ wf1T,
                                                        const float* __restrict__ w_f2,  u16* __restrict__ wf2T){
  int b = blockIdx.x, t = threadIdx.x;
  if (b < 256){
    castT_tile(w_gcn, wgcnT, DMODEL, DMODEL, (b>>4)*32, (b&15)*32, t);
  } else if (b < 1280){
    int local = b - 256;   // K=512 (16 tiles), N=2048 (64 tiles)
    castT_tile(w_f1, wf1T, DMODEL, DFF, (local&15)*32, (local>>4)*32, t);
  } else {
    int local = b - 1280;  // K=2048 (64 tiles), N=512 (16 tiles)
    castT_tile(w_f2, wf2T, DFF, DMODEL, (local&63)*32, (local>>6)*32, t);
  }
}

// ---------------- Q/K projections ----------------
__global__ __launch_bounds__(512) void qk_proj_kernel(const u16* __restrict__ xn,
                                                      const float* __restrict__ w1, const float* __restrict__ bp1,
                                                      const float* __restrict__ w2, const float* __restrict__ bp2,
                                                      u16* __restrict__ q, u16* __restrict__ k){
  __shared__ float sw1[64*64], sw2[64*64], xr[512];
  int t = threadIdx.x;
  #pragma unroll
  for (int i=0;i<8;i++){ sw1[i*512+t]=w1[i*512+t]; sw2[i*512+t]=w2[i*512+t]; }
  int rowbase = blockIdx.x*8;
  int h = t>>6, j = t&63;
  float bb1 = bp1[j], bb2 = bp2[j];
  for (int r=0;r<8;r++){
    int row = rowbase + r;
    __syncthreads();
    xr[t] = b2f(xn[(size_t)row*DMODEL + t]);
    __syncthreads();
    float a1=bb1, a2=bb2;
    const float* xv = &xr[h*64];
    #pragma unroll
    for (int kk=0;kk<64;kk++){
      float xvk = xv[kk];
      a1 += xvk*sw1[kk*64+j];
      a2 += xvk*sw2[kk*64+j];
    }
    int b_ = row / L_SEQ, l = row % L_SEQ;
    size_t o = (((size_t)(b_*NH+h))*L_SEQ + l)*64 + j;
    q[o]=f2bf(a1); k[o]=f2bf(a2);
  }
}

// ---------------- adj = gelu(Q K^T), LDS-staged coalesced store ----------------
__global__ __launch_bounds__(256) void qkt_mfma_kernel(const u16* __restrict__ q,
                                                       const u16* __restrict__ k,
                                                       u16* __restrict__ adj){
  __shared__ u16 sbuf[128*128];
  u16* Qs = sbuf; u16* Ks = sbuf + 128*64; u16* Cs = sbuf;
  int z = blockIdx.z;
  int i0 = blockIdx.x*128, j0 = blockIdx.y*128;
  int t = threadIdx.x;
  const char* Qb = (const char*)(q + (size_t)z*L_SEQ*64) + (size_t)i0*128;
  const char* Kb = (const char*)(k + (size_t)z*L_SEQ*64) + (size_t)j0*128;
  stage_tile(Qb, 128, Qs, 128, t);
  stage_tile(Kb, 128, Ks, 128, t);
  __syncthreads();
  int lane = t&63, w = t>>6, wm = w>>1, wn = w&1;
  int fr = lane&15, kb = (lane>>4)*8;
  f4v acc[4][4];
  #pragma unroll
  for (int m=0;m<4;m++)
    #pragma unroll
    for (int n=0;n<4;n++) acc[m][n]=(f4v){0.f,0.f,0.f,0.f};
  #pragma unroll
  for (int kk=0;kk<2;kk++){
    s8v a[4], bv[4];
    #pragma unroll
    for (int m=0;m<4;m++) a[m] = ldfrag(Qs, wm*64+m*16+fr, kk*32+kb);
    #pragma unroll
    for (int n=0;n<4;n++) bv[n] = ldfrag(Ks, wn*64+n*16+fr, kk*32+kb);
    #pragma unroll
    for (int m=0;m<4;m++)
      #pragma unroll
      for (int n=0;n<4;n++) acc[m][n] = MFMA(a[m], bv[n], acc[m][n]);
  }
  __syncthreads();
  #pragma unroll
  for (int m=0;m<4;m++){
    int row = wm*64 + m*16 + (lane>>4)*4;
    #pragma unroll
    for (int n=0;n<4;n++){
      int col = wn*64 + n*16 + fr;
      #pragma unroll
      for (int r=0;r<4;r++)
        Cs[(row+r)*128 + col] = f2bf(gelu_f(acc[m][n][r]));
    }
  }
  __syncthreads();
  u16* Cb = adj + (size_t)z*L_SEQ*L_SEQ;
  // C tile is 128 u16 wide = 16 uint4 chunks per row; 2048 chunks total
  #pragma unroll
  for (int i=0;i<8;i++){
    int idx = i*256 + t;
    int r = idx>>4, cc = (idx&15)*8;
    uint4 v = *(const uint4*)&Cs[r*128 + cc];
    *(uint4*)((char*)Cb + (size_t)(i0+r)*2816 + (j0+cc)*2) = v;
  }
}

// ---------------- generic MFMA GEMM: C = f(A@B + bias) ----------------
template<int OUTBF16,int ACT,int TRANSOUT>
__global__ __launch_bounds__(256) void gemm_mfma_kernel(const u16* __restrict__ A,
                                                        const u16* __restrict__ BT,
                                                        const float* __restrict__ bias,
                                                        void* __restrict__ outp,
                                                        int M, int N, int K){
  __shared__ u16 As[128*64], Bs[128*64];
  int i0 = blockIdx.x*128, j0 = blockIdx.y*128;
  int t = threadIdx.x, lane=t&63, w=t>>6, wm=w>>1, wn=w&1;
  int fr=lane&15, kb=(lane>>4)*8;
  f4v acc[4][4];
  #pragma unroll
  for (int m=0;m<4;m++)
    #pragma unroll
    for (int n=0;n<4;n++) acc[m][n]=(f4v){0.f,0.f,0.f,0.f};
  size_t strA=(size_t)K*2;
  const char* Ab = (const char*)A + (size_t)i0*strA;
  const char* Bb = (const char*)BT + (size_t)j0*strA;
  for (int k0=0;k0<K;k0+=64){
    stage_tile(Ab + (size_t)k0*2, strA, As, 128, t);
    stage_tile(Bb + (size_t)k0*2, strA, Bs, 128, t);
    __syncthreads();
    #pragma unroll
    for (int kk=0;kk<2;kk++){
      s8v a[4], bv[4];
      #pragma unroll
      for (int m=0;m<4;m++) a[m]=ldfrag(As, wm*64+m*16+fr, kk*32+kb);
      #pragma unroll
      for (int n=0;n<4;n++) bv[n]=ldfrag(Bs, wn*64+n*16+fr, kk*32+kb);
      #pragma unroll
      for (int m=0;m<4;m++)
        #pragma unroll
        for (int n=0;n<4;n++) acc[m][n]=MFMA(a[m],bv[n],acc[m][n]);
    }
    __syncthreads();
  }
  #pragma unroll
  for (int m=0;m<4;m++){
    int row = i0 + wm*64+m*16+(lane>>4)*4;
    #pragma unroll
    for (int n=0;n<4;n++){
      int col = j0 + wn*64+n*16+fr;
      float bb = bias[col];
      #pragma unroll
      for (int r=0;r<4;r++){
        float v = acc[m][n][r]+bb;
        if (ACT) v = gelu_f(v);
        if (TRANSOUT) ((u16*)outp)[(size_t)col*M + row + r] = f2bf(v);
        else if (OUTBF16) ((u16*)outp)[(size_t)(row+r)*N+col] = f2bf(v);
        else ((float*)outp)[(size_t)(row+r)*N+col] = v;
      }
    }
  }
}

// ---------------- split-K GEMM partial: P[z] = A@B over K slice ----------------
__global__ __launch_bounds__(256) void gemm_ks_kernel(const u16* __restrict__ A,
                                                      const u16* __restrict__ BT,
                                                      float* __restrict__ P,
                                                      int M, int N, int K, int KS){
  __shared__ u16 As[128*64], Bs[128*64];
  int i0 = blockIdx.x*128, j0 = blockIdx.y*128;
  int kbeg = blockIdx.z*KS;
  int t = threadIdx.x, lane=t&63, w=t>>6, wm=w>>1, wn=w&1;
  int fr=lane&15, kb=(lane>>4)*8;
  f4v acc[4][4];
  #pragma unroll
  for (int m=0;m<4;m++)
    #pragma unroll
    for (int n=0;n<4;n++) acc[m][n]=(f4v){0.f,0.f,0.f,0.f};
  size_t strA=(size_t)K*2;
  const char* Ab = (const char*)A + (size_t)i0*strA;
  const char* Bb = (const char*)BT + (size_t)j0*strA;
  for (int k0=kbeg; k0<kbeg+KS; k0+=64){
    stage_tile(Ab + (size_t)k0*2, strA, As, 128, t);
    stage_tile(Bb + (size_t)k0*2, strA, Bs, 128, t);
    __syncthreads();
    #pragma unroll
    for (int kk=0;kk<2;kk++){
      s8v a[4], bv[4];
      #pragma unroll
      for (int m=0;m<4;m++) a[m]=ldfrag(As, wm*64+m*16+fr, kk*32+kb);
      #pragma unroll
      for (int n=0;n<4;n++) bv[n]=ldfrag(Bs, wn*64+n*16+fr, kk*32+kb);
      #pragma unroll
      for (int m=0;m<4;m++)
        #pragma unroll
        for (int n=0;n<4;n++) acc[m][n]=MFMA(a[m],bv[n],acc[m][n]);
    }
    __syncthreads();
  }
  float* Pz = P + (size_t)blockIdx.z*M*N;
  #pragma unroll
  for (int m=0;m<4;m++){
    int row = i0 + wm*64+m*16+(lane>>4)*4;
    #pragma unroll
    for (int n=0;n<4;n++){
      int col = j0 + wn*64+n*16+fr;
      #pragma unroll
      for (int r=0;r<4;r++) Pz[(size_t)(row+r)*N+col] = acc[m][n][r];
    }
  }
}

// ---------------- FFN2 epilogue: out = P0+P1+x1+bias ----------------
__global__ __launch_bounds__(256) void add9_kernel(const float* __restrict__ P,
                                                   const float* __restrict__ x1,
                                                   const float* __restrict__ bias,
                                                   float* __restrict__ out){
  int idx = blockIdx.x*256 + threadIdx.x;   // float4 index
  const float4* P0 = (const float4*)P;
  const float4* P1 = (const float4*)(P + (size_t)ROWS*DMODEL);
  const float4* X  = (const float4*)x1;
  const float4* B4 = (const float4*)bias;
  float4 a = P0[idx], b = P1[idx], c = X[idx], d = B4[idx & 127];
  float4 o; o.x=a.x+b.x+c.x+d.x; o.y=a.y+b.y+c.y+d.y; o.z=a.z+b.z+c.z+d.z; o.w=a.w+b.w+c.w+d.w;
  ((float4*)out)[idx] = o;
}

// ---------------- graph conv split-K partial: P[ks] = adjn @ xp ----------------
__global__ __launch_bounds__(256) void gc_ks_kernel(const u16* __restrict__ adj,
                                                    const u16* __restrict__ xpt,
                                                    float* __restrict__ P){
  __shared__ u16 As[128*64], Bs[64*64];
  int z = blockIdx.z, b = z>>3, h = z&7;
  int i0 = blockIdx.x*128;
  int kbeg = blockIdx.y*704;
  int t = threadIdx.x, lane=t&63, w=t>>6, wm=w>>1, wn=w&1;
  int fr=lane&15, kb=(lane>>4)*8;
  const char* Ab = (const char*)(adj + (size_t)z*L_SEQ*L_SEQ) + (size_t)i0*2816;
  const char* Bb = (const char*)xpt + (size_t)(h*64)*5632 + (size_t)(b*L_SEQ)*2;
  f4v acc[4][2];
  #pragma unroll
  for (int m=0;m<4;m++){ acc[m][0]=(f4v){0.f,0.f,0.f,0.f}; acc[m][1]=(f4v){0.f,0.f,0.f,0.f}; }
  for (int k0=kbeg; k0<kbeg+704; k0+=64){
    stage_tile(Ab + (size_t)k0*2, 2816, As, 128, t);
    stage_tile(Bb + (size_t)k0*2, 5632, Bs, 64, t);
    __syncthreads();
    #pragma unroll
    for (int kk=0;kk<2;kk++){
      s8v a[4], bv[2];
      #pragma unroll
      for (int m=0;m<4;m++) a[m]=ldfrag(As, wm*64+m*16+fr, kk*32+kb);
      #pragma unroll
      for (int n=0;n<2;n++) bv[n]=ldfrag(Bs, wn*32+n*16+fr, kk*32+kb);
      #pragma unroll
      for (int m=0;m<4;m++)
        #pragma unroll
        for (int n=0;n<2;n++) acc[m][n]=MFMA(a[m],bv[n],acc[m][n]);
    }
    __syncthreads();
  }
  float* Pz = P + (size_t)blockIdx.y*ROWS*DMODEL;
  #pragma unroll
  for (int m=0;m<4;m++){
    int rl = i0 + wm*64+m*16+(lane>>4)*4;
    #pragma unroll
    for (int n=0;n<2;n++){
      int col = h*64 + wn*32+n*16+fr;
      #pragma unroll
      for (int r=0;r<4;r++)
        Pz[(size_t)(b*L_SEQ + rl + r)*DMODEL + col] = acc[m][n][r];
    }
  }
}

// ---------------- per-row pipeline: one WAVE per row, ballot binary-search select ----------------
__global__ __launch_bounds__(256) void row_pipe2_kernel(u16* __restrict__ adj,
                                                        const float* __restrict__ wg,
                                                        const float* __restrict__ masks,
                                                        float* __restrict__ spz,
                                                        float* __restrict__ entp){
  __shared__ float wgT[3][L_SEQ];
  int t = threadIdx.x, lane = t&63, w = t>>6;
  for (int idx=t; idx<3*L_SEQ; idx+=256){
    float v = wg[idx];
    int e = idx/3, j = idx - 3*e;
    wgT[j][e] = v;
  }
  __syncthreads();

  int rid = blockIdx.x*4 + w;
  int z = rid / L_SEQ;
  int l = rid - z*L_SEQ;
  unsigned* rowp = (unsigned*)(adj + (size_t)rid*L_SEQ);

  unsigned klo[11], khi[11];
  float x0[11], x1[11];
  #pragma unroll
  for (int i=0;i<11;i++){
    unsigned r = rowp[i*64 + lane];
    unsigned lo = r&0xFFFFu, hi = r>>16;
    klo[i] = key16(lo); khi[i] = key16(hi);
    x0[i] = b2f(lo); x1[i] = b2f(hi);
  }

  // --- 16-step ballot binary search for threshold key (bare v_cmp per value/step) ---
  unsigned thr = 0; int cnt_thr = 0;
  #pragma unroll
  for (int b=15;b>=0;b--){
    unsigned cand = thr | (1u<<b);
    int cnt = 0;
    #pragma unroll
    for (int i=0;i<11;i++){
      cnt += __popcll(__ballot(klo[i] < cand));
      cnt += __popcll(__ballot(khi[i] < cand));
    }
    if ((unsigned)cnt < KSEL){ thr = cand; cnt_thr = cnt; }
  }
  int z_eq = (int)(KSEL - cnt_thr);   // # entries equal to thr to zero, lowest index first

  // tie zeroing in global index order: pairs (lane,j) interleaved within step i
  unsigned long long mlt = (1ull<<lane)-1ull;
  int cnt = 0;
  #pragma unroll
  for (int i=0;i<11;i++){
    bool act = (cnt < z_eq);
    bool eq0 = act && (klo[i]==thr);
    bool eq1 = act && (khi[i]==thr);
    unsigned long long b0 = __ballot(eq0), b1 = __ballot(eq1);
    int pre0 = __popcll(b0&mlt) + __popcll(b1&mlt);
    int pre1 = pre0 + (eq0?1:0);
    if (eq0 && cnt+pre0 < z_eq) x0[i]=0.f;
    if (eq1 && cnt+pre1 < z_eq) x1[i]=0.f;
    cnt += __popcll(b0)+__popcll(b1);
  }
  // zero everything strictly below threshold
  #pragma unroll
  for (int i=0;i<11;i++){
    if (klo[i] < thr) x0[i]=0.f;
    if (khi[i] < thr) x1[i]=0.f;
  }

  // --- gating: p_j = sum x * wg[:,j] ---
  float p0=0.f, p1=0.f, p2=0.f;
  #pragma unroll
  for (int i=0;i<11;i++){
    int e0 = 2*(i*64+lane);
    float2 w0 = *(const float2*)&wgT[0][e0];
    float2 w1 = *(const float2*)&wgT[1][e0];
    float2 w2 = *(const float2*)&wgT[2][e0];
    p0 += x0[i]*w0.x + x1[i]*w0.y;
    p1 += x0[i]*w1.x + x1[i]*w1.y;
    p2 += x0[i]*w2.x + x1[i]*w2.y;
  }
  #pragma unroll
  for (int o=1;o<64;o<<=1){
    p0 += __shfl_xor(p0,o,64);
    p1 += __shfl_xor(p1,o,64);
    p2 += __shfl_xor(p2,o,64);
  }
  float mx = fmaxf(p0, fmaxf(p1,p2));
  float e0s=__expf(p0-mx), e1s=__expf(p1-mx), e2s=__expf(p2-mx);
  float inv = __builtin_amdgcn_rcpf(e0s+e1s+e2s);
  float pr[3]={e0s*inv, e1s*inv, e2s*inv};
  int i0=0; if (pr[1]>pr[i0]) i0=1; if (pr[2]>pr[i0]) i0=2;
  int a_=(i0==0)?1:0, b_=(i0==2)?1:2;
  int i1 = (pr[b_]>pr[a_])?b_:a_;
  bool top2 = !(pr[i0] > 0.5f);
  bool g0=(i0==0)||(top2&&i1==0);
  bool g1=(i0==1)||(top2&&i1==1);
  bool g2=(i0==2)||(top2&&i1==2);
  if (lane==0){
    float ent = pr[0]*__logf(pr[0]+1e-10f)+pr[1]*__logf(pr[1]+1e-10f)+pr[2]*__logf(pr[2]+1e-10f);
    atomicAdd(&entp[rid & 255], ent);
    atomicAdd(&spz[l*3+0], pr[i0]);
    if (top2) atomicAdd(&spz[l*3+1], pr[i1]);
  }

  // --- final mask + softmax ---
  const float* m0 = masks + ((size_t)l*3+0)*L_SEQ;
  const float* m1 = m0 + L_SEQ;
  const float* m2 = m1 + L_SEQ;
  float mxv = -3.0e38f;
  #pragma unroll
  for (int i=0;i<11;i++){
    int e0 = 2*(i*64+lane);
    float fm0 = (e0==l)?1.f:0.f, fm1 = (e0+1==l)?1.f:0.f;
    if (g0){ float2 v=*(const float2*)&m0[e0]; fm0+=v.x; fm1+=v.y; }
    if (g1){ float2 v=*(const float2*)&m1[e0]; fm0+=v.x; fm1+=v.y; }
    if (g2){ float2 v=*(const float2*)&m2[e0]; fm0+=v.x; fm1+=v.y; }
    x0[i] *= fm0; x1[i] *= fm1;
    mxv = fmaxf(mxv, fmaxf(x0[i], x1[i]));
  }
  #pragma unroll
  for (int o=1;o<64;o<<=1) mxv = fmaxf(mxv, __shfl_xor(mxv,o,64));
  float sum=0.f;
  #pragma unroll
  for (int i=0;i<11;i++){
    x0[i] = __expf(x0[i]-mxv);
    x1[i] = __expf(x1[i]-mxv);
    sum += x0[i]+x1[i];
  }
  #pragma unroll
  for (int o=1;o<64;o<<=1) sum += __shfl_xor(sum,o,64);
  float invs = __builtin_amdgcn_rcpf(sum);
  #pragma unroll
  for (int i=0;i<11;i++){
    unsigned lo = f2bf(x0[i]*invs), hi = f2bf(x1[i]*invs);
    rowp[i*64+lane] = lo | (hi<<16);
  }
}

// ---------------- loss finalize ----------------
__global__ __launch_bounds__(256) void loss_kernel(const float* __restrict__ spz,
                                                   const float* __restrict__ entp,
                                                   float* __restrict__ out){
  int t = threadIdx.x;
  float sum=0.f;
  for (int i=t;i<4224;i+=256) sum += spz[i];
  sum = block_reduce_sum(sum);
  float mu = sum/4224.f;
  float ss=0.f;
  for (int i=t;i<4224;i+=256){ float d=spz[i]-mu; ss+=d*d; }
  ss = block_reduce_sum(ss);
  float ent = block_reduce_sum(entp[t]);
  if (t==0){
    float var = ss/4223.f;
    float li = var/(mu*mu+1e-10f);
    float ld = -ent/48.f;
    out[0] = li + 0.1f*ld;
  }
}

extern "C" void kernel_launch(void* const* d_in, const int* in_sizes, int n_in,
                              void* d_out, int out_size, void* d_ws, size_t ws_size,
                              hipStream_t stream) {
  const float* x     = (const float*)d_in[0];
  const float* masks = (const float*)d_in[1];
  const float* ln1_g = (const float*)d_in[2];
  const float* ln1_b = (const float*)d_in[3];
  const float* w_p1  = (const float*)d_in[4];
  const float* b_p1  = (const float*)d_in[5];
  const float* w_p2  = (const float*)d_in[6];
  const float* b_p2  = (const float*)d_in[7];
  const float* w_gate= (const float*)d_in[8];
  const float* w_gcn = (const float*)d_in[9];
  const float* b_gcn = (const float*)d_in[10];
  const float* ln2_g = (const float*)d_in[11];
  const float* ln2_b = (const float*)d_in[12];
  const float* w_f1  = (const float*)d_in[13];
  const float* b_f1  = (const float*)d_in[14];
  const float* w_f2  = (const float*)d_in[15];
  const float* b_f2  = (const float*)d_in[16];
  float* out = (float*)d_out;

  char* wsb = (char*)d_ws;
  size_t off = 0;
  u16* adj   = (u16*)(wsb+off); off += (size_t)BH*L_SEQ*L_SEQ*2;  // 63.4 MB
  u16* xn    = (u16*)(wsb+off); off += (size_t)ROWS*DMODEL*2;
  u16* q     = (u16*)(wsb+off); off += (size_t)BH*L_SEQ*64*2;
  u16* kk    = (u16*)(wsb+off); off += (size_t)BH*L_SEQ*64*2;
  u16* xpt   = (u16*)(wsb+off); off += (size_t)DMODEL*ROWS*2;     // [512][2816]
  u16* xn2   = (u16*)(wsb+off); off += (size_t)ROWS*DMODEL*2;
  float* x1  = (float*)(wsb+off); off += (size_t)ROWS*DMODEL*4;
  float* Pk  = (float*)(wsb+off); off += (size_t)2*ROWS*DMODEL*4; // split-K partials (gc, then ffn2)
  u16* wgcnT = (u16*)(wsb+off); off += (size_t)DMODEL*DMODEL*2;
  u16* wf1T  = (u16*)(wsb+off); off += (size_t)DFF*DMODEL*2;
  u16* wf2T  = (u16*)(wsb+off); off += (size_t)DMODEL*DFF*2;
  float* spz = (float*)(wsb+off); off += 4224*4;
  float* entp= (float*)(wsb+off); off += 256*4;
  u16* ffh   = adj;   // reuse after graph conv

  hipMemsetAsync(spz, 0, (4224+256)*sizeof(float), stream);

  // weight transpose-casts (one launch)
  castT_all_kernel<<<dim3(2304), 256, 0, stream>>>(w_gcn, wgcnT, w_f1, wf1T, w_f2, wf2T);

  // 1. LN1
  ln_kernel<<<ROWS, 256, 0, stream>>>(x, ln1_g, ln1_b, xn);
  // 2. Q/K projections
  qk_proj_kernel<<<ROWS/8, 512, 0, stream>>>(xn, w_p1, b_p1, w_p2, b_p2, q, kk);
  // 3. adj = gelu(Q K^T)
  qkt_mfma_kernel<<<dim3(11,11,BH), 256, 0, stream>>>(q, kk, adj);
  // 4. per-row pipeline (wave per row)
  row_pipe2_kernel<<<dim3(BH*L_SEQ/4), 256, 0, stream>>>(adj, w_gate, masks, spz, entp);
  // 5. xp^T = (xn @ w_gcn + b_gcn)^T
  gemm_mfma_kernel<0,0,1><<<dim3(22,4), 256, 0, stream>>>(xn, wgcnT, b_gcn, xpt, ROWS, DMODEL, DMODEL);
  // 6. gc partials (split-K 2)
  gc_ks_kernel<<<dim3(11,2,BH), 256, 0, stream>>>(adj, xpt, Pk);
  // 7. x1 = x+P0+P1 ; xn2 = LN2(x1)
  ln2_fuse_kernel<<<ROWS, 256, 0, stream>>>(x, Pk, ln2_g, ln2_b, x1, xn2);
  // 8. ffh = gelu(xn2 @ w_f1 + b_f1)
  gemm_mfma_kernel<1,1,0><<<dim3(22,16), 256, 0, stream>>>(xn2, wf1T, b_f1, ffh, ROWS, DFF, DMODEL);
  // 9. FFN2 partials (split-K 2) then epilogue
  gemm_ks_kernel<<<dim3(22,4,2), 256, 0, stream>>>(ffh, wf2T, Pk, ROWS, DMODEL, DFF, DFF/2);
  add9_kernel<<<dim3(ROWS*DMODEL/1024), 256, 0, stream>>>(Pk, x1, b_f2, out);
  // 10. loss
  loss_kernel<<<1, 256, 0, stream>>>(spz, entp, out + (size_t)ROWS*DMODEL);
}

// Round 7
// 270.395 us; speedup vs baseline: 4.2829x; 1.0859x over previous
//
#include <hip/hip_runtime.h>

#define L_SEQ 1408
#define DMODEL 512
#define NH 8
#define BATCH 2
#define BH 16
#define ROWS 2816
#define DFF 2048
#define KSEL 704

typedef unsigned short u16;
typedef short s8v __attribute__((ext_vector_type(8)));
typedef float f4v __attribute__((ext_vector_type(4)));

// scalar popcount of a 64-bit ballot (SALU, overlaps VALU)
#define SPOPC(b, out) asm("s_bcnt1_i32_b64 %0, %1" : "=s"(out) : "s"(b))

// fast gelu: x*sigmoid(1.59577(x+.044715x^3)); max abs err ~1e-3 < bf16 quantization
__device__ __forceinline__ float gelu_f(float x){
  float u = 1.595769122f*(x + 0.044715f*x*x*x);
  return x * __builtin_amdgcn_rcpf(1.0f + __expf(-u));
}
__device__ __forceinline__ u16 f2bf(float f){
  unsigned u = __float_as_uint(f);
  u += 0x7fffu + ((u>>16)&1u);
  return (u16)(u>>16);
}
__device__ __forceinline__ float b2f(unsigned h){ return __uint_as_float(h<<16); }
__device__ __forceinline__ unsigned key16(unsigned h){
  return (h & 0x8000u) ? (0xFFFFu & ~h) : (h | 0x8000u);
}

__device__ __forceinline__ f4v MFMA(s8v a, s8v b, f4v c){
  return __builtin_amdgcn_mfma_f32_16x16x32_bf16(a, b, c, 0, 0, 0);
}

// all LDS tiles have 128-byte rows (64 bf16); XOR swizzle spreads banks
__device__ __forceinline__ s8v ldfrag(const u16* lds, int row, int kb){
  return *(const s8v*)((const char*)lds + row*128 + ((kb*2) ^ ((row&7)<<4)));
}
__device__ __forceinline__ void stage_tile(const char* g, size_t gstride, u16* lds, int nrows, int t){
  int nch = nrows*8;
  for (int ci = t; ci < nch; ci += 256){
    int row = ci>>3, kc = (ci&7)*16;
    uint4 v = *(const uint4*)(g + (size_t)row*gstride + kc);
    *(uint4*)((char*)lds + row*128 + (kc ^ ((row&7)<<4))) = v;
  }
}

__device__ __forceinline__ float block_reduce_sum(float v){
  __shared__ float sred[8];
  int lane = threadIdx.x & 63, w = threadIdx.x >> 6;
  #pragma unroll
  for (int o=32;o>0;o>>=1) v += __shfl_down(v,o,64);
  if (lane==0) sred[w]=v;
  __syncthreads();
  if (w==0){
    float x = (lane < (int)(blockDim.x>>6)) ? sred[lane] : 0.f;
    #pragma unroll
    for (int o=4;o>0;o>>=1) x += __shfl_down(x,o,64);
    if (lane==0) sred[0]=x;
  }
  __syncthreads();
  float r = sred[0];
  __syncthreads();
  return r;
}

// ---------------- LN body (used by prep and ln2_fuse variants) ----------------
__device__ __forceinline__ void ln_body(const float* xr, const float* g, const float* b,
                                        u16* orow, int t, float v0, float v1){
  float s = block_reduce_sum(v0+v1);
  float mean = s * (1.f/512.f);
  float d0 = v0-mean, d1 = v1-mean;
  float ss = block_reduce_sum(d0*d0 + d1*d1);
  float rstd = rsqrtf(ss*(1.f/512.f) + 1e-5f);
  orow[t]     = f2bf(d0*rstd*g[t]     + b[t]);
  orow[t+256] = f2bf(d1*rstd*g[t+256] + b[t+256]);
}

// ---------------- transpose-cast tile helper ----------------
__device__ __forceinline__ void castT_tile(const float* in, u16* outT, int K, int N,
                                           int k0, int n0, int t){
  __shared__ u16 tl[32][33];
  int r = t>>5, c = t&31;
  #pragma unroll
  for (int i=0;i<4;i++){
    int rr = r + i*8;
    tl[rr][c] = f2bf(in[(size_t)(k0+rr)*N + n0 + c]);
  }
  __syncthreads();
  #pragma unroll
  for (int i=0;i<4;i++){
    int rr = r + i*8;
    outT[(size_t)(n0+rr)*K + k0 + c] = tl[c][rr];
  }
}

// ---------------- prep: all weight transpose-casts + LN1 in one launch ----------------
__global__ __launch_bounds__(256) void prep_kernel(const float* __restrict__ w_gcn, u16* __restrict__ wgcnT,
                                                   const float* __restrict__ w_f1,  u16* __restrict__ wf1T,
                                                   const float* __restrict__ w_f2,  u16* __restrict__ wf2T,
                                                   const float* __restrict__ w_p1,  u16* __restrict__ wp1T,
                                                   const float* __restrict__ w_p2,  u16* __restrict__ wp2T,
                                                   const float* __restrict__ x,
                                                   const float* __restrict__ g,
                                                   const float* __restrict__ b,
                                                   u16* __restrict__ xn){
  int blk = blockIdx.x, t = threadIdx.x;
  if (blk < 256){
    castT_tile(w_gcn, wgcnT, DMODEL, DMODEL, (blk>>4)*32, (blk&15)*32, t);
  } else if (blk < 1280){
    int lo = blk - 256;
    castT_tile(w_f1, wf1T, DMODEL, DFF, (lo&15)*32, (lo>>4)*32, t);
  } else if (blk < 2304){
    int lo = blk - 1280;
    castT_tile(w_f2, wf2T, DFF, DMODEL, (lo&63)*32, (lo>>6)*32, t);
  } else if (blk < 2308){
    int lo = blk - 2304;
    castT_tile(w_p1, wp1T, 64, 64, (lo>>1)*32, (lo&1)*32, t);
  } else if (blk < 2312){
    int lo = blk - 2308;
    castT_tile(w_p2, wp2T, 64, 64, (lo>>1)*32, (lo&1)*32, t);
  } else {
    int row = blk - 2312;
    const float* xr = x + (size_t)row*DMODEL;
    ln_body(xr, g, b, xn + (size_t)row*DMODEL, t, xr[t], xr[t+256]);
  }
}

// ---------------- fused x1 = x+P0+P1 ; xn2 = LN(x1) ----------------
__global__ __launch_bounds__(256) void ln2_fuse_kernel(const float* __restrict__ x,
                                                       const float* __restrict__ P,
                                                       const float* __restrict__ g,
                                                       const float* __restrict__ b,
                                                       float* __restrict__ x1,
                                                       u16* __restrict__ xn2){
  int row = blockIdx.x, t = threadIdx.x;
  size_t base = (size_t)row*DMODEL;
  const float* P1 = P + (size_t)ROWS*DMODEL;
  float v0 = x[base+t]     + P[base+t]     + P1[base+t];
  float v1 = x[base+t+256] + P[base+t+256] + P1[base+t+256];
  x1[base+t] = v0; x1[base+t+256] = v1;
  ln_body(nullptr, g, b, xn2 + base, t, v0, v1);
}

// ---------------- Q/K projections via MFMA: M=ROWS*8, N=64, K=64 ----------------
// A = xn viewed as [22528][64] (contiguous); B = wp1T/wp2T [64][64] (j,k)
__global__ __launch_bounds__(256) void qk_mfma_kernel(const u16* __restrict__ xn,
                                                      const u16* __restrict__ wp1T,
                                                      const u16* __restrict__ wp2T,
                                                      const float* __restrict__ bp1,
                                                      const float* __restrict__ bp2,
                                                      u16* __restrict__ q, u16* __restrict__ k){
  __shared__ u16 As[128*64], W1[64*64], W2[64*64];
  int m0 = blockIdx.x*128;
  int t = threadIdx.x, lane=t&63, w=t>>6;
  stage_tile((const char*)xn + (size_t)m0*128, 128, As, 128, t);
  stage_tile((const char*)wp1T, 128, W1, 64, t);
  stage_tile((const char*)wp2T, 128, W2, 64, t);
  __syncthreads();
  int fr=lane&15, kb=(lane>>4)*8;
  f4v aq[2][4], ak[2][4];
  #pragma unroll
  for (int mi=0;mi<2;mi++)
    #pragma unroll
    for (int n=0;n<4;n++){ aq[mi][n]=(f4v){0.f,0.f,0.f,0.f}; ak[mi][n]=(f4v){0.f,0.f,0.f,0.f}; }
  #pragma unroll
  for (int kk=0;kk<2;kk++){
    s8v a[2], b1[4], b2[4];
    #pragma unroll
    for (int mi=0;mi<2;mi++) a[mi] = ldfrag(As, w*32+mi*16+fr, kk*32+kb);
    #pragma unroll
    for (int n=0;n<4;n++){ b1[n]=ldfrag(W1, n*16+fr, kk*32+kb); b2[n]=ldfrag(W2, n*16+fr, kk*32+kb); }
    #pragma unroll
    for (int mi=0;mi<2;mi++)
      #pragma unroll
      for (int n=0;n<4;n++){
        aq[mi][n] = MFMA(a[mi], b1[n], aq[mi][n]);
        ak[mi][n] = MFMA(a[mi], b2[n], ak[mi][n]);
      }
  }
  #pragma unroll
  for (int mi=0;mi<2;mi++){
    #pragma unroll
    for (int n=0;n<4;n++){
      int j = n*16 + fr;
      float bq = bp1[j], bk = bp2[j];
      #pragma unroll
      for (int r=0;r<4;r++){
        int m = m0 + w*32 + mi*16 + (lane>>4)*4 + r;
        int bl = m>>3, h = m&7;
        int b_ = bl / L_SEQ, l = bl - b_*L_SEQ;
        size_t o = (((size_t)(b_*NH+h))*L_SEQ + l)*64 + j;
        q[o] = f2bf(aq[mi][n][r] + bq);
        k[o] = f2bf(ak[mi][n][r] + bk);
      }
    }
  }
}

// ---------------- adj = gelu(Q K^T), LDS-staged coalesced store ----------------
__global__ __launch_bounds__(256) void qkt_mfma_kernel(const u16* __restrict__ q,
                                                       const u16* __restrict__ k,
                                                       u16* __restrict__ adj){
  __shared__ u16 sbuf[128*128];
  u16* Qs = sbuf; u16* Ks = sbuf + 128*64; u16* Cs = sbuf;
  int z = blockIdx.z;
  int i0 = blockIdx.x*128, j0 = blockIdx.y*128;
  int t = threadIdx.x;
  const char* Qb = (const char*)(q + (size_t)z*L_SEQ*64) + (size_t)i0*128;
  const char* Kb = (const char*)(k + (size_t)z*L_SEQ*64) + (size_t)j0*128;
  stage_tile(Qb, 128, Qs, 128, t);
  stage_tile(Kb, 128, Ks, 128, t);
  __syncthreads();
  int lane = t&63, w = t>>6, wm = w>>1, wn = w&1;
  int fr = lane&15, kb = (lane>>4)*8;
  f4v acc[4][4];
  #pragma unroll
  for (int m=0;m<4;m++)
    #pragma unroll
    for (int n=0;n<4;n++) acc[m][n]=(f4v){0.f,0.f,0.f,0.f};
  #pragma unroll
  for (int kk=0;kk<2;kk++){
    s8v a[4], bv[4];
    #pragma unroll
    for (int m=0;m<4;m++) a[m] = ldfrag(Qs, wm*64+m*16+fr, kk*32+kb);
    #pragma unroll
    for (int n=0;n<4;n++) bv[n] = ldfrag(Ks, wn*64+n*16+fr, kk*32+kb);
    #pragma unroll
    for (int m=0;m<4;m++)
      #pragma unroll
      for (int n=0;n<4;n++) acc[m][n] = MFMA(a[m], bv[n], acc[m][n]);
  }
  __syncthreads();
  #pragma unroll
  for (int m=0;m<4;m++){
    int row = wm*64 + m*16 + (lane>>4)*4;
    #pragma unroll
    for (int n=0;n<4;n++){
      int col = wn*64 + n*16 + fr;
      #pragma unroll
      for (int r=0;r<4;r++)
        Cs[(row+r)*128 + col] = f2bf(gelu_f(acc[m][n][r]));
    }
  }
  __syncthreads();
  u16* Cb = adj + (size_t)z*L_SEQ*L_SEQ;
  #pragma unroll
  for (int i=0;i<8;i++){
    int idx = i*256 + t;
    int r = idx>>4, cc = (idx&15)*8;
    uint4 v = *(const uint4*)&Cs[r*128 + cc];
    *(uint4*)((char*)Cb + (size_t)(i0+r)*2816 + (j0+cc)*2) = v;
  }
}

// ---------------- generic MFMA GEMM: C = f(A@B + bias) ----------------
template<int OUTBF16,int ACT,int TRANSOUT>
__global__ __launch_bounds__(256) void gemm_mfma_kernel(const u16* __restrict__ A,
                                                        const u16* __restrict__ BT,
                                                        const float* __restrict__ bias,
                                                        void* __restrict__ outp,
                                                        int M, int N, int K){
  __shared__ u16 As[128*64], Bs[128*64];
  int i0 = blockIdx.x*128, j0 = blockIdx.y*128;
  int t = threadIdx.x, lane=t&63, w=t>>6, wm=w>>1, wn=w&1;
  int fr=lane&15, kb=(lane>>4)*8;
  f4v acc[4][4];
  #pragma unroll
  for (int m=0;m<4;m++)
    #pragma unroll
    for (int n=0;n<4;n++) acc[m][n]=(f4v){0.f,0.f,0.f,0.f};
  size_t strA=(size_t)K*2;
  const char* Ab = (const char*)A + (size_t)i0*strA;
  const char* Bb = (const char*)BT + (size_t)j0*strA;
  for (int k0=0;k0<K;k0+=64){
    stage_tile(Ab + (size_t)k0*2, strA, As, 128, t);
    stage_tile(Bb + (size_t)k0*2, strA, Bs, 128, t);
    __syncthreads();
    #pragma unroll
    for (int kk=0;kk<2;kk++){
      s8v a[4], bv[4];
      #pragma unroll
      for (int m=0;m<4;m++) a[m]=ldfrag(As, wm*64+m*16+fr, kk*32+kb);
      #pragma unroll
      for (int n=0;n<4;n++) bv[n]=ldfrag(Bs, wn*64+n*16+fr, kk*32+kb);
      #pragma unroll
      for (int m=0;m<4;m++)
        #pragma unroll
        for (int n=0;n<4;n++) acc[m][n]=MFMA(a[m],bv[n],acc[m][n]);
    }
    __syncthreads();
  }
  #pragma unroll
  for (int m=0;m<4;m++){
    int row = i0 + wm*64+m*16+(lane>>4)*4;
    #pragma unroll
    for (int n=0;n<4;n++){
      int col = j0 + wn*64+n*16+fr;
      float bb = bias[col];
      #pragma unroll
      for (int r=0;r<4;r++){
        float v = acc[m][n][r]+bb;
        if (ACT) v = gelu_f(v);
        if (TRANSOUT) ((u16*)outp)[(size_t)col*M + row + r] = f2bf(v);
        else if (OUTBF16) ((u16*)outp)[(size_t)(row+r)*N+col] = f2bf(v);
        else ((float*)outp)[(size_t)(row+r)*N+col] = v;
      }
    }
  }
}

// ---------------- split-K GEMM partial: P[z] = A@B over K slice ----------------
__global__ __launch_bounds__(256) void gemm_ks_kernel(const u16* __restrict__ A,
                                                      const u16* __restrict__ BT,
                                                      float* __restrict__ P,
                                                      int M, int N, int K, int KS){
  __shared__ u16 As[128*64], Bs[128*64];
  int i0 = blockIdx.x*128, j0 = blockIdx.y*128;
  int kbeg = blockIdx.z*KS;
  int t = threadIdx.x, lane=t&63, w=t>>6, wm=w>>1, wn=w&1;
  int fr=lane&15, kb=(lane>>4)*8;
  f4v acc[4][4];
  #pragma unroll
  for (int m=0;m<4;m++)
    #pragma unroll
    for (int n=0;n<4;n++) acc[m][n]=(f4v){0.f,0.f,0.f,0.f};
  size_t strA=(size_t)K*2;
  const char* Ab = (const char*)A + (size_t)i0*strA;
  const char* Bb = (const char*)BT + (size_t)j0*strA;
  for (int k0=kbeg; k0<kbeg+KS; k0+=64){
    stage_tile(Ab + (size_t)k0*2, strA, As, 128, t);
    stage_tile(Bb + (size_t)k0*2, strA, Bs, 128, t);
    __syncthreads();
    #pragma unroll
    for (int kk=0;kk<2;kk++){
      s8v a[4], bv[4];
      #pragma unroll
      for (int m=0;m<4;m++) a[m]=ldfrag(As, wm*64+m*16+fr, kk*32+kb);
      #pragma unroll
      for (int n=0;n<4;n++) bv[n]=ldfrag(Bs, wn*64+n*16+fr, kk*32+kb);
      #pragma unroll
      for (int m=0;m<4;m++)
        #pragma unroll
        for (int n=0;n<4;n++) acc[m][n]=MFMA(a[m],bv[n],acc[m][n]);
    }
    __syncthreads();
  }
  float* Pz = P + (size_t)blockIdx.z*M*N;
  #pragma unroll
  for (int m=0;m<4;m++){
    int row = i0 + wm*64+m*16+(lane>>4)*4;
    #pragma unroll
    for (int n=0;n<4;n++){
      int col = j0 + wn*64+n*16+fr;
      #pragma unroll
      for (int r=0;r<4;r++) Pz[(size_t)(row+r)*N+col] = acc[m][n][r];
    }
  }
}

// ---------------- graph conv split-K partial: P[ks] = adjn @ xp ----------------
__global__ __launch_bounds__(256) void gc_ks_kernel(const u16* __restrict__ adj,
                                                    const u16* __restrict__ xpt,
                                                    float* __restrict__ P){
  __shared__ u16 As[128*64], Bs[64*64];
  int z = blockIdx.z, b = z>>3, h = z&7;
  int i0 = blockIdx.x*128;
  int kbeg = blockIdx.y*704;
  int t = threadIdx.x, lane=t&63, w=t>>6, wm=w>>1, wn=w&1;
  int fr=lane&15, kb=(lane>>4)*8;
  const char* Ab = (const char*)(adj + (size_t)z*L_SEQ*L_SEQ) + (size_t)i0*2816;
  const char* Bb = (const char*)xpt + (size_t)(h*64)*5632 + (size_t)(b*L_SEQ)*2;
  f4v acc[4][2];
  #pragma unroll
  for (int m=0;m<4;m++){ acc[m][0]=(f4v){0.f,0.f,0.f,0.f}; acc[m][1]=(f4v){0.f,0.f,0.f,0.f}; }
  for (int k0=kbeg; k0<kbeg+704; k0+=64){
    stage_tile(Ab + (size_t)k0*2, 2816, As, 128, t);
    stage_tile(Bb + (size_t)k0*2, 5632, Bs, 64, t);
    __syncthreads();
    #pragma unroll
    for (int kk=0;kk<2;kk++){
      s8v a[4], bv[2];
      #pragma unroll
      for (int m=0;m<4;m++) a[m]=ldfrag(As, wm*64+m*16+fr, kk*32+kb);
      #pragma unroll
      for (int n=0;n<2;n++) bv[n]=ldfrag(Bs, wn*32+n*16+fr, kk*32+kb);
      #pragma unroll
      for (int m=0;m<4;m++)
        #pragma unroll
        for (int n=0;n<2;n++) acc[m][n]=MFMA(a[m],bv[n],acc[m][n]);
    }
    __syncthreads();
  }
  float* Pz = P + (size_t)blockIdx.y*ROWS*DMODEL;
  #pragma unroll
  for (int m=0;m<4;m++){
    int rl = i0 + wm*64+m*16+(lane>>4)*4;
    #pragma unroll
    for (int n=0;n<2;n++){
      int col = h*64 + wn*32+n*16+fr;
      #pragma unroll
      for (int r=0;r<4;r++)
        Pz[(size_t)(b*L_SEQ + rl + r)*DMODEL + col] = acc[m][n][r];
    }
  }
}

// ---------------- per-row pipeline: one WAVE per row, ballot binary-search select ----------------
__global__ __launch_bounds__(256) void row_pipe2_kernel(u16* __restrict__ adj,
                                                        const float* __restrict__ wg,
                                                        const float* __restrict__ masks,
                                                        float* __restrict__ spz,
                                                        float* __restrict__ entp){
  __shared__ float wgT[3][L_SEQ];
  int t = threadIdx.x, lane = t&63, w = t>>6;
  for (int idx=t; idx<3*L_SEQ; idx+=256){
    float v = wg[idx];
    int e = idx/3, j = idx - 3*e;
    wgT[j][e] = v;
  }
  __syncthreads();

  int rid = blockIdx.x*4 + w;
  int z = rid / L_SEQ;
  int l = rid - z*L_SEQ;
  unsigned* rowp = (unsigned*)(adj + (size_t)rid*L_SEQ);

  unsigned klo[11], khi[11];
  float x0[11], x1[11];
  #pragma unroll
  for (int i=0;i<11;i++){
    unsigned r = rowp[i*64 + lane];
    unsigned lo = r&0xFFFFu, hi = r>>16;
    klo[i] = key16(lo); khi[i] = key16(hi);
    x0[i] = b2f(lo); x1[i] = b2f(hi);
  }

  // --- 16-step ballot binary search; counts via SALU s_bcnt1 ---
  unsigned thr = 0; int cnt_thr = 0;
  #pragma unroll
  for (int b=15;b>=0;b--){
    unsigned cand = thr | (1u<<b);
    int cnt = 0;
    #pragma unroll
    for (int i=0;i<11;i++){
      unsigned long long b0 = __ballot(klo[i] < cand);
      unsigned long long b1 = __ballot(khi[i] < cand);
      int c0, c1; SPOPC(b0, c0); SPOPC(b1, c1);
      cnt += c0 + c1;
    }
    if ((unsigned)cnt < KSEL){ thr = cand; cnt_thr = cnt; }
  }
  int z_eq = (int)(KSEL - cnt_thr);   // # entries equal to thr to zero, lowest index first

  // tie zeroing in global index order; prefix via mbcnt (2 VALU), totals via SALU
  int cnt = 0;
  #pragma unroll
  for (int i=0;i<11;i++){
    bool act = (cnt < z_eq);
    bool eq0 = act && (klo[i]==thr);
    bool eq1 = act && (khi[i]==thr);
    unsigned long long b0 = __ballot(eq0), b1 = __ballot(eq1);
    int p0b = __builtin_amdgcn_mbcnt_hi((unsigned)(b0>>32), __builtin_amdgcn_mbcnt_lo((unsigned)b0, 0));
    int p1b = __builtin_amdgcn_mbcnt_hi((unsigned)(b1>>32), __builtin_amdgcn_mbcnt_lo((unsigned)b1, 0));
    int pre0 = p0b + p1b;
    int pre1 = pre0 + (eq0?1:0);
    if (eq0 && cnt+pre0 < z_eq) x0[i]=0.f;
    if (eq1 && cnt+pre1 < z_eq) x1[i]=0.f;
    int c0, c1; SPOPC(b0, c0); SPOPC(b1, c1);
    cnt += c0 + c1;
  }
  // zero everything strictly below threshold
  #pragma unroll
  for (int i=0;i<11;i++){
    if (klo[i] < thr) x0[i]=0.f;
    if (khi[i] < thr) x1[i]=0.f;
  }

  // --- gating: p_j = sum x * wg[:,j] ---
  float p0=0.f, p1=0.f, p2=0.f;
  #pragma unroll
  for (int i=0;i<11;i++){
    int e0 = 2*(i*64+lane);
    float2 w0 = *(const float2*)&wgT[0][e0];
    float2 w1 = *(const float2*)&wgT[1][e0];
    float2 w2 = *(const float2*)&wgT[2][e0];
    p0 += x0[i]*w0.x + x1[i]*w0.y;
    p1 += x0[i]*w1.x + x1[i]*w1.y;
    p2 += x0[i]*w2.x + x1[i]*w2.y;
  }
  #pragma unroll
  for (int o=1;o<64;o<<=1){
    p0 += __shfl_xor(p0,o,64);
    p1 += __shfl_xor(p1,o,64);
    p2 += __shfl_xor(p2,o,64);
  }
  float mx = fmaxf(p0, fmaxf(p1,p2));
  float e0s=__expf(p0-mx), e1s=__expf(p1-mx), e2s=__expf(p2-mx);
  float inv = __builtin_amdgcn_rcpf(e0s+e1s+e2s);
  float pr[3]={e0s*inv, e1s*inv, e2s*inv};
  int i0=0; if (pr[1]>pr[i0]) i0=1; if (pr[2]>pr[i0]) i0=2;
  int a_=(i0==0)?1:0, b_=(i0==2)?1:2;
  int i1 = (pr[b_]>pr[a_])?b_:a_;
  bool top2 = !(pr[i0] > 0.5f);
  bool g0=(i0==0)||(top2&&i1==0);
  bool g1=(i0==1)||(top2&&i1==1);
  bool g2=(i0==2)||(top2&&i1==2);
  if (lane==0){
    float ent = pr[0]*__logf(pr[0]+1e-10f)+pr[1]*__logf(pr[1]+1e-10f)+pr[2]*__logf(pr[2]+1e-10f);
    atomicAdd(&entp[rid & 255], ent);
    atomicAdd(&spz[l*3+0], pr[i0]);
    if (top2) atomicAdd(&spz[l*3+1], pr[i1]);
  }

  // --- final mask + softmax ---
  const float* m0 = masks + ((size_t)l*3+0)*L_SEQ;
  const float* m1 = m0 + L_SEQ;
  const float* m2 = m1 + L_SEQ;
  float mxv = -3.0e38f;
  #pragma unroll
  for (int i=0;i<11;i++){
    int e0 = 2*(i*64+lane);
    float fm0 = (e0==l)?1.f:0.f, fm1 = (e0+1==l)?1.f:0.f;
    if (g0){ float2 v=*(const float2*)&m0[e0]; fm0+=v.x; fm1+=v.y; }
    if (g1){ float2 v=*(const float2*)&m1[e0]; fm0+=v.x; fm1+=v.y; }
    if (g2){ float2 v=*(const float2*)&m2[e0]; fm0+=v.x; fm1+=v.y; }
    x0[i] *= fm0; x1[i] *= fm1;
    mxv = fmaxf(mxv, fmaxf(x0[i], x1[i]));
  }
  #pragma unroll
  for (int o=1;o<64;o<<=1) mxv = fmaxf(mxv, __shfl_xor(mxv,o,64));
  float sum=0.f;
  #pragma unroll
  for (int i=0;i<11;i++){
    x0[i] = __expf(x0[i]-mxv);
    x1[i] = __expf(x1[i]-mxv);
    sum += x0[i]+x1[i];
  }
  #pragma unroll
  for (int o=1;o<64;o<<=1) sum += __shfl_xor(sum,o,64);
  float invs = __builtin_amdgcn_rcpf(sum);
  #pragma unroll
  for (int i=0;i<11;i++){
    unsigned lo = f2bf(x0[i]*invs), hi = f2bf(x1[i]*invs);
    rowp[i*64+lane] = lo | (hi<<16);
  }
}

// ---------------- final: add9 epilogue + loss in one launch ----------------
__global__ __launch_bounds__(256) void final_kernel(const float* __restrict__ P,
                                                    const float* __restrict__ x1,
                                                    const float* __restrict__ bias,
                                                    const float* __restrict__ spz,
                                                    const float* __restrict__ entp,
                                                    float* __restrict__ out){
  int t = threadIdx.x;
  if (blockIdx.x < 1408){
    int idx = blockIdx.x*256 + t;   // float4 index
    const float4* P0 = (const float4*)P;
    const float4* P1 = (const float4*)(P + (size_t)ROWS*DMODEL);
    const float4* X  = (const float4*)x1;
    const float4* B4 = (const float4*)bias;
    float4 a = P0[idx], b = P1[idx], c = X[idx], d = B4[idx & 127];
    float4 o; o.x=a.x+b.x+c.x+d.x; o.y=a.y+b.y+c.y+d.y; o.z=a.z+b.z+c.z+d.z; o.w=a.w+b.w+c.w+d.w;
    ((float4*)out)[idx] = o;
  } else {
    float sum=0.f;
    for (int i=t;i<4224;i+=256) sum += spz[i];
    sum = block_reduce_sum(sum);
    float mu = sum/4224.f;
    float ss=0.f;
    for (int i=t;i<4224;i+=256){ float d=spz[i]-mu; ss+=d*d; }
    ss = block_reduce_sum(ss);
    float ent = block_reduce_sum(entp[t]);
    if (t==0){
      float var = ss/4223.f;
      float li = var/(mu*mu+1e-10f);
      float ld = -ent/48.f;
      out[(size_t)ROWS*DMODEL] = li + 0.1f*ld;
    }
  }
}

extern "C" void kernel_launch(void* const* d_in, const int* in_sizes, int n_in,
                              void* d_out, int out_size, void* d_ws, size_t ws_size,
                              hipStream_t stream) {
  const float* x     = (const float*)d_in[0];
  const float* masks = (const float*)d_in[1];
  const float* ln1_g = (const float*)d_in[2];
  const float* ln1_b = (const float*)d_in[3];
  const float* w_p1  = (const float*)d_in[4];
  const float* b_p1  = (const float*)d_in[5];
  const float* w_p2  = (const float*)d_in[6];
  const float* b_p2  = (const float*)d_in[7];
  const float* w_gate= (const float*)d_in[8];
  const float* w_gcn = (const float*)d_in[9];
  const float* b_gcn = (const float*)d_in[10];
  const float* ln2_g = (const float*)d_in[11];
  const float* ln2_b = (const float*)d_in[12];
  const float* w_f1  = (const float*)d_in[13];
  const float* b_f1  = (const float*)d_in[14];
  const float* w_f2  = (const float*)d_in[15];
  const float* b_f2  = (const float*)d_in[16];
  float* out = (float*)d_out;

  char* wsb = (char*)d_ws;
  size_t off = 0;
  u16* adj   = (u16*)(wsb+off); off += (size_t)BH*L_SEQ*L_SEQ*2;  // 63.4 MB
  u16* xn    = (u16*)(wsb+off); off += (size_t)ROWS*DMODEL*2;
  u16* q     = (u16*)(wsb+off); off += (size_t)BH*L_SEQ*64*2;
  u16* kk    = (u16*)(wsb+off); off += (size_t)BH*L_SEQ*64*2;
  u16* xpt   = (u16*)(wsb+off); off += (size_t)DMODEL*ROWS*2;     // [512][2816]
  u16* xn2   = (u16*)(wsb+off); off += (size_t)ROWS*DMODEL*2;
  float* x1  = (float*)(wsb+off); off += (size_t)ROWS*DMODEL*4;
  float* Pk  = (float*)(wsb+off); off += (size_t)2*ROWS*DMODEL*4; // split-K partials
  u16* wgcnT = (u16*)(wsb+off); off += (size_t)DMODEL*DMODEL*2;
  u16* wf1T  = (u16*)(wsb+off); off += (size_t)DFF*DMODEL*2;
  u16* wf2T  = (u16*)(wsb+off); off += (size_t)DMODEL*DFF*2;
  u16* wp1T  = (u16*)(wsb+off); off += (size_t)64*64*2;
  u16* wp2T  = (u16*)(wsb+off); off += (size_t)64*64*2;
  float* spz = (float*)(wsb+off); off += 4224*4;
  float* entp= (float*)(wsb+off); off += 256*4;
  u16* ffh   = adj;   // reuse after graph conv

  hipMemsetAsync(spz, 0, (4224+256)*sizeof(float), stream);

  // 0. prep: all weight transpose-casts + LN1
  prep_kernel<<<dim3(2312+ROWS), 256, 0, stream>>>(w_gcn, wgcnT, w_f1, wf1T, w_f2, wf2T,
                                                   w_p1, wp1T, w_p2, wp2T, x, ln1_g, ln1_b, xn);
  // 1. Q/K projections (MFMA)
  qk_mfma_kernel<<<dim3(176), 256, 0, stream>>>(xn, wp1T, wp2T, b_p1, b_p2, q, kk);
  // 2. adj = gelu(Q K^T)
  qkt_mfma_kernel<<<dim3(11,11,BH), 256, 0, stream>>>(q, kk, adj);
  // 3. per-row pipeline (wave per row)
  row_pipe2_kernel<<<dim3(BH*L_SEQ/4), 256, 0, stream>>>(adj, w_gate, masks, spz, entp);
  // 4. xp^T = (xn @ w_gcn + b_gcn)^T
  gemm_mfma_kernel<0,0,1><<<dim3(22,4), 256, 0, stream>>>(xn, wgcnT, b_gcn, xpt, ROWS, DMODEL, DMODEL);
  // 5. gc partials (split-K 2)
  gc_ks_kernel<<<dim3(11,2,BH), 256, 0, stream>>>(adj, xpt, Pk);
  // 6. x1 = x+P0+P1 ; xn2 = LN2(x1)
  ln2_fuse_kernel<<<ROWS, 256, 0, stream>>>(x, Pk, ln2_g, ln2_b, x1, xn2);
  // 7. ffh = gelu(xn2 @ w_f1 + b_f1)
  gemm_mfma_kernel<1,1,0><<<dim3(22,16), 256, 0, stream>>>(xn2, wf1T, b_f1, ffh, ROWS, DFF, DMODEL);
  // 8. FFN2 partials (split-K 2)
  gemm_ks_kernel<<<dim3(22,4,2), 256, 0, stream>>>(ffh, wf2T, Pk, ROWS, DMODEL, DFF, DFF/2);
  // 9. out = P0+P1+x1+bias ; loss
  final_kernel<<<dim3(1409), 256, 0, stream>>>(Pk, x1, b_f2, spz, entp, out);
}

// Round 8
// 188.766 us; speedup vs baseline: 6.1350x; 1.4324x over previous
//
#include <hip/hip_runtime.h>

#define L_SEQ 1408
#define DMODEL 512
#define NH 8
#define BATCH 2
#define BH 16
#define ROWS 2816
#define DFF 2048
#define KSEL 704

typedef unsigned short u16;
typedef short s8v __attribute__((ext_vector_type(8)));
typedef float f4v __attribute__((ext_vector_type(4)));

// scalar popcount of a 64-bit ballot (SALU, overlaps VALU)
#define SPOPC(b, out) asm("s_bcnt1_i32_b64 %0, %1" : "=s"(out) : "s"(b))

// fast gelu: x*sigmoid(1.59577(x+.044715x^3)); max abs err ~1e-3 < bf16 quantization
__device__ __forceinline__ float gelu_f(float x){
  float u = 1.595769122f*(x + 0.044715f*x*x*x);
  return x * __builtin_amdgcn_rcpf(1.0f + __expf(-u));
}
__device__ __forceinline__ u16 f2bf(float f){
  unsigned u = __float_as_uint(f);
  u += 0x7fffu + ((u>>16)&1u);
  return (u16)(u>>16);
}
__device__ __forceinline__ float b2f(unsigned h){ return __uint_as_float(h<<16); }
__device__ __forceinline__ unsigned key16(unsigned h){
  return (h & 0x8000u) ? (0xFFFFu & ~h) : (h | 0x8000u);
}

__device__ __forceinline__ f4v MFMA(s8v a, s8v b, f4v c){
  return __builtin_amdgcn_mfma_f32_16x16x32_bf16(a, b, c, 0, 0, 0);
}

// all LDS tiles have 128-byte rows (64 bf16); XOR swizzle spreads banks.
// Read side: fragment at swizzled offset.
__device__ __forceinline__ s8v ldfrag(const u16* lds, int row, int kb){
  return *(const s8v*)((const char*)lds + row*128 + ((kb*2) ^ ((row&7)<<4)));
}
// Staging via async global->LDS DMA: LDS write is LINEAR (wave-uniform base + lane*16);
// the swizzle is applied by pre-swizzling the per-lane GLOBAL source chunk (m173 pattern):
// linear LDS slot (row, j) must hold global chunk (row, j ^ ((row&7)<<4)).
__device__ __forceinline__ void stage_tile(const char* g, size_t gstride, u16* lds, int nrows, int t){
  int lane = t&63;
  int nch = nrows*8;                       // 16B chunks in tile
  for (int ci0 = (t>>6)*64; ci0 < nch; ci0 += 256){
    int ci = ci0 + lane;
    int row = ci>>3, j = (ci&7)*16;
    const char* src = g + (size_t)row*gstride + (j ^ ((row&7)<<4));
    u16* dstbase = lds + (size_t)ci0*8;    // wave-uniform; HW adds lane*16
    __builtin_amdgcn_global_load_lds((const __attribute__((address_space(1))) void*)src,
                                     (__attribute__((address_space(3))) void*)dstbase,
                                     16, 0, 0);
  }
}

__device__ __forceinline__ float block_reduce_sum(float v){
  __shared__ float sred[8];
  int lane = threadIdx.x & 63, w = threadIdx.x >> 6;
  #pragma unroll
  for (int o=32;o>0;o>>=1) v += __shfl_down(v,o,64);
  if (lane==0) sred[w]=v;
  __syncthreads();
  if (w==0){
    float x = (lane < (int)(blockDim.x>>6)) ? sred[lane] : 0.f;
    #pragma unroll
    for (int o=4;o>0;o>>=1) x += __shfl_down(x,o,64);
    if (lane==0) sred[0]=x;
  }
  __syncthreads();
  float r = sred[0];
  __syncthreads();
  return r;
}

// ---------------- LN body ----------------
__device__ __forceinline__ void ln_body(const float* g, const float* b,
                                        u16* orow, int t, float v0, float v1){
  float s = block_reduce_sum(v0+v1);
  float mean = s * (1.f/512.f);
  float d0 = v0-mean, d1 = v1-mean;
  float ss = block_reduce_sum(d0*d0 + d1*d1);
  float rstd = rsqrtf(ss*(1.f/512.f) + 1e-5f);
  orow[t]     = f2bf(d0*rstd*g[t]     + b[t]);
  orow[t+256] = f2bf(d1*rstd*g[t+256] + b[t+256]);
}

// ---------------- transpose-cast tile helper ----------------
__device__ __forceinline__ void castT_tile(const float* in, u16* outT, int K, int N,
                                           int k0, int n0, int t){
  __shared__ u16 tl[32][33];
  int r = t>>5, c = t&31;
  #pragma unroll
  for (int i=0;i<4;i++){
    int rr = r + i*8;
    tl[rr][c] = f2bf(in[(size_t)(k0+rr)*N + n0 + c]);
  }
  __syncthreads();
  #pragma unroll
  for (int i=0;i<4;i++){
    int rr = r + i*8;
    outT[(size_t)(n0+rr)*K + k0 + c] = tl[c][rr];
  }
}

// ---------------- prep: all weight transpose-casts + LN1 in one launch ----------------
__global__ __launch_bounds__(256) void prep_kernel(const float* __restrict__ w_gcn, u16* __restrict__ wgcnT,
                                                   const float* __restrict__ w_f1,  u16* __restrict__ wf1T,
                                                   const float* __restrict__ w_f2,  u16* __restrict__ wf2T,
                                                   const float* __restrict__ w_p1,  u16* __restrict__ wp1T,
                                                   const float* __restrict__ w_p2,  u16* __restrict__ wp2T,
                                                   const float* __restrict__ x,
                                                   const float* __restrict__ g,
                                                   const float* __restrict__ b,
                                                   u16* __restrict__ xn){
  int blk = blockIdx.x, t = threadIdx.x;
  if (blk < 256){
    castT_tile(w_gcn, wgcnT, DMODEL, DMODEL, (blk>>4)*32, (blk&15)*32, t);
  } else if (blk < 1280){
    int lo = blk - 256;
    castT_tile(w_f1, wf1T, DMODEL, DFF, (lo&15)*32, (lo>>4)*32, t);
  } else if (blk < 2304){
    int lo = blk - 1280;
    castT_tile(w_f2, wf2T, DFF, DMODEL, (lo&63)*32, (lo>>6)*32, t);
  } else if (blk < 2308){
    int lo = blk - 2304;
    castT_tile(w_p1, wp1T, 64, 64, (lo>>1)*32, (lo&1)*32, t);
  } else if (blk < 2312){
    int lo = blk - 2308;
    castT_tile(w_p2, wp2T, 64, 64, (lo>>1)*32, (lo&1)*32, t);
  } else {
    int row = blk - 2312;
    const float* xr = x + (size_t)row*DMODEL;
    ln_body(g, b, xn + (size_t)row*DMODEL, t, xr[t], xr[t+256]);
  }
}

// ---------------- fused x1 = x+P0+P1 ; xn2 = LN(x1) ----------------
__global__ __launch_bounds__(256) void ln2_fuse_kernel(const float* __restrict__ x,
                                                       const float* __restrict__ P,
                                                       const float* __restrict__ g,
                                                       const float* __restrict__ b,
                                                       float* __restrict__ x1,
                                                       u16* __restrict__ xn2){
  int row = blockIdx.x, t = threadIdx.x;
  size_t base = (size_t)row*DMODEL;
  const float* P1 = P + (size_t)ROWS*DMODEL;
  float v0 = x[base+t]     + P[base+t]     + P1[base+t];
  float v1 = x[base+t+256] + P[base+t+256] + P1[base+t+256];
  x1[base+t] = v0; x1[base+t+256] = v1;
  ln_body(g, b, xn2 + base, t, v0, v1);
}

// ---------------- Q/K projections via MFMA ----------------
__global__ __launch_bounds__(256) void qk_mfma_kernel(const u16* __restrict__ xn,
                                                      const u16* __restrict__ wp1T,
                                                      const u16* __restrict__ wp2T,
                                                      const float* __restrict__ bp1,
                                                      const float* __restrict__ bp2,
                                                      u16* __restrict__ q, u16* __restrict__ k){
  __shared__ u16 As[128*64], W1[64*64], W2[64*64];
  int m0 = blockIdx.x*128;
  int t = threadIdx.x, lane=t&63, w=t>>6;
  stage_tile((const char*)xn + (size_t)m0*128, 128, As, 128, t);
  stage_tile((const char*)wp1T, 128, W1, 64, t);
  stage_tile((const char*)wp2T, 128, W2, 64, t);
  __syncthreads();
  int fr=lane&15, kb=(lane>>4)*8;
  f4v aq[2][4], ak[2][4];
  #pragma unroll
  for (int mi=0;mi<2;mi++)
    #pragma unroll
    for (int n=0;n<4;n++){ aq[mi][n]=(f4v){0.f,0.f,0.f,0.f}; ak[mi][n]=(f4v){0.f,0.f,0.f,0.f}; }
  #pragma unroll
  for (int kk=0;kk<2;kk++){
    s8v a[2], b1[4], b2[4];
    #pragma unroll
    for (int mi=0;mi<2;mi++) a[mi] = ldfrag(As, w*32+mi*16+fr, kk*32+kb);
    #pragma unroll
    for (int n=0;n<4;n++){ b1[n]=ldfrag(W1, n*16+fr, kk*32+kb); b2[n]=ldfrag(W2, n*16+fr, kk*32+kb); }
    #pragma unroll
    for (int mi=0;mi<2;mi++)
      #pragma unroll
      for (int n=0;n<4;n++){
        aq[mi][n] = MFMA(a[mi], b1[n], aq[mi][n]);
        ak[mi][n] = MFMA(a[mi], b2[n], ak[mi][n]);
      }
  }
  #pragma unroll
  for (int mi=0;mi<2;mi++){
    #pragma unroll
    for (int n=0;n<4;n++){
      int j = n*16 + fr;
      float bq = bp1[j], bk = bp2[j];
      #pragma unroll
      for (int r=0;r<4;r++){
        int m = m0 + w*32 + mi*16 + (lane>>4)*4 + r;
        int bl = m>>3, h = m&7;
        int b_ = bl / L_SEQ, l = bl - b_*L_SEQ;
        size_t o = (((size_t)(b_*NH+h))*L_SEQ + l)*64 + j;
        q[o] = f2bf(aq[mi][n][r] + bq);
        k[o] = f2bf(ak[mi][n][r] + bk);
      }
    }
  }
}

// ---------------- adj = gelu(Q K^T), LDS-staged coalesced store ----------------
__global__ __launch_bounds__(256) void qkt_mfma_kernel(const u16* __restrict__ q,
                                                       const u16* __restrict__ k,
                                                       u16* __restrict__ adj){
  __shared__ u16 sbuf[128*128];
  u16* Qs = sbuf; u16* Ks = sbuf + 128*64; u16* Cs = sbuf;
  int z = blockIdx.z;
  int i0 = blockIdx.x*128, j0 = blockIdx.y*128;
  int t = threadIdx.x;
  const char* Qb = (const char*)(q + (size_t)z*L_SEQ*64) + (size_t)i0*128;
  const char* Kb = (const char*)(k + (size_t)z*L_SEQ*64) + (size_t)j0*128;
  stage_tile(Qb, 128, Qs, 128, t);
  stage_tile(Kb, 128, Ks, 128, t);
  __syncthreads();
  int lane = t&63, w = t>>6, wm = w>>1, wn = w&1;
  int fr = lane&15, kb = (lane>>4)*8;
  f4v acc[4][4];
  #pragma unroll
  for (int m=0;m<4;m++)
    #pragma unroll
    for (int n=0;n<4;n++) acc[m][n]=(f4v){0.f,0.f,0.f,0.f};
  #pragma unroll
  for (int kk=0;kk<2;kk++){
    s8v a[4], bv[4];
    #pragma unroll
    for (int m=0;m<4;m++) a[m] = ldfrag(Qs, wm*64+m*16+fr, kk*32+kb);
    #pragma unroll
    for (int n=0;n<4;n++) bv[n] = ldfrag(Ks, wn*64+n*16+fr, kk*32+kb);
    #pragma unroll
    for (int m=0;m<4;m++)
      #pragma unroll
      for (int n=0;n<4;n++) acc[m][n] = MFMA(a[m], bv[n], acc[m][n]);
  }
  __syncthreads();
  #pragma unroll
  for (int m=0;m<4;m++){
    int row = wm*64 + m*16 + (lane>>4)*4;
    #pragma unroll
    for (int n=0;n<4;n++){
      int col = wn*64 + n*16 + fr;
      #pragma unroll
      for (int r=0;r<4;r++)
        Cs[(row+r)*128 + col] = f2bf(gelu_f(acc[m][n][r]));
    }
  }
  __syncthreads();
  u16* Cb = adj + (size_t)z*L_SEQ*L_SEQ;
  #pragma unroll
  for (int i=0;i<8;i++){
    int idx = i*256 + t;
    int r = idx>>4, cc = (idx&15)*8;
    uint4 v = *(const uint4*)&Cs[r*128 + cc];
    *(uint4*)((char*)Cb + (size_t)(i0+r)*2816 + (j0+cc)*2) = v;
  }
}

// ---------------- generic MFMA GEMM: C = f(A@B + bias) ----------------
template<int OUTBF16,int ACT,int TRANSOUT>
__global__ __launch_bounds__(256) void gemm_mfma_kernel(const u16* __restrict__ A,
                                                        const u16* __restrict__ BT,
                                                        const float* __restrict__ bias,
                                                        void* __restrict__ outp,
                                                        int M, int N, int K){
  __shared__ u16 As[128*64], Bs[128*64];
  int i0 = blockIdx.x*128, j0 = blockIdx.y*128;
  int t = threadIdx.x, lane=t&63, w=t>>6, wm=w>>1, wn=w&1;
  int fr=lane&15, kb=(lane>>4)*8;
  f4v acc[4][4];
  #pragma unroll
  for (int m=0;m<4;m++)
    #pragma unroll
    for (int n=0;n<4;n++) acc[m][n]=(f4v){0.f,0.f,0.f,0.f};
  size_t strA=(size_t)K*2;
  const char* Ab = (const char*)A + (size_t)i0*strA;
  const char* Bb = (const char*)BT + (size_t)j0*strA;
  for (int k0=0;k0<K;k0+=64){
    stage_tile(Ab + (size_t)k0*2, strA, As, 128, t);
    stage_tile(Bb + (size_t)k0*2, strA, Bs, 128, t);
    __syncthreads();
    #pragma unroll
    for (int kk=0;kk<2;kk++){
      s8v a[4], bv[4];
      #pragma unroll
      for (int m=0;m<4;m++) a[m]=ldfrag(As, wm*64+m*16+fr, kk*32+kb);
      #pragma unroll
      for (int n=0;n<4;n++) bv[n]=ldfrag(Bs, wn*64+n*16+fr, kk*32+kb);
      #pragma unroll
      for (int m=0;m<4;m++)
        #pragma unroll
        for (int n=0;n<4;n++) acc[m][n]=MFMA(a[m],bv[n],acc[m][n]);
    }
    __syncthreads();
  }
  #pragma unroll
  for (int m=0;m<4;m++){
    int row = i0 + wm*64+m*16+(lane>>4)*4;
    #pragma unroll
    for (int n=0;n<4;n++){
      int col = j0 + wn*64+n*16+fr;
      float bb = bias[col];
      #pragma unroll
      for (int r=0;r<4;r++){
        float v = acc[m][n][r]+bb;
        if (ACT) v = gelu_f(v);
        if (TRANSOUT) ((u16*)outp)[(size_t)col*M + row + r] = f2bf(v);
        else if (OUTBF16) ((u16*)outp)[(size_t)(row+r)*N+col] = f2bf(v);
        else ((float*)outp)[(size_t)(row+r)*N+col] = v;
      }
    }
  }
}

// ---------------- split-K GEMM partial: P[z] = A@B over K slice ----------------
__global__ __launch_bounds__(256) void gemm_ks_kernel(const u16* __restrict__ A,
                                                      const u16* __restrict__ BT,
                                                      float* __restrict__ P,
                                                      int M, int N, int K, int KS){
  __shared__ u16 As[128*64], Bs[128*64];
  int i0 = blockIdx.x*128, j0 = blockIdx.y*128;
  int kbeg = blockIdx.z*KS;
  int t = threadIdx.x, lane=t&63, w=t>>6, wm=w>>1, wn=w&1;
  int fr=lane&15, kb=(lane>>4)*8;
  f4v acc[4][4];
  #pragma unroll
  for (int m=0;m<4;m++)
    #pragma unroll
    for (int n=0;n<4;n++) acc[m][n]=(f4v){0.f,0.f,0.f,0.f};
  size_t strA=(size_t)K*2;
  const char* Ab = (const char*)A + (size_t)i0*strA;
  const char* Bb = (const char*)BT + (size_t)j0*strA;
  for (int k0=kbeg; k0<kbeg+KS; k0+=64){
    stage_tile(Ab + (size_t)k0*2, strA, As, 128, t);
    stage_tile(Bb + (size_t)k0*2, strA, Bs, 128, t);
    __syncthreads();
    #pragma unroll
    for (int kk=0;kk<2;kk++){
      s8v a[4], bv[4];
      #pragma unroll
      for (int m=0;m<4;m++) a[m]=ldfrag(As, wm*64+m*16+fr, kk*32+kb);
      #pragma unroll
      for (int n=0;n<4;n++) bv[n]=ldfrag(Bs, wn*64+n*16+fr, kk*32+kb);
      #pragma unroll
      for (int m=0;m<4;m++)
        #pragma unroll
        for (int n=0;n<4;n++) acc[m][n]=MFMA(a[m],bv[n],acc[m][n]);
    }
    __syncthreads();
  }
  float* Pz = P + (size_t)blockIdx.z*M*N;
  #pragma unroll
  for (int m=0;m<4;m++){
    int row = i0 + wm*64+m*16+(lane>>4)*4;
    #pragma unroll
    for (int n=0;n<4;n++){
      int col = j0 + wn*64+n*16+fr;
      #pragma unroll
      for (int r=0;r<4;r++) Pz[(size_t)(row+r)*N+col] = acc[m][n][r];
    }
  }
}

// ---------------- graph conv split-K partial: P[ks] = adjn @ xp ----------------
__global__ __launch_bounds__(256) void gc_ks_kernel(const u16* __restrict__ adj,
                                                    const u16* __restrict__ xpt,
                                                    float* __restrict__ P){
  __shared__ u16 As[128*64], Bs[64*64];
  int z = blockIdx.z, b = z>>3, h = z&7;
  int i0 = blockIdx.x*128;
  int kbeg = blockIdx.y*704;
  int t = threadIdx.x, lane=t&63, w=t>>6, wm=w>>1, wn=w&1;
  int fr=lane&15, kb=(lane>>4)*8;
  const char* Ab = (const char*)(adj + (size_t)z*L_SEQ*L_SEQ) + (size_t)i0*2816;
  const char* Bb = (const char*)xpt + (size_t)(h*64)*5632 + (size_t)(b*L_SEQ)*2;
  f4v acc[4][2];
  #pragma unroll
  for (int m=0;m<4;m++){ acc[m][0]=(f4v){0.f,0.f,0.f,0.f}; acc[m][1]=(f4v){0.f,0.f,0.f,0.f}; }
  for (int k0=kbeg; k0<kbeg+704; k0+=64){
    stage_tile(Ab + (size_t)k0*2, 2816, As, 128, t);
    stage_tile(Bb + (size_t)k0*2, 5632, Bs, 64, t);
    __syncthreads();
    #pragma unroll
    for (int kk=0;kk<2;kk++){
      s8v a[4], bv[2];
      #pragma unroll
      for (int m=0;m<4;m++) a[m]=ldfrag(As, wm*64+m*16+fr, kk*32+kb);
      #pragma unroll
      for (int n=0;n<2;n++) bv[n]=ldfrag(Bs, wn*32+n*16+fr, kk*32+kb);
      #pragma unroll
      for (int m=0;m<4;m++)
        #pragma unroll
        for (int n=0;n<2;n++) acc[m][n]=MFMA(a[m],bv[n],acc[m][n]);
    }
    __syncthreads();
  }
  float* Pz = P + (size_t)blockIdx.y*ROWS*DMODEL;
  #pragma unroll
  for (int m=0;m<4;m++){
    int rl = i0 + wm*64+m*16+(lane>>4)*4;
    #pragma unroll
    for (int n=0;n<2;n++){
      int col = h*64 + wn*32+n*16+fr;
      #pragma unroll
      for (int r=0;r<4;r++)
        Pz[(size_t)(b*L_SEQ + rl + r)*DMODEL + col] = acc[m][n][r];
    }
  }
}

// ---------------- per-row pipeline: one WAVE per row ----------------
__global__ __launch_bounds__(256) void row_pipe2_kernel(u16* __restrict__ adj,
                                                        const float* __restrict__ wg,
                                                        const float* __restrict__ masks,
                                                        float* __restrict__ spz,
                                                        float* __restrict__ entp){
  __shared__ float wgT[3][L_SEQ];
  int t = threadIdx.x, lane = t&63, w = t>>6;
  for (int idx=t; idx<3*L_SEQ; idx+=256){
    float v = wg[idx];
    int e = idx/3, j = idx - 3*e;
    wgT[j][e] = v;
  }
  __syncthreads();

  int rid = blockIdx.x*4 + w;
  int z = rid / L_SEQ;
  int l = rid - z*L_SEQ;
  unsigned* rowp = (unsigned*)(adj + (size_t)rid*L_SEQ);

  unsigned klo[11], khi[11];
  float x0[11], x1[11];
  #pragma unroll
  for (int i=0;i<11;i++){
    unsigned r = rowp[i*64 + lane];
    unsigned lo = r&0xFFFFu, hi = r>>16;
    klo[i] = key16(lo); khi[i] = key16(hi);
    x0[i] = b2f(lo); x1[i] = b2f(hi);
  }

  // --- 16-step ballot binary search; counts via SALU s_bcnt1 ---
  unsigned thr = 0; int cnt_thr = 0;
  #pragma unroll
  for (int b=15;b>=0;b--){
    unsigned cand = thr | (1u<<b);
    int cnt = 0;
    #pragma unroll
    for (int i=0;i<11;i++){
      unsigned long long b0 = __ballot(klo[i] < cand);
      unsigned long long b1 = __ballot(khi[i] < cand);
      int c0, c1; SPOPC(b0, c0); SPOPC(b1, c1);
      cnt += c0 + c1;
    }
    if ((unsigned)cnt < KSEL){ thr = cand; cnt_thr = cnt; }
  }
  int z_eq = (int)(KSEL - cnt_thr);

  // tie zeroing in global index order
  int cnt = 0;
  #pragma unroll
  for (int i=0;i<11;i++){
    bool act = (cnt < z_eq);
    bool eq0 = act && (klo[i]==thr);
    bool eq1 = act && (khi[i]==thr);
    unsigned long long b0 = __ballot(eq0), b1 = __ballot(eq1);
    int p0b = __builtin_amdgcn_mbcnt_hi((unsigned)(b0>>32), __builtin_amdgcn_mbcnt_lo((unsigned)b0, 0));
    int p1b = __builtin_amdgcn_mbcnt_hi((unsigned)(b1>>32), __builtin_amdgcn_mbcnt_lo((unsigned)b1, 0));
    int pre0 = p0b + p1b;
    int pre1 = pre0 + (eq0?1:0);
    if (eq0 && cnt+pre0 < z_eq) x0[i]=0.f;
    if (eq1 && cnt+pre1 < z_eq) x1[i]=0.f;
    int c0, c1; SPOPC(b0, c0); SPOPC(b1, c1);
    cnt += c0 + c1;
  }
  // zero everything strictly below threshold
  #pragma unroll
  for (int i=0;i<11;i++){
    if (klo[i] < thr) x0[i]=0.f;
    if (khi[i] < thr) x1[i]=0.f;
  }

  // --- gating: p_j = sum x * wg[:,j] ---
  float p0=0.f, p1=0.f, p2=0.f;
  #pragma unroll
  for (int i=0;i<11;i++){
    int e0 = 2*(i*64+lane);
    float2 w0 = *(const float2*)&wgT[0][e0];
    float2 w1 = *(const float2*)&wgT[1][e0];
    float2 w2 = *(const float2*)&wgT[2][e0];
    p0 += x0[i]*w0.x + x1[i]*w0.y;
    p1 += x0[i]*w1.x + x1[i]*w1.y;
    p2 += x0[i]*w2.x + x1[i]*w2.y;
  }
  #pragma unroll
  for (int o=1;o<64;o<<=1){
    p0 += __shfl_xor(p0,o,64);
    p1 += __shfl_xor(p1,o,64);
    p2 += __shfl_xor(p2,o,64);
  }
  float mx = fmaxf(p0, fmaxf(p1,p2));
  float e0s=__expf(p0-mx), e1s=__expf(p1-mx), e2s=__expf(p2-mx);
  float inv = __builtin_amdgcn_rcpf(e0s+e1s+e2s);
  float pr[3]={e0s*inv, e1s*inv, e2s*inv};
  int i0=0; if (pr[1]>pr[i0]) i0=1; if (pr[2]>pr[i0]) i0=2;
  int a_=(i0==0)?1:0, b_=(i0==2)?1:2;
  int i1 = (pr[b_]>pr[a_])?b_:a_;
  bool top2 = !(pr[i0] > 0.5f);
  bool g0=(i0==0)||(top2&&i1==0);
  bool g1=(i0==1)||(top2&&i1==1);
  bool g2=(i0==2)||(top2&&i1==2);
  if (lane==0){
    float ent = pr[0]*__logf(pr[0]+1e-10f)+pr[1]*__logf(pr[1]+1e-10f)+pr[2]*__logf(pr[2]+1e-10f);
    atomicAdd(&entp[rid & 255], ent);
    atomicAdd(&spz[l*3+0], pr[i0]);
    if (top2) atomicAdd(&spz[l*3+1], pr[i1]);
  }

  // --- final mask + softmax: wave-uniform 2-pointer mask selection ---
  const float* m0 = masks + ((size_t)l*3+0)*L_SEQ;
  const float* m1 = m0 + L_SEQ;
  const float* m2 = m1 + L_SEQ;
  const float* pA = g0 ? m0 : (g1 ? m1 : m2);
  const float* pB = pA; float sB = 0.f;
  if (g0 && g1){ pB = m1; sB = 1.f; }
  else if (g0 && g2){ pB = m2; sB = 1.f; }
  else if (g1 && g2){ pB = m2; sB = 1.f; }
  float mxv = -3.0e38f;
  #pragma unroll
  for (int i=0;i<11;i++){
    int e0 = 2*(i*64+lane);
    float2 va = *(const float2*)&pA[e0];
    float2 vb = *(const float2*)&pB[e0];
    float fm0 = va.x + sB*vb.x + ((e0==l)?1.f:0.f);
    float fm1 = va.y + sB*vb.y + ((e0+1==l)?1.f:0.f);
    x0[i] *= fm0; x1[i] *= fm1;
    mxv = fmaxf(mxv, fmaxf(x0[i], x1[i]));
  }
  #pragma unroll
  for (int o=1;o<64;o<<=1) mxv = fmaxf(mxv, __shfl_xor(mxv,o,64));
  float sum=0.f;
  #pragma unroll
  for (int i=0;i<11;i++){
    x0[i] = __expf(x0[i]-mxv);
    x1[i] = __expf(x1[i]-mxv);
    sum += x0[i]+x1[i];
  }
  #pragma unroll
  for (int o=1;o<64;o<<=1) sum += __shfl_xor(sum,o,64);
  float invs = __builtin_amdgcn_rcpf(sum);
  #pragma unroll
  for (int i=0;i<11;i++){
    unsigned lo = f2bf(x0[i]*invs), hi = f2bf(x1[i]*invs);
    rowp[i*64+lane] = lo | (hi<<16);
  }
}

// ---------------- final: add9 epilogue + loss in one launch ----------------
__global__ __launch_bounds__(256) void final_kernel(const float* __restrict__ P,
                                                    const float* __restrict__ x1,
                                                    const float* __restrict__ bias,
                                                    const float* __restrict__ spz,
                                                    const float* __restrict__ entp,
                                                    float* __restrict__ out){
  int t = threadIdx.x;
  if (blockIdx.x < 1408){
    int idx = blockIdx.x*256 + t;   // float4 index
    const float4* P0 = (const float4*)P;
    const float4* P1 = (const float4*)(P + (size_t)ROWS*DMODEL);
    const float4* X  = (const float4*)x1;
    const float4* B4 = (const float4*)bias;
    float4 a = P0[idx], b = P1[idx], c = X[idx], d = B4[idx & 127];
    float4 o; o.x=a.x+b.x+c.x+d.x; o.y=a.y+b.y+c.y+d.y; o.z=a.z+b.z+c.z+d.z; o.w=a.w+b.w+c.w+d.w;
    ((float4*)out)[idx] = o;
  } else {
    float sum=0.f;
    for (int i=t;i<4224;i+=256) sum += spz[i];
    sum = block_reduce_sum(sum);
    float mu = sum/4224.f;
    float ss=0.f;
    for (int i=t;i<4224;i+=256){ float d=spz[i]-mu; ss+=d*d; }
    ss = block_reduce_sum(ss);
    float ent = block_reduce_sum(entp[t]);
    if (t==0){
      float var = ss/4223.f;
      float li = var/(mu*mu+1e-10f);
      float ld = -ent/48.f;
      out[(size_t)ROWS*DMODEL] = li + 0.1f*ld;
    }
  }
}

extern "C" void kernel_launch(void* const* d_in, const int* in_sizes, int n_in,
                              void* d_out, int out_size, void* d_ws, size_t ws_size,
                              hipStream_t stream) {
  const float* x     = (const float*)d_in[0];
  const float* masks = (const float*)d_in[1];
  const float* ln1_g = (const float*)d_in[2];
  const float* ln1_b = (const float*)d_in[3];
  const float* w_p1  = (const float*)d_in[4];
  const float* b_p1  = (const float*)d_in[5];
  const float* w_p2  = (const float*)d_in[6];
  const float* b_p2  = (const float*)d_in[7];
  const float* w_gate= (const float*)d_in[8];
  const float* w_gcn = (const float*)d_in[9];
  const float* b_gcn = (const float*)d_in[10];
  const float* ln2_g = (const float*)d_in[11];
  const float* ln2_b = (const float*)d_in[12];
  const float* w_f1  = (const float*)d_in[13];
  const float* b_f1  = (const float*)d_in[14];
  const float* w_f2  = (const float*)d_in[15];
  const float* b_f2  = (const float*)d_in[16];
  float* out = (float*)d_out;

  char* wsb = (char*)d_ws;
  size_t off = 0;
  u16* adj   = (u16*)(wsb+off); off += (size_t)BH*L_SEQ*L_SEQ*2;  // 63.4 MB
  u16* xn    = (u16*)(wsb+off); off += (size_t)ROWS*DMODEL*2;
  u16* q     = (u16*)(wsb+off); off += (size_t)BH*L_SEQ*64*2;
  u16* kk    = (u16*)(wsb+off); off += (size_t)BH*L_SEQ*64*2;
  u16* xpt   = (u16*)(wsb+off); off += (size_t)DMODEL*ROWS*2;     // [512][2816]
  u16* xn2   = (u16*)(wsb+off); off += (size_t)ROWS*DMODEL*2;
  float* x1  = (float*)(wsb+off); off += (size_t)ROWS*DMODEL*4;
  float* Pk  = (float*)(wsb+off); off += (size_t)2*ROWS*DMODEL*4; // split-K partials
  u16* wgcnT = (u16*)(wsb+off); off += (size_t)DMODEL*DMODEL*2;
  u16* wf1T  = (u16*)(wsb+off); off += (size_t)DFF*DMODEL*2;
  u16* wf2T  = (u16*)(wsb+off); off += (size_t)DMODEL*DFF*2;
  u16* wp1T  = (u16*)(wsb+off); off += (size_t)64*64*2;
  u16* wp2T  = (u16*)(wsb+off); off += (size_t)64*64*2;
  float* spz = (float*)(wsb+off); off += 4224*4;
  float* entp= (float*)(wsb+off); off += 256*4;
  u16* ffh   = adj;   // reuse after graph conv

  hipMemsetAsync(spz, 0, (4224+256)*sizeof(float), stream);

  // 0. prep: all weight transpose-casts + LN1
  prep_kernel<<<dim3(2312+ROWS), 256, 0, stream>>>(w_gcn, wgcnT, w_f1, wf1T, w_f2, wf2T,
                                                   w_p1, wp1T, w_p2, wp2T, x, ln1_g, ln1_b, xn);
  // 1. Q/K projections (MFMA)
  qk_mfma_kernel<<<dim3(176), 256, 0, stream>>>(xn, wp1T, wp2T, b_p1, b_p2, q, kk);
  // 2. adj = gelu(Q K^T)
  qkt_mfma_kernel<<<dim3(11,11,BH), 256, 0, stream>>>(q, kk, adj);
  // 3. per-row pipeline (wave per row)
  row_pipe2_kernel<<<dim3(BH*L_SEQ/4), 256, 0, stream>>>(adj, w_gate, masks, spz, entp);
  // 4. xp^T = (xn @ w_gcn + b_gcn)^T
  gemm_mfma_kernel<0,0,1><<<dim3(22,4), 256, 0, stream>>>(xn, wgcnT, b_gcn, xpt, ROWS, DMODEL, DMODEL);
  // 5. gc partials (split-K 2)
  gc_ks_kernel<<<dim3(11,2,BH), 256, 0, stream>>>(adj, xpt, Pk);
  // 6. x1 = x+P0+P1 ; xn2 = LN2(x1)
  ln2_fuse_kernel<<<ROWS, 256, 0, stream>>>(x, Pk, ln2_g, ln2_b, x1, xn2);
  // 7. ffh = gelu(xn2 @ w_f1 + b_f1)
  gemm_mfma_kernel<1,1,0><<<dim3(22,16), 256, 0, stream>>>(xn2, wf1T, b_f1, ffh, ROWS, DFF, DMODEL);
  // 8. FFN2 partials (split-K 2)
  gemm_ks_kernel<<<dim3(22,4,2), 256, 0, stream>>>(ffh, wf2T, Pk, ROWS, DMODEL, DFF, DFF/2);
  // 9. out = P0+P1+x1+bias ; loss
  final_kernel<<<dim3(1409), 256, 0, stream>>>(Pk, x1, b_f2, spz, entp, out);
}

// Round 9
// 186.799 us; speedup vs baseline: 6.1996x; 1.0105x over previous
//
#include <hip/hip_runtime.h>

#define L_SEQ 1408
#define DMODEL 512
#define NH 8
#define BATCH 2
#define BH 16
#define ROWS 2816
#define DFF 2048
#define KSEL 704

typedef unsigned short u16;
typedef short s8v __attribute__((ext_vector_type(8)));
typedef float f4v __attribute__((ext_vector_type(4)));

// scalar popcount of a 64-bit ballot (SALU, overlaps VALU)
#define SPOPC(b, out) asm("s_bcnt1_i32_b64 %0, %1" : "=s"(out) : "s"(b))
// single-VALU ballot: VOP3 v_cmp_lt_u32 with SGPR dest (a<b across wave)
__device__ __forceinline__ unsigned long long vcmp_lt_u32(unsigned a, unsigned b){
  unsigned long long m;
  asm("v_cmp_lt_u32 %0, %1, %2" : "=s"(m) : "v"(a), "s"(b));
  return m;
}

// fast gelu: x*sigmoid(1.59577(x+.044715x^3)); max abs err ~1e-3 < bf16 quantization
__device__ __forceinline__ float gelu_f(float x){
  float u = 1.595769122f*(x + 0.044715f*x*x*x);
  return x * __builtin_amdgcn_rcpf(1.0f + __expf(-u));
}
__device__ __forceinline__ u16 f2bf(float f){
  unsigned u = __float_as_uint(f);
  u += 0x7fffu + ((u>>16)&1u);
  return (u16)(u>>16);
}
__device__ __forceinline__ float b2f(unsigned h){ return __uint_as_float(h<<16); }
__device__ __forceinline__ unsigned key16(unsigned h){
  return (h & 0x8000u) ? (0xFFFFu & ~h) : (h | 0x8000u);
}

__device__ __forceinline__ f4v MFMA(s8v a, s8v b, f4v c){
  return __builtin_amdgcn_mfma_f32_16x16x32_bf16(a, b, c, 0, 0, 0);
}

// all LDS tiles have 128-byte rows (64 bf16); XOR swizzle spreads banks.
__device__ __forceinline__ s8v ldfrag(const u16* lds, int row, int kb){
  return *(const s8v*)((const char*)lds + row*128 + ((kb*2) ^ ((row&7)<<4)));
}
// Staging via async global->LDS DMA: linear LDS dest (wave-uniform base + lane*16);
// swizzle applied by pre-swizzling the per-lane GLOBAL source chunk (m173 pattern).
__device__ __forceinline__ void stage_tile(const char* g, size_t gstride, u16* lds, int nrows, int t){
  int lane = t&63;
  int nch = nrows*8;
  for (int ci0 = (t>>6)*64; ci0 < nch; ci0 += 256){
    int ci = ci0 + lane;
    int row = ci>>3, j = (ci&7)*16;
    const char* src = g + (size_t)row*gstride + (j ^ ((row&7)<<4));
    u16* dstbase = lds + (size_t)ci0*8;
    __builtin_amdgcn_global_load_lds((const __attribute__((address_space(1))) void*)src,
                                     (__attribute__((address_space(3))) void*)dstbase,
                                     16, 0, 0);
  }
}

__device__ __forceinline__ float block_reduce_sum(float v){
  __shared__ float sred[8];
  int lane = threadIdx.x & 63, w = threadIdx.x >> 6;
  #pragma unroll
  for (int o=32;o>0;o>>=1) v += __shfl_down(v,o,64);
  if (lane==0) sred[w]=v;
  __syncthreads();
  if (w==0){
    float x = (lane < (int)(blockDim.x>>6)) ? sred[lane] : 0.f;
    #pragma unroll
    for (int o=4;o>0;o>>=1) x += __shfl_down(x,o,64);
    if (lane==0) sred[0]=x;
  }
  __syncthreads();
  float r = sred[0];
  __syncthreads();
  return r;
}

// ---------------- LN body ----------------
__device__ __forceinline__ void ln_body(const float* g, const float* b,
                                        u16* orow, int t, float v0, float v1){
  float s = block_reduce_sum(v0+v1);
  float mean = s * (1.f/512.f);
  float d0 = v0-mean, d1 = v1-mean;
  float ss = block_reduce_sum(d0*d0 + d1*d1);
  float rstd = rsqrtf(ss*(1.f/512.f) + 1e-5f);
  orow[t]     = f2bf(d0*rstd*g[t]     + b[t]);
  orow[t+256] = f2bf(d1*rstd*g[t+256] + b[t+256]);
}

// ---------------- transpose-cast tile helper ----------------
__device__ __forceinline__ void castT_tile(const float* in, u16* outT, int K, int N,
                                           int k0, int n0, int t){
  __shared__ u16 tl[32][33];
  int r = t>>5, c = t&31;
  #pragma unroll
  for (int i=0;i<4;i++){
    int rr = r + i*8;
    tl[rr][c] = f2bf(in[(size_t)(k0+rr)*N + n0 + c]);
  }
  __syncthreads();
  #pragma unroll
  for (int i=0;i<4;i++){
    int rr = r + i*8;
    outT[(size_t)(n0+rr)*K + k0 + c] = tl[c][rr];
  }
}

// ---------------- prep: weight transpose-casts + w_gate transpose + LN1 ----------------
__global__ __launch_bounds__(256) void prep_kernel(const float* __restrict__ w_gcn, u16* __restrict__ wgcnT,
                                                   const float* __restrict__ w_f1,  u16* __restrict__ wf1T,
                                                   const float* __restrict__ w_f2,  u16* __restrict__ wf2T,
                                                   const float* __restrict__ w_p1,  u16* __restrict__ wp1T,
                                                   const float* __restrict__ w_p2,  u16* __restrict__ wp2T,
                                                   const float* __restrict__ w_gate, float* __restrict__ wgt,
                                                   const float* __restrict__ x,
                                                   const float* __restrict__ g,
                                                   const float* __restrict__ b,
                                                   u16* __restrict__ xn){
  int blk = blockIdx.x, t = threadIdx.x;
  if (blk < 256){
    castT_tile(w_gcn, wgcnT, DMODEL, DMODEL, (blk>>4)*32, (blk&15)*32, t);
  } else if (blk < 1280){
    int lo = blk - 256;
    castT_tile(w_f1, wf1T, DMODEL, DFF, (lo&15)*32, (lo>>4)*32, t);
  } else if (blk < 2304){
    int lo = blk - 1280;
    castT_tile(w_f2, wf2T, DFF, DMODEL, (lo&63)*32, (lo>>6)*32, t);
  } else if (blk < 2308){
    int lo = blk - 2304;
    castT_tile(w_p1, wp1T, 64, 64, (lo>>1)*32, (lo&1)*32, t);
  } else if (blk < 2312){
    int lo = blk - 2308;
    castT_tile(w_p2, wp2T, 64, 64, (lo>>1)*32, (lo&1)*32, t);
  } else if (blk < 2329){
    int idx = (blk-2312)*256 + t;       // wgt[j][e] = w_gate[e][j]
    if (idx < 3*L_SEQ){
      int j = (idx >= 2*L_SEQ) ? 2 : (idx >= L_SEQ ? 1 : 0);
      int e = idx - j*L_SEQ;
      wgt[idx] = w_gate[e*3 + j];
    }
  } else {
    int row = blk - 2329;
    const float* xr = x + (size_t)row*DMODEL;
    ln_body(g, b, xn + (size_t)row*DMODEL, t, xr[t], xr[t+256]);
  }
}

// ---------------- fused x1 = x+P0+P1 ; xn2 = LN(x1) ----------------
__global__ __launch_bounds__(256) void ln2_fuse_kernel(const float* __restrict__ x,
                                                       const float* __restrict__ P,
                                                       const float* __restrict__ g,
                                                       const float* __restrict__ b,
                                                       float* __restrict__ x1,
                                                       u16* __restrict__ xn2){
  int row = blockIdx.x, t = threadIdx.x;
  size_t base = (size_t)row*DMODEL;
  const float* P1 = P + (size_t)ROWS*DMODEL;
  float v0 = x[base+t]     + P[base+t]     + P1[base+t];
  float v1 = x[base+t+256] + P[base+t+256] + P1[base+t+256];
  x1[base+t] = v0; x1[base+t+256] = v1;
  ln_body(g, b, xn2 + base, t, v0, v1);
}

// ---------------- Q/K projections via MFMA ----------------
__global__ __launch_bounds__(256) void qk_mfma_kernel(const u16* __restrict__ xn,
                                                      const u16* __restrict__ wp1T,
                                                      const u16* __restrict__ wp2T,
                                                      const float* __restrict__ bp1,
                                                      const float* __restrict__ bp2,
                                                      u16* __restrict__ q, u16* __restrict__ k){
  __shared__ u16 As[128*64], W1[64*64], W2[64*64];
  int m0 = blockIdx.x*128;
  int t = threadIdx.x, lane=t&63, w=t>>6;
  stage_tile((const char*)xn + (size_t)m0*128, 128, As, 128, t);
  stage_tile((const char*)wp1T, 128, W1, 64, t);
  stage_tile((const char*)wp2T, 128, W2, 64, t);
  __syncthreads();
  int fr=lane&15, kb=(lane>>4)*8;
  f4v aq[2][4], ak[2][4];
  #pragma unroll
  for (int mi=0;mi<2;mi++)
    #pragma unroll
    for (int n=0;n<4;n++){ aq[mi][n]=(f4v){0.f,0.f,0.f,0.f}; ak[mi][n]=(f4v){0.f,0.f,0.f,0.f}; }
  #pragma unroll
  for (int kk=0;kk<2;kk++){
    s8v a[2], b1[4], b2[4];
    #pragma unroll
    for (int mi=0;mi<2;mi++) a[mi] = ldfrag(As, w*32+mi*16+fr, kk*32+kb);
    #pragma unroll
    for (int n=0;n<4;n++){ b1[n]=ldfrag(W1, n*16+fr, kk*32+kb); b2[n]=ldfrag(W2, n*16+fr, kk*32+kb); }
    #pragma unroll
    for (int mi=0;mi<2;mi++)
      #pragma unroll
      for (int n=0;n<4;n++){
        aq[mi][n] = MFMA(a[mi], b1[n], aq[mi][n]);
        ak[mi][n] = MFMA(a[mi], b2[n], ak[mi][n]);
      }
  }
  #pragma unroll
  for (int mi=0;mi<2;mi++){
    #pragma unroll
    for (int n=0;n<4;n++){
      int j = n*16 + fr;
      float bq = bp1[j], bk = bp2[j];
      #pragma unroll
      for (int r=0;r<4;r++){
        int m = m0 + w*32 + mi*16 + (lane>>4)*4 + r;
        int bl = m>>3, h = m&7;
        int b_ = bl / L_SEQ, l = bl - b_*L_SEQ;
        size_t o = (((size_t)(b_*NH+h))*L_SEQ + l)*64 + j;
        q[o] = f2bf(aq[mi][n][r] + bq);
        k[o] = f2bf(ak[mi][n][r] + bk);
      }
    }
  }
}

// ---------------- adj = gelu(Q K^T), LDS-staged coalesced store ----------------
__global__ __launch_bounds__(256) void qkt_mfma_kernel(const u16* __restrict__ q,
                                                       const u16* __restrict__ k,
                                                       u16* __restrict__ adj){
  __shared__ u16 sbuf[128*128];
  u16* Qs = sbuf; u16* Ks = sbuf + 128*64; u16* Cs = sbuf;
  int z = blockIdx.z;
  int i0 = blockIdx.x*128, j0 = blockIdx.y*128;
  int t = threadIdx.x;
  const char* Qb = (const char*)(q + (size_t)z*L_SEQ*64) + (size_t)i0*128;
  const char* Kb = (const char*)(k + (size_t)z*L_SEQ*64) + (size_t)j0*128;
  stage_tile(Qb, 128, Qs, 128, t);
  stage_tile(Kb, 128, Ks, 128, t);
  __syncthreads();
  int lane = t&63, w = t>>6, wm = w>>1, wn = w&1;
  int fr = lane&15, kb = (lane>>4)*8;
  f4v acc[4][4];
  #pragma unroll
  for (int m=0;m<4;m++)
    #pragma unroll
    for (int n=0;n<4;n++) acc[m][n]=(f4v){0.f,0.f,0.f,0.f};
  #pragma unroll
  for (int kk=0;kk<2;kk++){
    s8v a[4], bv[4];
    #pragma unroll
    for (int m=0;m<4;m++) a[m] = ldfrag(Qs, wm*64+m*16+fr, kk*32+kb);
    #pragma unroll
    for (int n=0;n<4;n++) bv[n] = ldfrag(Ks, wn*64+n*16+fr, kk*32+kb);
    #pragma unroll
    for (int m=0;m<4;m++)
      #pragma unroll
      for (int n=0;n<4;n++) acc[m][n] = MFMA(a[m], bv[n], acc[m][n]);
  }
  __syncthreads();
  #pragma unroll
  for (int m=0;m<4;m++){
    int row = wm*64 + m*16 + (lane>>4)*4;
    #pragma unroll
    for (int n=0;n<4;n++){
      int col = wn*64 + n*16 + fr;
      #pragma unroll
      for (int r=0;r<4;r++)
        Cs[(row+r)*128 + col] = f2bf(gelu_f(acc[m][n][r]));
    }
  }
  __syncthreads();
  u16* Cb = adj + (size_t)z*L_SEQ*L_SEQ;
  #pragma unroll
  for (int i=0;i<8;i++){
    int idx = i*256 + t;
    int r = idx>>4, cc = (idx&15)*8;
    uint4 v = *(const uint4*)&Cs[r*128 + cc];
    *(uint4*)((char*)Cb + (size_t)(i0+r)*2816 + (j0+cc)*2) = v;
  }
}

// ---------------- generic MFMA GEMM: C = f(A@B + bias) ----------------
template<int OUTBF16,int ACT,int TRANSOUT>
__global__ __launch_bounds__(256) void gemm_mfma_kernel(const u16* __restrict__ A,
                                                        const u16* __restrict__ BT,
                                                        const float* __restrict__ bias,
                                                        void* __restrict__ outp,
                                                        int M, int N, int K){
  __shared__ u16 As[128*64], Bs[128*64];
  int i0 = blockIdx.x*128, j0 = blockIdx.y*128;
  int t = threadIdx.x, lane=t&63, w=t>>6, wm=w>>1, wn=w&1;
  int fr=lane&15, kb=(lane>>4)*8;
  f4v acc[4][4];
  #pragma unroll
  for (int m=0;m<4;m++)
    #pragma unroll
    for (int n=0;n<4;n++) acc[m][n]=(f4v){0.f,0.f,0.f,0.f};
  size_t strA=(size_t)K*2;
  const char* Ab = (const char*)A + (size_t)i0*strA;
  const char* Bb = (const char*)BT + (size_t)j0*strA;
  for (int k0=0;k0<K;k0+=64){
    stage_tile(Ab + (size_t)k0*2, strA, As, 128, t);
    stage_tile(Bb + (size_t)k0*2, strA, Bs, 128, t);
    __syncthreads();
    #pragma unroll
    for (int kk=0;kk<2;kk++){
      s8v a[4], bv[4];
      #pragma unroll
      for (int m=0;m<4;m++) a[m]=ldfrag(As, wm*64+m*16+fr, kk*32+kb);
      #pragma unroll
      for (int n=0;n<4;n++) bv[n]=ldfrag(Bs, wn*64+n*16+fr, kk*32+kb);
      #pragma unroll
      for (int m=0;m<4;m++)
        #pragma unroll
        for (int n=0;n<4;n++) acc[m][n]=MFMA(a[m],bv[n],acc[m][n]);
    }
    __syncthreads();
  }
  #pragma unroll
  for (int m=0;m<4;m++){
    int row = i0 + wm*64+m*16+(lane>>4)*4;
    #pragma unroll
    for (int n=0;n<4;n++){
      int col = j0 + wn*64+n*16+fr;
      float bb = bias[col];
      #pragma unroll
      for (int r=0;r<4;r++){
        float v = acc[m][n][r]+bb;
        if (ACT) v = gelu_f(v);
        if (TRANSOUT) ((u16*)outp)[(size_t)col*M + row + r] = f2bf(v);
        else if (OUTBF16) ((u16*)outp)[(size_t)(row+r)*N+col] = f2bf(v);
        else ((float*)outp)[(size_t)(row+r)*N+col] = v;
      }
    }
  }
}

// ---------------- split-K GEMM partial ----------------
__global__ __launch_bounds__(256) void gemm_ks_kernel(const u16* __restrict__ A,
                                                      const u16* __restrict__ BT,
                                                      float* __restrict__ P,
                                                      int M, int N, int K, int KS){
  __shared__ u16 As[128*64], Bs[128*64];
  int i0 = blockIdx.x*128, j0 = blockIdx.y*128;
  int kbeg = blockIdx.z*KS;
  int t = threadIdx.x, lane=t&63, w=t>>6, wm=w>>1, wn=w&1;
  int fr=lane&15, kb=(lane>>4)*8;
  f4v acc[4][4];
  #pragma unroll
  for (int m=0;m<4;m++)
    #pragma unroll
    for (int n=0;n<4;n++) acc[m][n]=(f4v){0.f,0.f,0.f,0.f};
  size_t strA=(size_t)K*2;
  const char* Ab = (const char*)A + (size_t)i0*strA;
  const char* Bb = (const char*)BT + (size_t)j0*strA;
  for (int k0=kbeg; k0<kbeg+KS; k0+=64){
    stage_tile(Ab + (size_t)k0*2, strA, As, 128, t);
    stage_tile(Bb + (size_t)k0*2, strA, Bs, 128, t);
    __syncthreads();
    #pragma unroll
    for (int kk=0;kk<2;kk++){
      s8v a[4], bv[4];
      #pragma unroll
      for (int m=0;m<4;m++) a[m]=ldfrag(As, wm*64+m*16+fr, kk*32+kb);
      #pragma unroll
      for (int n=0;n<4;n++) bv[n]=ldfrag(Bs, wn*64+n*16+fr, kk*32+kb);
      #pragma unroll
      for (int m=0;m<4;m++)
        #pragma unroll
        for (int n=0;n<4;n++) acc[m][n]=MFMA(a[m],bv[n],acc[m][n]);
    }
    __syncthreads();
  }
  float* Pz = P + (size_t)blockIdx.z*M*N;
  #pragma unroll
  for (int m=0;m<4;m++){
    int row = i0 + wm*64+m*16+(lane>>4)*4;
    #pragma unroll
    for (int n=0;n<4;n++){
      int col = j0 + wn*64+n*16+fr;
      #pragma unroll
      for (int r=0;r<4;r++) Pz[(size_t)(row+r)*N+col] = acc[m][n][r];
    }
  }
}

// ---------------- graph conv split-K partial ----------------
__global__ __launch_bounds__(256) void gc_ks_kernel(const u16* __restrict__ adj,
                                                    const u16* __restrict__ xpt,
                                                    float* __restrict__ P){
  __shared__ u16 As[128*64], Bs[64*64];
  int z = blockIdx.z, b = z>>3, h = z&7;
  int i0 = blockIdx.x*128;
  int kbeg = blockIdx.y*704;
  int t = threadIdx.x, lane=t&63, w=t>>6, wm=w>>1, wn=w&1;
  int fr=lane&15, kb=(lane>>4)*8;
  const char* Ab = (const char*)(adj + (size_t)z*L_SEQ*L_SEQ) + (size_t)i0*2816;
  const char* Bb = (const char*)xpt + (size_t)(h*64)*5632 + (size_t)(b*L_SEQ)*2;
  f4v acc[4][2];
  #pragma unroll
  for (int m=0;m<4;m++){ acc[m][0]=(f4v){0.f,0.f,0.f,0.f}; acc[m][1]=(f4v){0.f,0.f,0.f,0.f}; }
  for (int k0=kbeg; k0<kbeg+704; k0+=64){
    stage_tile(Ab + (size_t)k0*2, 2816, As, 128, t);
    stage_tile(Bb + (size_t)k0*2, 5632, Bs, 64, t);
    __syncthreads();
    #pragma unroll
    for (int kk=0;kk<2;kk++){
      s8v a[4], bv[2];
      #pragma unroll
      for (int m=0;m<4;m++) a[m]=ldfrag(As, wm*64+m*16+fr, kk*32+kb);
      #pragma unroll
      for (int n=0;n<2;n++) bv[n]=ldfrag(Bs, wn*32+n*16+fr, kk*32+kb);
      #pragma unroll
      for (int m=0;m<4;m++)
        #pragma unroll
        for (int n=0;n<2;n++) acc[m][n]=MFMA(a[m],bv[n],acc[m][n]);
    }
    __syncthreads();
  }
  float* Pz = P + (size_t)blockIdx.y*ROWS*DMODEL;
  #pragma unroll
  for (int m=0;m<4;m++){
    int rl = i0 + wm*64+m*16+(lane>>4)*4;
    #pragma unroll
    for (int n=0;n<2;n++){
      int col = h*64 + wn*32+n*16+fr;
      #pragma unroll
      for (int r=0;r<4;r++)
        Pz[(size_t)(b*L_SEQ + rl + r)*DMODEL + col] = acc[m][n][r];
    }
  }
}

// ---------------- per-row pipeline: one WAVE per row, no LDS, no barriers ----------------
__global__ __launch_bounds__(256) void row_pipe2_kernel(u16* __restrict__ adj,
                                                        const float* __restrict__ wgt,
                                                        const float* __restrict__ masks,
                                                        float* __restrict__ spz,
                                                        float* __restrict__ entp){
  int t = threadIdx.x, lane = t&63, w = t>>6;
  int rid = blockIdx.x*4 + w;
  int z = rid / L_SEQ;
  int l = rid - z*L_SEQ;
  unsigned* rowp = (unsigned*)(adj + (size_t)rid*L_SEQ);

  unsigned klo[11], khi[11];
  float x0[11], x1[11];
  #pragma unroll
  for (int i=0;i<11;i++){
    unsigned r = rowp[i*64 + lane];
    unsigned lo = r&0xFFFFu, hi = r>>16;
    klo[i] = key16(lo); khi[i] = key16(hi);
    x0[i] = b2f(lo); x1[i] = b2f(hi);
  }

  // --- 16-step binary search; single-VALU v_cmp ballots, SALU popcounts ---
  unsigned thr = 0; int cnt_thr = 0;
  #pragma unroll
  for (int b=15;b>=0;b--){
    unsigned cand = thr | (1u<<b);
    int cnt = 0;
    #pragma unroll
    for (int i=0;i<11;i++){
      unsigned long long b0 = vcmp_lt_u32(klo[i], cand);
      unsigned long long b1 = vcmp_lt_u32(khi[i], cand);
      int c0, c1; SPOPC(b0, c0); SPOPC(b1, c1);
      cnt += c0 + c1;
    }
    if ((unsigned)cnt < KSEL){ thr = cand; cnt_thr = cnt; }
  }
  int z_eq = (int)(KSEL - cnt_thr);

  // tie zeroing in global index order
  int cnt = 0;
  #pragma unroll
  for (int i=0;i<11;i++){
    bool eq0 = (klo[i]==thr);
    bool eq1 = (khi[i]==thr);
    unsigned long long b0 = __ballot(eq0), b1 = __ballot(eq1);
    int p0b = __builtin_amdgcn_mbcnt_hi((unsigned)(b0>>32), __builtin_amdgcn_mbcnt_lo((unsigned)b0, 0));
    int p1b = __builtin_amdgcn_mbcnt_hi((unsigned)(b1>>32), __builtin_amdgcn_mbcnt_lo((unsigned)b1, 0));
    int pre0 = p0b + p1b;
    int pre1 = pre0 + (eq0?1:0);
    if (eq0 && cnt+pre0 < z_eq) x0[i]=0.f;
    if (eq1 && cnt+pre1 < z_eq) x1[i]=0.f;
    int c0, c1; SPOPC(b0, c0); SPOPC(b1, c1);
    cnt += c0 + c1;
  }
  // zero everything strictly below threshold
  #pragma unroll
  for (int i=0;i<11;i++){
    if (klo[i] < thr) x0[i]=0.f;
    if (khi[i] < thr) x1[i]=0.f;
  }

  // --- gating: wgt is [3][1408] transposed, L1-resident; direct global reads ---
  const float* wg0 = wgt;
  const float* wg1 = wgt + L_SEQ;
  const float* wg2 = wgt + 2*L_SEQ;
  float p0=0.f, p1=0.f, p2=0.f;
  #pragma unroll
  for (int i=0;i<11;i++){
    int e0 = 2*(i*64+lane);
    float2 w0 = *(const float2*)&wg0[e0];
    float2 w1 = *(const float2*)&wg1[e0];
    float2 w2 = *(const float2*)&wg2[e0];
    p0 += x0[i]*w0.x + x1[i]*w0.y;
    p1 += x0[i]*w1.x + x1[i]*w1.y;
    p2 += x0[i]*w2.x + x1[i]*w2.y;
  }
  #pragma unroll
  for (int o=1;o<64;o<<=1){
    p0 += __shfl_xor(p0,o,64);
    p1 += __shfl_xor(p1,o,64);
    p2 += __shfl_xor(p2,o,64);
  }
  float mx = fmaxf(p0, fmaxf(p1,p2));
  float e0s=__expf(p0-mx), e1s=__expf(p1-mx), e2s=__expf(p2-mx);
  float inv = __builtin_amdgcn_rcpf(e0s+e1s+e2s);
  float pr[3]={e0s*inv, e1s*inv, e2s*inv};
  int i0=0; if (pr[1]>pr[i0]) i0=1; if (pr[2]>pr[i0]) i0=2;
  int a_=(i0==0)?1:0, b_=(i0==2)?1:2;
  int i1 = (pr[b_]>pr[a_])?b_:a_;
  bool top2 = !(pr[i0] > 0.5f);
  bool g0=(i0==0)||(top2&&i1==0);
  bool g1=(i0==1)||(top2&&i1==1);
  bool g2=(i0==2)||(top2&&i1==2);
  if (lane==0){
    float ent = pr[0]*__logf(pr[0]+1e-10f)+pr[1]*__logf(pr[1]+1e-10f)+pr[2]*__logf(pr[2]+1e-10f);
    atomicAdd(&entp[rid & 255], ent);
    atomicAdd(&spz[l*3+0], pr[i0]);
    if (top2) atomicAdd(&spz[l*3+1], pr[i1]);
  }

  // --- final mask + softmax: wave-uniform 2-pointer mask selection ---
  const float* m0 = masks + ((size_t)l*3+0)*L_SEQ;
  const float* m1 = m0 + L_SEQ;
  const float* m2 = m1 + L_SEQ;
  const float* pA = g0 ? m0 : (g1 ? m1 : m2);
  const float* pB = pA; float sB = 0.f;
  if (g0 && g1){ pB = m1; sB = 1.f; }
  else if (g0 && g2){ pB = m2; sB = 1.f; }
  else if (g1 && g2){ pB = m2; sB = 1.f; }
  float mxv = -3.0e38f;
  #pragma unroll
  for (int i=0;i<11;i++){
    int e0 = 2*(i*64+lane);
    float2 va = *(const float2*)&pA[e0];
    float2 vb = *(const float2*)&pB[e0];
    float fm0 = va.x + sB*vb.x + ((e0==l)?1.f:0.f);
    float fm1 = va.y + sB*vb.y + ((e0+1==l)?1.f:0.f);
    x0[i] *= fm0; x1[i] *= fm1;
    mxv = fmaxf(mxv, fmaxf(x0[i], x1[i]));
  }
  #pragma unroll
  for (int o=1;o<64;o<<=1) mxv = fmaxf(mxv, __shfl_xor(mxv,o,64));
  float sum=0.f;
  #pragma unroll
  for (int i=0;i<11;i++){
    x0[i] = __expf(x0[i]-mxv);
    x1[i] = __expf(x1[i]-mxv);
    sum += x0[i]+x1[i];
  }
  #pragma unroll
  for (int o=1;o<64;o<<=1) sum += __shfl_xor(sum,o,64);
  float invs = __builtin_amdgcn_rcpf(sum);
  #pragma unroll
  for (int i=0;i<11;i++){
    unsigned lo = f2bf(x0[i]*invs), hi = f2bf(x1[i]*invs);
    rowp[i*64+lane] = lo | (hi<<16);
  }
}

// ---------------- final: add9 epilogue + loss in one launch ----------------
__global__ __launch_bounds__(256) void final_kernel(const float* __restrict__ P,
                                                    const float* __restrict__ x1,
                                                    const float* __restrict__ bias,
                                                    const float* __restrict__ spz,
                                                    const float* __restrict__ entp,
                                                    float* __restrict__ out){
  int t = threadIdx.x;
  if (blockIdx.x < 1408){
    int idx = blockIdx.x*256 + t;
    const float4* P0 = (const float4*)P;
    const float4* P1 = (const float4*)(P + (size_t)ROWS*DMODEL);
    const float4* X  = (const float4*)x1;
    const float4* B4 = (const float4*)bias;
    float4 a = P0[idx], b = P1[idx], c = X[idx], d = B4[idx & 127];
    float4 o; o.x=a.x+b.x+c.x+d.x; o.y=a.y+b.y+c.y+d.y; o.z=a.z+b.z+c.z+d.z; o.w=a.w+b.w+c.w+d.w;
    ((float4*)out)[idx] = o;
  } else {
    float sum=0.f;
    for (int i=t;i<4224;i+=256) sum += spz[i];
    sum = block_reduce_sum(sum);
    float mu = sum/4224.f;
    float ss=0.f;
    for (int i=t;i<4224;i+=256){ float d=spz[i]-mu; ss+=d*d; }
    ss = block_reduce_sum(ss);
    float ent = block_reduce_sum(entp[t]);
    if (t==0){
      float var = ss/4223.f;
      float li = var/(mu*mu+1e-10f);
      float ld = -ent/48.f;
      out[(size_t)ROWS*DMODEL] = li + 0.1f*ld;
    }
  }
}

extern "C" void kernel_launch(void* const* d_in, const int* in_sizes, int n_in,
                              void* d_out, int out_size, void* d_ws, size_t ws_size,
                              hipStream_t stream) {
  const float* x     = (const float*)d_in[0];
  const float* masks = (const float*)d_in[1];
  const float* ln1_g = (const float*)d_in[2];
  const float* ln1_b = (const float*)d_in[3];
  const float* w_p1  = (const float*)d_in[4];
  const float* b_p1  = (const float*)d_in[5];
  const float* w_p2  = (const float*)d_in[6];
  const float* b_p2  = (const float*)d_in[7];
  const float* w_gate= (const float*)d_in[8];
  const float* w_gcn = (const float*)d_in[9];
  const float* b_gcn = (const float*)d_in[10];
  const float* ln2_g = (const float*)d_in[11];
  const float* ln2_b = (const float*)d_in[12];
  const float* w_f1  = (const float*)d_in[13];
  const float* b_f1  = (const float*)d_in[14];
  const float* w_f2  = (const float*)d_in[15];
  const float* b_f2  = (const float*)d_in[16];
  float* out = (float*)d_out;

  char* wsb = (char*)d_ws;
  size_t off = 0;
  u16* adj   = (u16*)(wsb+off); off += (size_t)BH*L_SEQ*L_SEQ*2;  // 63.4 MB
  u16* xn    = (u16*)(wsb+off); off += (size_t)ROWS*DMODEL*2;
  u16* q     = (u16*)(wsb+off); off += (size_t)BH*L_SEQ*64*2;
  u16* kk    = (u16*)(wsb+off); off += (size_t)BH*L_SEQ*64*2;
  u16* xpt   = (u16*)(wsb+off); off += (size_t)DMODEL*ROWS*2;     // [512][2816]
  u16* xn2   = (u16*)(wsb+off); off += (size_t)ROWS*DMODEL*2;
  float* x1  = (float*)(wsb+off); off += (size_t)ROWS*DMODEL*4;
  float* Pk  = (float*)(wsb+off); off += (size_t)2*ROWS*DMODEL*4; // split-K partials
  u16* wgcnT = (u16*)(wsb+off); off += (size_t)DMODEL*DMODEL*2;
  u16* wf1T  = (u16*)(wsb+off); off += (size_t)DFF*DMODEL*2;
  u16* wf2T  = (u16*)(wsb+off); off += (size_t)DMODEL*DFF*2;
  u16* wp1T  = (u16*)(wsb+off); off += (size_t)64*64*2;
  u16* wp2T  = (u16*)(wsb+off); off += (size_t)64*64*2;
  float* wgt = (float*)(wsb+off); off += (size_t)3*L_SEQ*4;       // transposed w_gate
  float* spz = (float*)(wsb+off); off += 4224*4;
  float* entp= (float*)(wsb+off); off += 256*4;
  u16* ffh   = adj;   // reuse after graph conv

  hipMemsetAsync(spz, 0, (4224+256)*sizeof(float), stream);

  // 0. prep: weight transpose-casts + w_gate transpose + LN1
  prep_kernel<<<dim3(2329+ROWS), 256, 0, stream>>>(w_gcn, wgcnT, w_f1, wf1T, w_f2, wf2T,
                                                   w_p1, wp1T, w_p2, wp2T, w_gate, wgt,
                                                   x, ln1_g, ln1_b, xn);
  // 1. Q/K projections (MFMA)
  qk_mfma_kernel<<<dim3(176), 256, 0, stream>>>(xn, wp1T, wp2T, b_p1, b_p2, q, kk);
  // 2. adj = gelu(Q K^T)
  qkt_mfma_kernel<<<dim3(11,11,BH), 256, 0, stream>>>(q, kk, adj);
  // 3. per-row pipeline (wave per row)
  row_pipe2_kernel<<<dim3(BH*L_SEQ/4), 256, 0, stream>>>(adj, wgt, masks, spz, entp);
  // 4. xp^T = (xn @ w_gcn + b_gcn)^T
  gemm_mfma_kernel<0,0,1><<<dim3(22,4), 256, 0, stream>>>(xn, wgcnT, b_gcn, xpt, ROWS, DMODEL, DMODEL);
  // 5. gc partials (split-K 2)
  gc_ks_kernel<<<dim3(11,2,BH), 256, 0, stream>>>(adj, xpt, Pk);
  // 6. x1 = x+P0+P1 ; xn2 = LN2(x1)
  ln2_fuse_kernel<<<ROWS, 256, 0, stream>>>(x, Pk, ln2_g, ln2_b, x1, xn2);
  // 7. ffh = gelu(xn2 @ w_f1 + b_f1)
  gemm_mfma_kernel<1,1,0><<<dim3(22,16), 256, 0, stream>>>(xn2, wf1T, b_f1, ffh, ROWS, DFF, DMODEL);
  // 8. FFN2 partials (split-K 2)
  gemm_ks_kernel<<<dim3(22,4,2), 256, 0, stream>>>(ffh, wf2T, Pk, ROWS, DMODEL, DFF, DFF/2);
  // 9. out = P0+P1+x1+bias ; loss
  final_kernel<<<dim3(1409), 256, 0, stream>>>(Pk, x1, b_f2, spz, entp, out);
}